// Round 1
// 1460.124 us; speedup vs baseline: 1.2082x; 1.2082x over previous
//
#include <hip/hip_runtime.h>
#include <math.h>

#define LSEQ 16384
#define CDIM 320
#define DIN 640
#define NHH 8
#define CONVD 704
#define XBCW 712
#define YSTR 704
#define QCH 64
#define NCHUNK 256

typedef __bf16 bf16_t;
typedef __bf16 bf16x8 __attribute__((ext_vector_type(8)));
typedef float f32x4 __attribute__((ext_vector_type(4)));

// ---------------- reduction helpers ----------------
__device__ __forceinline__ float wave_sum(float v) {
#pragma unroll
  for (int o = 32; o > 0; o >>= 1) v += __shfl_down(v, o, 64);
  return v;
}
__device__ __forceinline__ float wave_max(float v) {
#pragma unroll
  for (int o = 32; o > 0; o >>= 1) v = fmaxf(v, __shfl_down(v, o, 64));
  return v;
}
__device__ __forceinline__ float block_sum256(float v, float* red) {
  int tid = threadIdx.x;
  v = wave_sum(v);
  __syncthreads();
  if ((tid & 63) == 0) red[tid >> 6] = v;
  __syncthreads();
  return red[0] + red[1] + red[2] + red[3];
}
__device__ __forceinline__ float block_max256(float v, float* red) {
  int tid = threadIdx.x;
  v = wave_max(v);
  __syncthreads();
  if ((tid & 63) == 0) red[tid >> 6] = v;
  __syncthreads();
  return fmaxf(fmaxf(red[0], red[1]), fmaxf(red[2], red[3]));
}

__global__ void ws_probe(float* out, float v) { out[0] = v; }

// ---------------- transpose (P,Q)->(Q,P), single batch ----------------
__global__ void ktranspose(const float* __restrict__ src, float* __restrict__ dst,
                           int P, int Q) {
  __shared__ float tile[32][33];
  int p0 = blockIdx.y * 32;
  int q0 = blockIdx.x * 32;
  int tx = threadIdx.x, ty = threadIdx.y;  // 32x8
  for (int i = ty; i < 32; i += 8) {
    int p = p0 + i, q = q0 + tx;
    if (p < P && q < Q) tile[i][tx] = src[(size_t)p * Q + q];
  }
  __syncthreads();
  for (int i = ty; i < 32; i += 8) {
    int q = q0 + i, p = p0 + tx;
    if (q < Q && p < P) dst[(size_t)q * P + p] = tile[tx][i];
  }
}

// -------- fused transpose + layernorm: x[b] (C,L) -> out (L,C), LN over C ----
__global__ __launch_bounds__(256) void tln(const float* __restrict__ x,
                                           const float* __restrict__ w,
                                           const float* __restrict__ b,
                                           float* __restrict__ out) {
  __shared__ float sT[32][321];
  int t0 = blockIdx.x * 32;
  int tid = threadIdx.x;
  for (int i = tid; i < 2560; i += 256) {
    int c = i >> 3, j4 = i & 7;
    float4 v = *(const float4*)(x + (size_t)c * LSEQ + t0 + j4 * 4);
    sT[j4 * 4 + 0][c] = v.x;
    sT[j4 * 4 + 1][c] = v.y;
    sT[j4 * 4 + 2][c] = v.z;
    sT[j4 * 4 + 3][c] = v.w;
  }
  __syncthreads();
  int wave = tid >> 6, lane = tid & 63;
  for (int tt = wave; tt < 32; tt += 4) {
    float xv[5];
    float s = 0.f;
#pragma unroll
    for (int k = 0; k < 5; ++k) { xv[k] = sT[tt][lane + 64 * k]; s += xv[k]; }
    s = wave_sum(s); s = __shfl(s, 0, 64);
    float mean = s * (1.f / 320.f);
    float v = 0.f;
#pragma unroll
    for (int k = 0; k < 5; ++k) { float d = xv[k] - mean; v += d * d; }
    v = wave_sum(v); v = __shfl(v, 0, 64);
    float rstd = rsqrtf(v * (1.f / 320.f) + 1e-5f);
    float* op = out + (size_t)(t0 + tt) * CDIM;
#pragma unroll
    for (int k = 0; k < 5; ++k) {
      int i = lane + 64 * k;
      op[i] = (xv[k] - mean) * rstd * w[i] + b[i];
    }
  }
}

// ---------------- layernorm rows (D=320), one wave per row -------------------
__global__ __launch_bounds__(64) void ln_rows64(float* __restrict__ io,
                                                const float* __restrict__ w,
                                                const float* __restrict__ b) {
  size_t row = blockIdx.x;
  float* xp = io + row * CDIM;
  int lane = threadIdx.x;
  float x[5];
  float s = 0.f;
#pragma unroll
  for (int k = 0; k < 5; ++k) { x[k] = xp[lane + 64 * k]; s += x[k]; }
  s = wave_sum(s); s = __shfl(s, 0, 64);
  float mean = s * (1.f / 320.f);
  float v = 0.f;
#pragma unroll
  for (int k = 0; k < 5; ++k) { float t = x[k] - mean; v += t * t; }
  v = wave_sum(v); v = __shfl(v, 0, 64);
  float rstd = rsqrtf(v * (1.f / 320.f) + 1e-5f);
#pragma unroll
  for (int k = 0; k < 5; ++k) {
    int i = lane + 64 * k;
    xp[i] = (x[k] - mean) * rstd * w[i] + b[i];
  }
}

// ------------- bf16 MFMA GEMM, 128x64 tile, XCD-chunked swizzle --------------
// C[..] = (A (+pe)) @ W^T (+bias) (+=C).  Optional column split at nsplit:
// cols [0,nsplit) -> C (ld=ldc), cols [nsplit,N) -> C2 (ld=ldc2).
__global__ __launch_bounds__(256) void gemm_bf(
    const float* __restrict__ A, const float* __restrict__ W,
    const float* __restrict__ bias, const float* __restrict__ pe,
    float* __restrict__ C, float* __restrict__ C2,
    int M, int N, int K, int lda, int ldc, int nsplit, int ldc2,
    int addC, long long sA, long long sC) {
  int z = blockIdx.z;
  A += (size_t)z * sA;
  C += (size_t)z * sC;
  // bijective XCD-chunked swizzle: XCD k owns a contiguous range of tiles
  int gx = gridDim.x;
  int nwg = gx * gridDim.y;
  int lin = blockIdx.y * gx + blockIdx.x;
  int xcd = lin & 7, idx = lin >> 3;
  int q = nwg >> 3, r = nwg & 7;
  int base = (xcd < r) ? xcd * (q + 1) : r * (q + 1) + (xcd - r) * q;
  int lin2 = base + idx;
  int mblk = lin2 / gx, nblk = lin2 % gx;
  int m0 = mblk << 7, n0 = nblk << 6;

  __shared__ __align__(16) bf16_t As[2][4096];  // 8 groups of 16 rows x 32 k
  __shared__ __align__(16) bf16_t Ws[2][2048];  // 4 groups
  int tid = threadIdx.x;
  int wave = tid >> 6, lane = tid & 63;
  int fm = lane & 15, quad = lane >> 4;
  // staging mapping
  int rA = tid >> 1, hA = tid & 1;  // A row (0..127), col-half (16 floats)
  int rW = tid >> 2, qW = tid & 3;  // W row (0..63), col-quad (8 floats)
  const float* ag = A + (size_t)(m0 + rA) * lda + hA * 16;
  const float* peg = pe ? pe + (size_t)(m0 + rA) * lda + hA * 16 : (const float*)0;
  int wRow = n0 + rW;
  const float* wg = W + (size_t)wRow * K + qW * 8;
  bool wok = wRow < N;
  int aoff = (rA >> 4) * 512 + (hA * 32 + (rA & 15)) * 8;  // quad hA*2; +128 for hA*2+1
  int woff = (rW >> 4) * 512 + (qW * 16 + (rW & 15)) * 8;

  f32x4 acc[2][4];
#pragma unroll
  for (int i = 0; i < 2; ++i)
#pragma unroll
    for (int j = 0; j < 4; ++j) acc[i][j] = (f32x4){0.f, 0.f, 0.f, 0.f};

  float4 pa0, pa1, pa2, pa3, pw0, pw1;
  auto loadG = [&](int k0) {
    pa0 = *(const float4*)(ag + k0);
    pa1 = *(const float4*)(ag + k0 + 4);
    pa2 = *(const float4*)(ag + k0 + 8);
    pa3 = *(const float4*)(ag + k0 + 12);
    if (peg) {
      float4 q0 = *(const float4*)(peg + k0);
      float4 q1 = *(const float4*)(peg + k0 + 4);
      float4 q2 = *(const float4*)(peg + k0 + 8);
      float4 q3 = *(const float4*)(peg + k0 + 12);
      pa0.x += q0.x; pa0.y += q0.y; pa0.z += q0.z; pa0.w += q0.w;
      pa1.x += q1.x; pa1.y += q1.y; pa1.z += q1.z; pa1.w += q1.w;
      pa2.x += q2.x; pa2.y += q2.y; pa2.z += q2.z; pa2.w += q2.w;
      pa3.x += q3.x; pa3.y += q3.y; pa3.z += q3.z; pa3.w += q3.w;
    }
    pw0 = make_float4(0.f, 0.f, 0.f, 0.f);
    pw1 = pw0;
    if (wok) {
      pw0 = *(const float4*)(wg + k0);
      pw1 = *(const float4*)(wg + k0 + 4);
    }
  };
  auto packLDS = [&](int buf) {
    bf16x8 v;
    v[0] = (bf16_t)pa0.x; v[1] = (bf16_t)pa0.y; v[2] = (bf16_t)pa0.z; v[3] = (bf16_t)pa0.w;
    v[4] = (bf16_t)pa1.x; v[5] = (bf16_t)pa1.y; v[6] = (bf16_t)pa1.z; v[7] = (bf16_t)pa1.w;
    *(bf16x8*)&As[buf][aoff] = v;
    v[0] = (bf16_t)pa2.x; v[1] = (bf16_t)pa2.y; v[2] = (bf16_t)pa2.z; v[3] = (bf16_t)pa2.w;
    v[4] = (bf16_t)pa3.x; v[5] = (bf16_t)pa3.y; v[6] = (bf16_t)pa3.z; v[7] = (bf16_t)pa3.w;
    *(bf16x8*)&As[buf][aoff + 128] = v;
    v[0] = (bf16_t)pw0.x; v[1] = (bf16_t)pw0.y; v[2] = (bf16_t)pw0.z; v[3] = (bf16_t)pw0.w;
    v[4] = (bf16_t)pw1.x; v[5] = (bf16_t)pw1.y; v[6] = (bf16_t)pw1.z; v[7] = (bf16_t)pw1.w;
    *(bf16x8*)&Ws[buf][woff] = v;
  };

  int nk = K >> 5;
  loadG(0);
  packLDS(0);
  __syncthreads();
  for (int i = 0; i < nk; ++i) {
    int buf = i & 1;
    bool more = (i + 1 < nk);
    if (more) loadG((i + 1) << 5);
    int ab = wave * 1024 + lane * 8;
    bf16x8 af0 = *(bf16x8*)&As[buf][ab];
    bf16x8 af1 = *(bf16x8*)&As[buf][ab + 512];
    bf16x8 b0 = *(bf16x8*)&Ws[buf][lane * 8];
    bf16x8 b1 = *(bf16x8*)&Ws[buf][512 + lane * 8];
    bf16x8 b2 = *(bf16x8*)&Ws[buf][1024 + lane * 8];
    bf16x8 b3 = *(bf16x8*)&Ws[buf][1536 + lane * 8];
    acc[0][0] = __builtin_amdgcn_mfma_f32_16x16x32_bf16(af0, b0, acc[0][0], 0, 0, 0);
    acc[0][1] = __builtin_amdgcn_mfma_f32_16x16x32_bf16(af0, b1, acc[0][1], 0, 0, 0);
    acc[0][2] = __builtin_amdgcn_mfma_f32_16x16x32_bf16(af0, b2, acc[0][2], 0, 0, 0);
    acc[0][3] = __builtin_amdgcn_mfma_f32_16x16x32_bf16(af0, b3, acc[0][3], 0, 0, 0);
    acc[1][0] = __builtin_amdgcn_mfma_f32_16x16x32_bf16(af1, b0, acc[1][0], 0, 0, 0);
    acc[1][1] = __builtin_amdgcn_mfma_f32_16x16x32_bf16(af1, b1, acc[1][1], 0, 0, 0);
    acc[1][2] = __builtin_amdgcn_mfma_f32_16x16x32_bf16(af1, b2, acc[1][2], 0, 0, 0);
    acc[1][3] = __builtin_amdgcn_mfma_f32_16x16x32_bf16(af1, b3, acc[1][3], 0, 0, 0);
    if (more) {
      packLDS(buf ^ 1);
      __syncthreads();
    }
  }
#pragma unroll
  for (int ms = 0; ms < 2; ++ms)
#pragma unroll
    for (int ns = 0; ns < 4; ++ns) {
      int n = n0 + ns * 16 + fm;
      if (n >= N) continue;
      float bv = bias ? bias[n] : 0.f;
      float* Cb;
      int ldcb, nc;
      if (n < nsplit) { Cb = C; ldcb = ldc; nc = n; }
      else           { Cb = C2; ldcb = ldc2; nc = n - nsplit; }
#pragma unroll
      for (int rr = 0; rr < 4; ++rr) {
        int m = m0 + wave * 32 + ms * 16 + quad * 4 + rr;
        float v = acc[ms][ns][rr] + bv;
        size_t off = (size_t)m * ldcb + nc;
        if (addC) v += Cb[off];
        Cb[off] = v;
      }
    }
}

// -------- small matmul (token side), wave-per-output-column ------------------
__global__ __launch_bounds__(256) void smallmm(
    const float* __restrict__ A, const float* __restrict__ A2,
    const float* __restrict__ W, const float* __restrict__ bias,
    float* __restrict__ C, int M, int N, int K, int addC, int relu, int a2lim) {
  int wave = threadIdx.x >> 6, lane = threadIdx.x & 63;
  int n = blockIdx.x * 4 + wave;
  if (n >= N) return;
  const float* w = W + (size_t)n * K;
  float wreg[16];
  int nu = (K + 63) >> 6;
#pragma unroll 4
  for (int u = 0; u < nu; ++u) {
    int k = lane + (u << 6);
    wreg[u] = (k < K) ? w[k] : 0.f;
  }
  bool useA2 = (A2 != nullptr) && (n < a2lim);
  float part[12];
  for (int m = 0; m < M; ++m) part[m] = 0.f;
  for (int u = 0; u < nu; ++u) {
    int k = lane + (u << 6);
    if (k < K) {
      float wv = wreg[u];
      for (int m = 0; m < M; ++m) {
        float av = A[(size_t)m * K + k];
        if (useA2) av += A2[(size_t)m * K + k];
        part[m] += av * wv;
      }
    }
  }
  float bv = bias ? bias[n] : 0.f;
  for (int m = 0; m < M; ++m) {
    float dot = wave_sum(part[m]);
    if (lane == 0) {
      float v = dot + bv;
      if (relu) v = fmaxf(v, 0.f);
      size_t off = (size_t)m * N + n;
      if (addC) v += C[off];
      C[off] = v;
    }
  }
}

// ---------------- dt = softplus(dt_raw + dt_bias), layout (h,t) --------------
__global__ void dt_kernel(const float* __restrict__ XBC, const float* __restrict__ dt_bias,
                          float* __restrict__ dtbuf) {
  int idx = blockIdx.x * 256 + threadIdx.x;
  if (idx >= LSEQ * NHH) return;
  int h = idx & 7;
  int t = idx >> 3;
  float v = XBC[(size_t)t * XBCW + 704 + h] + dt_bias[h];
  float sp = (v > 20.f) ? v : log1pf(expf(v));
  dtbuf[(size_t)h * LSEQ + t] = sp;
}

// ---------------- causal depthwise conv + silu ----------------
__global__ void conv_kernel(const float* __restrict__ XBC, const float* __restrict__ conv_w,
                            const float* __restrict__ conv_b, float* __restrict__ Cv) {
  int idx = blockIdx.x * 256 + threadIdx.x;
  if (idx >= LSEQ * CONVD) return;
  int d = idx % CONVD;
  int t = idx / CONVD;
  float acc = conv_b[d];
#pragma unroll
  for (int k = 0; k < 4; ++k) {
    int tt = t - 3 + k;
    if (tt >= 0) acc += XBC[(size_t)tt * XBCW + d] * conv_w[d * 4 + k];
  }
  Cv[(size_t)t * CONVD + d] = acc / (1.f + expf(-acc));
}

// ---------------- scan phase A: per-chunk states + cumulative log-decay ------
__global__ __launch_bounds__(256) void scan_a(const float* __restrict__ Cv,
                                              const float* __restrict__ dtbuf,
                                              const float* __restrict__ A_log,
                                              float* __restrict__ Schunk,
                                              float* __restrict__ cabuf) {
  int c = blockIdx.x, h = blockIdx.y;
  int t0 = c * QCH;
  __shared__ float sdt[64], sca[64], sw[64];
  __shared__ __align__(16) float sB[64][36];
  __shared__ __align__(16) float sXt[80][68];
  int tid = threadIdx.x;
  float Aval = -expf(A_log[h]);
  if (tid < 64) sdt[tid] = dtbuf[(size_t)h * LSEQ + t0 + tid];
  __syncthreads();
  if (tid == 0) {
    float run = 0.f;
    for (int j = 0; j < 64; ++j) { run += sdt[j] * Aval; sca[j] = run; }
  }
  __syncthreads();
  float caend = sca[63];
  if (tid < 64) {
    sw[tid] = expf(caend - sca[tid]) * sdt[tid];
    cabuf[(size_t)h * LSEQ + t0 + tid] = sca[tid];
  }
  for (int i = tid; i < 2048; i += 256) {
    int j = i >> 5, n = i & 31;
    sB[j][n] = Cv[(size_t)(t0 + j) * CONVD + 640 + n];
  }
  for (int i = tid; i < 5120; i += 256) {
    int j = i / 80, p = i % 80;
    sXt[p][j] = Cv[(size_t)(t0 + j) * CONVD + h * 80 + p];
  }
  __syncthreads();
  int n = tid >> 3, pb = tid & 7;
  float acc[10];
#pragma unroll
  for (int u = 0; u < 10; ++u) acc[u] = 0.f;
  for (int jb = 0; jb < 16; ++jb) {
    float wB[4];
#pragma unroll
    for (int jj = 0; jj < 4; ++jj) {
      int j = jb * 4 + jj;
      wB[jj] = sw[j] * sB[j][n];
    }
#pragma unroll
    for (int u = 0; u < 10; ++u) {
      int p = pb * 10 + u;
      float4 x4 = *(const float4*)&sXt[p][jb * 4];
      acc[u] += wB[0] * x4.x + wB[1] * x4.y + wB[2] * x4.z + wB[3] * x4.w;
    }
  }
  float* outp = Schunk + (size_t)(h * NCHUNK + c) * 2560;
#pragma unroll
  for (int u = 0; u < 10; ++u) outp[n * 80 + pb * 10 + u] = acc[u];
}

// ---------------- scan phase B: sequential over chunks, 80 blocks ------------
__global__ __launch_bounds__(256) void scan_b(const float* __restrict__ Schunk,
                                              const float* __restrict__ cabuf,
                                              float* __restrict__ Sprev) {
  int pc = blockIdx.x, h = blockIdx.y;
  __shared__ float sdec[256];
  int tid = threadIdx.x;
  sdec[tid] = expf(cabuf[(size_t)h * LSEQ + tid * 64 + 63]);
  __syncthreads();
  int e = pc * 256 + tid;
  const float* base = Schunk + (size_t)h * NCHUNK * 2560 + e;
  float* pbase = Sprev + (size_t)h * NCHUNK * 2560 + e;
  float s = 0.f;
  float v = base[0];
  for (int c = 0; c < NCHUNK; ++c) {
    float vn = (c < NCHUNK - 1) ? base[(size_t)(c + 1) * 2560] : 0.f;
    pbase[(size_t)c * 2560] = s;
    s = s * sdec[c] + v;
    v = vn;
  }
}

// ---------------- scan phase C: MFMA version; Y written IN-PLACE over the ----
// ---------------- X-portion of Cv (stride YSTR=704, cols 0..640) ------------
__global__ __launch_bounds__(256) void scan_c(const float* __restrict__ Cv,
                                              const float* __restrict__ dtbuf,
                                              const float* __restrict__ cabuf,
                                              const float* __restrict__ Sprev,
                                              const float* __restrict__ Dp,
                                              float* __restrict__ Y) {
  int c = blockIdx.x, h = blockIdx.y;
  int t0 = c * QCH;
  __shared__ float sdt[64], sca[64], sexp[64];
  __shared__ __align__(16) bf16_t sC[64 * 40];   // C[j][n], stride 40
  __shared__ __align__(16) bf16_t sB[64 * 40];   // B[s][n], stride 40
  __shared__ __align__(16) bf16_t sXt[80 * 72];  // X^T [p][j], stride 72
  __shared__ __align__(16) bf16_t sSt[80 * 40];  // Sprev^T [p][n], stride 40
  __shared__ __align__(16) bf16_t sP[64 * 72];   // scores [j][s], stride 72
  int tid = threadIdx.x;
  int wave = tid >> 6, lane = tid & 63;
  int fm = lane & 15, quad = lane >> 4;
  if (tid < 64) {
    sdt[tid] = dtbuf[(size_t)h * LSEQ + t0 + tid];
    float cav = cabuf[(size_t)h * LSEQ + t0 + tid];
    sca[tid] = cav;
    sexp[tid] = expf(cav);
  }
  for (int i = tid; i < 2048; i += 256) {
    int j = i >> 5, n = i & 31;
    size_t base = (size_t)(t0 + j) * CONVD;
    sB[j * 40 + n] = (bf16_t)Cv[base + 640 + n];
    sC[j * 40 + n] = (bf16_t)Cv[base + 672 + n];
  }
  for (int i = tid; i < 5120; i += 256) {
    int j = i / 80, p = i % 80;
    sXt[p * 72 + j] = (bf16_t)Cv[(size_t)(t0 + j) * CONVD + h * 80 + p];
  }
  {
    const float* sp = Sprev + (size_t)(h * NCHUNK + c) * 2560;
    for (int i = tid; i < 2560; i += 256) {
      int n = i / 80, p = i % 80;
      sSt[p * 40 + n] = (bf16_t)sp[i];
    }
  }
  __syncthreads();
  int m0 = wave * 16;
  int jbase = m0 + quad * 4;
  bf16x8 afC = *(bf16x8*)&sC[(m0 + fm) * 40 + quad * 8];
  f32x4 accS[4];
#pragma unroll
  for (int nt = 0; nt < 4; ++nt) {
    bf16x8 bf = *(bf16x8*)&sB[(nt * 16 + fm) * 40 + quad * 8];
    f32x4 zero = (f32x4){0.f, 0.f, 0.f, 0.f};
    accS[nt] = __builtin_amdgcn_mfma_f32_16x16x32_bf16(afC, bf, zero, 0, 0, 0);
  }
  float scaj[4];
#pragma unroll
  for (int r = 0; r < 4; ++r) scaj[r] = sca[jbase + r];
#pragma unroll
  for (int nt = 0; nt < 4; ++nt) {
    int s = nt * 16 + fm;
    float dts = sdt[s], scas = sca[s];
#pragma unroll
    for (int r = 0; r < 4; ++r) {
      int j = jbase + r;
      float v = 0.f;
      if (s <= j) v = accS[nt][r] * dts * expf(scaj[r] - scas);
      sP[j * 72 + s] = (bf16_t)v;
    }
  }
  f32x4 acc[5];
#pragma unroll
  for (int pt = 0; pt < 5; ++pt) {
    bf16x8 bf = *(bf16x8*)&sSt[(pt * 16 + fm) * 40 + quad * 8];
    f32x4 zero = (f32x4){0.f, 0.f, 0.f, 0.f};
    acc[pt] = __builtin_amdgcn_mfma_f32_16x16x32_bf16(afC, bf, zero, 0, 0, 0);
  }
  float gj[4];
#pragma unroll
  for (int r = 0; r < 4; ++r) gj[r] = sexp[jbase + r];
#pragma unroll
  for (int pt = 0; pt < 5; ++pt)
#pragma unroll
    for (int r = 0; r < 4; ++r) acc[pt][r] *= gj[r];
  bf16x8 afP0 = *(bf16x8*)&sP[(m0 + fm) * 72 + 0 + quad * 8];
  bf16x8 afP1 = *(bf16x8*)&sP[(m0 + fm) * 72 + 32 + quad * 8];
#pragma unroll
  for (int pt = 0; pt < 5; ++pt) {
    bf16x8 bx0 = *(bf16x8*)&sXt[(pt * 16 + fm) * 72 + 0 + quad * 8];
    bf16x8 bx1 = *(bf16x8*)&sXt[(pt * 16 + fm) * 72 + 32 + quad * 8];
    acc[pt] = __builtin_amdgcn_mfma_f32_16x16x32_bf16(afP0, bx0, acc[pt], 0, 0, 0);
    acc[pt] = __builtin_amdgcn_mfma_f32_16x16x32_bf16(afP1, bx1, acc[pt], 0, 0, 0);
  }
  float dval = Dp[h];
#pragma unroll
  for (int pt = 0; pt < 5; ++pt) {
    int p = pt * 16 + fm;
#pragma unroll
    for (int r = 0; r < 4; ++r) {
      int j = jbase + r;
      float xv = (float)sXt[p * 72 + j];
      Y[(size_t)(t0 + j) * YSTR + h * 80 + p] = acc[pt][r] + dval * xv;
    }
  }
}

// ------------- y *= silu(z); rmsnorm * rms_w  (Y stride YSTR) ----------------
__global__ __launch_bounds__(256) void gate_rms(float* __restrict__ Y,
                                                const float* __restrict__ Z,
                                                const float* __restrict__ rms_w) {
  __shared__ float red[4];
  size_t row = blockIdx.x;
  float* y = Y + row * YSTR;
  const float* z = Z + row * DIN;
  float ss = 0.f;
  for (int i = threadIdx.x; i < DIN; i += 256) {
    float zi = z[i];
    float g = y[i] * (zi / (1.f + expf(-zi)));
    y[i] = g;
    ss += g * g;
  }
  float tot = block_sum256(ss, red);
  float r = rsqrtf(tot / (float)DIN + 1e-5f);
  for (int i = threadIdx.x; i < DIN; i += 256) y[i] = y[i] * r * rms_w[i];
}

// ---------------- dense image PE ----------------
__global__ void kpe_kernel(const float* __restrict__ gauss, float* __restrict__ KPE) {
  int idx = blockIdx.x * 256 + threadIdx.x;
  if (idx >= LSEQ * 160) return;
  int f = idx % 160, t = idx / 160;
  int d = t >> 10, hh = (t >> 5) & 31, w = t & 31;
  float vx = 2.f * ((d + 0.5f) / 16.f) - 1.f;
  float vy = 2.f * ((hh + 0.5f) / 32.f) - 1.f;
  float vz = 2.f * ((w + 0.5f) / 32.f) - 1.f;
  float cc = 6.28318530717958647692f * (vx * gauss[f] + vy * gauss[160 + f] + vz * gauss[320 + f]);
  KPE[(size_t)t * CDIM + f] = sinf(cc);
  KPE[(size_t)t * CDIM + 160 + f] = cosf(cc);
}

// ---------------- point embeddings (both batches: 12 points) -----------------
__global__ void point_kernel(const float* __restrict__ coords, const int* __restrict__ labels,
                             const float* __restrict__ gauss, const float* __restrict__ ptab,
                             float* __restrict__ qpe, float* __restrict__ queries) {
  int idx = blockIdx.x * 64 + threadIdx.x;
  if (idx >= 12 * 160) return;
  int f = idx % 160, pt = idx / 160;
  const float* co = coords + pt * 3;
  float vx = 2.f * (co[0] / 128.f) - 1.f;
  float vy = 2.f * (co[1] / 256.f) - 1.f;
  float vz = 2.f * (co[2] / 256.f) - 1.f;
  float cc = 6.28318530717958647692f * (vx * gauss[f] + vy * gauss[160 + f] + vz * gauss[320 + f]);
  int lab = labels[pt];
  float sv = sinf(cc) + ptab[lab * CDIM + f];
  float cv = cosf(cc) + ptab[lab * CDIM + 160 + f];
  qpe[pt * CDIM + f] = sv;       qpe[pt * CDIM + 160 + f] = cv;
  queries[pt * CDIM + f] = sv;   queries[pt * CDIM + 160 + f] = cv;
}

// --------- self-attn over 6 tokens from fused P3[12][960], grid (4,2) --------
__global__ void attn_self(const float* __restrict__ P3, float* __restrict__ O) {
  int h = blockIdx.x, b = blockIdx.y;
  __shared__ float sq[6][80], sk[6][80], sv[6][80], sw[6][6];
  int tid = threadIdx.x;  // 128
  for (int i = tid; i < 480; i += 128) {
    int tok = i / 80, p = i % 80;
    const float* base = P3 + (size_t)(b * 6 + tok) * 960 + h * 80 + p;
    sq[tok][p] = base[0]; sk[tok][p] = base[320]; sv[tok][p] = base[640];
  }
  __syncthreads();
  if (tid < 36) {
    int qi = tid / 6, ki = tid % 6;
    float d = 0.f;
    for (int p = 0; p < 80; ++p) d += sq[qi][p] * sk[ki][p];
    sw[qi][ki] = d * 0.11180339887498948f;  // 1/sqrt(80)
  }
  __syncthreads();
  if (tid < 6) {
    float mx = sw[tid][0];
    for (int k = 1; k < 6; ++k) mx = fmaxf(mx, sw[tid][k]);
    float s = 0.f;
    for (int k = 0; k < 6; ++k) { float e = expf(sw[tid][k] - mx); sw[tid][k] = e; s += e; }
    float inv = 1.f / s;
    for (int k = 0; k < 6; ++k) sw[tid][k] *= inv;
  }
  __syncthreads();
  for (int i = tid; i < 480; i += 128) {
    int qi = i / 80, p = i % 80;
    float o = 0.f;
    for (int k = 0; k < 6; ++k) o += sw[qi][k] * sv[k][p];
    O[(size_t)(b * 6 + qi) * CDIM + h * 80 + p] = o;
  }
}

// ------------- t2i attention pass 1: split-K partials, grid (64,24,2) --------
__global__ __launch_bounds__(256) void attn_t2i_part(const float* __restrict__ Qp,
                                                     const float* __restrict__ Kp,
                                                     const float* __restrict__ Vp,
                                                     float* __restrict__ Part) {
  int b = blockIdx.z;
  int blk = blockIdx.y;  // h*6 + qi
  int qi = blk % 6;
  int h = blk / 6;
  int c = blockIdx.x;
  Qp += (size_t)b * 960;
  Kp += (size_t)b * LSEQ * 160;
  Vp += (size_t)b * LSEQ * 160;
  Part += (size_t)b * 24 * 64 * 42;
  __shared__ __align__(16) float sq[40];
  __shared__ float red[4];
  __shared__ float sOp[4][40];
  int tid = threadIdx.x;
  if (tid < 40) sq[tid] = Qp[(size_t)qi * 160 + h * 40 + tid];
  __syncthreads();
  int t = c * 256 + tid;
  const float* kp = Kp + (size_t)t * 160 + h * 40;
  float d = 0.f;
#pragma unroll
  for (int v = 0; v < 10; ++v) {
    float4 q4 = *(const float4*)&sq[v * 4];
    float4 k4 = *(const float4*)(kp + v * 4);
    d += q4.x * k4.x + q4.y * k4.y + q4.z * k4.z + q4.w * k4.w;
  }
  d *= 0.15811388300841897f;  // 1/sqrt(40)
  float gmax = block_max256(d, red);
  float e = expf(d - gmax);
  float ls = block_sum256(e, red);
  const float* vp = Vp + (size_t)t * 160 + h * 40;
  float vr[40];
#pragma unroll
  for (int v = 0; v < 10; ++v) {
    float4 v4 = *(const float4*)(vp + v * 4);
    vr[v * 4 + 0] = v4.x; vr[v * 4 + 1] = v4.y; vr[v * 4 + 2] = v4.z; vr[v * 4 + 3] = v4.w;
  }
  int wave = tid >> 6, lane = tid & 63;
#pragma unroll
  for (int p = 0; p < 40; ++p) {
    float v = wave_sum(e * vr[p]);
    if (lane == 0) sOp[wave][p] = v;
  }
  __syncthreads();
  float* part = Part + (size_t)(blk * 64 + c) * 42;
  if (tid == 0) { part[40] = gmax; part[41] = ls; }
  if (tid < 40) part[tid] = sOp[0][tid] + sOp[1][tid] + sOp[2][tid] + sOp[3][tid];
}

// ------------- t2i attention pass 2: combine 64 partials, grid (24,2) --------
__global__ void attn_t2i_comb(const float* __restrict__ Part, float* __restrict__ O) {
  int b = blockIdx.y;
  int blk = blockIdx.x;  // h*6 + qi
  int qi = blk % 6;
  int h = blk / 6;
  int j = threadIdx.x;  // 64
  const float* part = Part + (size_t)b * 24 * 64 * 42 + (size_t)(blk * 64 + j) * 42;
  float m = part[40], l = part[41];
  float gmax = wave_max(m);
  gmax = __shfl(gmax, 0, 64);
  float sc = expf(m - gmax);
  float tot = wave_sum(l * sc);
  tot = __shfl(tot, 0, 64);
  float inv = 1.f / tot;
  for (int p = 0; p < 40; ++p) {
    float v = wave_sum(part[p] * sc);
    if (j == 0) O[(size_t)b * 960 + (size_t)qi * 160 + h * 40 + p] = v * inv;
  }
}

// ------- i2t attention: 16384 q vs 6 k, KV fused [12][320], grid (64,4,2) ----
__global__ __launch_bounds__(256) void attn_i2t(const float* __restrict__ Qp,
                                                const float* __restrict__ KV,
                                                float* __restrict__ O) {
  int h = blockIdx.y, b = blockIdx.z;
  int t = blockIdx.x * 256 + threadIdx.x;
  Qp += (size_t)b * LSEQ * 160;
  O += (size_t)b * LSEQ * 160;
  __shared__ float sk[6][40], sv[6][40];
  if (threadIdx.x < 240) {
    int tok = threadIdx.x / 40, p = threadIdx.x % 40;
    const float* base = KV + (size_t)(b * 6 + tok) * 320 + h * 40 + p;
    sk[tok][p] = base[0];
    sv[tok][p] = base[160];
  }
  __syncthreads();
  const float* q = Qp + (size_t)t * 160 + h * 40;
  float qr[40];
#pragma unroll
  for (int v = 0; v < 10; ++v) {
    float4 q4 = *(const float4*)(q + v * 4);
    qr[v * 4 + 0] = q4.x; qr[v * 4 + 1] = q4.y; qr[v * 4 + 2] = q4.z; qr[v * 4 + 3] = q4.w;
  }
  float s[6];
#pragma unroll
  for (int k = 0; k < 6; ++k) {
    float d = 0.f;
    for (int p = 0; p < 40; ++p) d += qr[p] * sk[k][p];
    s[k] = d * 0.15811388300841897f;
  }
  float mx = s[0];
#pragma unroll
  for (int k = 1; k < 6; ++k) mx = fmaxf(mx, s[k]);
  float sum = 0.f;
#pragma unroll
  for (int k = 0; k < 6; ++k) { s[k] = expf(s[k] - mx); sum += s[k]; }
  float inv = 1.f / sum;
  float* o = O + (size_t)t * 160 + h * 40;
#pragma unroll
  for (int p = 0; p < 40; ++p) {
    float v = 0.f;
    for (int k = 0; k < 6; ++k) v += s[k] * sv[k][p];
    o[p] = v * inv;
  }
}

// =======================================================================
extern "C" void kernel_launch(void* const* d_in, const int* in_sizes, int n_in,
                              void* d_out, int out_size, void* d_ws, size_t ws_size,
                              hipStream_t stream) {
  (void)in_sizes; (void)n_in; (void)out_size;
  const float* x       = (const float*)d_in[0];
  const float* coords  = (const float*)d_in[1];
  const int*   labels  = (const int*)  d_in[2];
  const float* ln_w    = (const float*)d_in[3];
  const float* ln_b    = (const float*)d_in[4];
  const float* in_w    = (const float*)d_in[5];
  const float* conv_w  = (const float*)d_in[6];
  const float* conv_b  = (const float*)d_in[7];
  const float* dt_bias = (const float*)d_in[8];
  const float* A_log   = (const float*)d_in[9];
  const float* Dp      = (const float*)d_in[10];
  const float* rms_w   = (const float*)d_in[11];
  const float* out_w   = (const float*)d_in[12];
  const float* gauss   = (const float*)d_in[13];
  const float* ptab    = (const float*)d_in[14];
  const float* sa_w    = (const float*)d_in[15];
  const float* sa_b    = (const float*)d_in[16];
  const float* t2i_w   = (const float*)d_in[17];
  const float* t2i_b   = (const float*)d_in[18];
  const float* t2i_ow  = (const float*)d_in[19];
  const float* t2i_ob  = (const float*)d_in[20];
  const float* i2t_w   = (const float*)d_in[21];
  const float* i2t_b   = (const float*)d_in[22];
  const float* i2t_ow  = (const float*)d_in[23];
  const float* i2t_ob  = (const float*)d_in[24];
  const float* norms_w = (const float*)d_in[25];
  const float* norms_b = (const float*)d_in[26];
  const float* mlp_w1  = (const float*)d_in[27];
  const float* mlp_b1  = (const float*)d_in[28];
  const float* mlp_w2  = (const float*)d_in[29];
  const float* mlp_b2  = (const float*)d_in[30];
  float* out = (float*)d_out;
  float* ws = (float*)d_ws;

  const size_t NEED = (size_t)(10485760 + 5242880 + 11665408 + 11534336 + 10485760 +
                               131072 + 131072 + 65536) * 4;
  if (ws_size < NEED) {
    ws_probe<<<1, 1, 0, stream>>>(out, (float)ws_size);
    return;
  }
  float* R_K = ws;                         // [2][16384][320]
  float* P   = ws + 10485760;              // scratch pool (39,256,064 floats)
  // ---- mamba-phase layout (per batch, reused) ----
  float* XN_     = P;                      // 5,242,880  (LN'd input; dead after in_proj)
  float* SCHUNK_ = P;                      // reuses XN after in_proj
  float* ZB_     = P + 5242880;            // 10,485,760 (z; live until gate_rms)
  float* XBC_    = P + 15728640;           // 11,665,408 (xBC|dt; dead after conv/dt)
  float* SPREV_  = P + 15728640;           // reuses XBC
  float* CV_     = P + 27394048;           // 11,534,336 (conv out; Y written in place)
  float* DT_     = P + 38928384;           // 131,072
  float* CA_     = P + 39059456;           // 131,072   (pool ends 39,190,528)
  // ---- transformer-phase layout ----
  float* KPE_  = P;                        // 5,242,880
  float* T0_   = P + 5242880;              // [2][16384][160]
  float* T1_   = P + 15728640;             // [2][16384][160]
  float* T2_   = P + 26214400;             // [2][16384][160]
  float* PART_ = P + 36700160;             // [2][24][64][42] = 129,024
  float* SM_   = P + 36829184;             // small token buffers
  float* QPE_  = SM_;
  float* QRY_  = SM_ + 3840;
  float* P3_   = SM_ + 7680;
  float* PO_   = SM_ + 19200;
  float* H_    = SM_ + 23040;
  float* Q160_ = SM_ + 35328;
  float* O160_ = SM_ + 37248;
  float* KV_   = SM_ + 39168;

  const long long sIMG160 = (long long)LSEQ * 160;
  const long long sIMG320 = (long long)LSEQ * CDIM;
  const int NOSPLIT = 1 << 30;

  // ======== mamba phase, per batch ========
  for (int b = 0; b < 2; ++b) {
    const float* xb = x + (size_t)b * CDIM * LSEQ;
    float* Kb = R_K + (size_t)b * LSEQ * CDIM;

    tln<<<LSEQ / 32, 256, 0, stream>>>(xb, ln_w, ln_b, XN_);

    // fused in_proj: cols [0,640) -> ZB_ (z), cols [640,1352) -> XBC_ (xBC|dt)
    gemm_bf<<<dim3(22, 128, 1), 256, 0, stream>>>(
        XN_, in_w, nullptr, nullptr, ZB_, XBC_,
        LSEQ, 1352, CDIM, CDIM, DIN, DIN, XBCW, 0, 0, 0);

    dt_kernel<<<LSEQ * NHH / 256, 256, 0, stream>>>(XBC_, dt_bias, DT_);
    conv_kernel<<<LSEQ * CONVD / 256, 256, 0, stream>>>(XBC_, conv_w, conv_b, CV_);

    scan_a<<<dim3(NCHUNK, NHH), 256, 0, stream>>>(CV_, DT_, A_log, SCHUNK_, CA_);
    scan_b<<<dim3(10, NHH), 256, 0, stream>>>(SCHUNK_, CA_, SPREV_);
    scan_c<<<dim3(NCHUNK, NHH), 256, 0, stream>>>(CV_, DT_, CA_, SPREV_, Dp, CV_);

    gate_rms<<<LSEQ, 256, 0, stream>>>(CV_, ZB_, rms_w);

    gemm_bf<<<dim3(5, 128, 1), 256, 0, stream>>>(
        CV_, out_w, nullptr, nullptr, Kb, nullptr,
        LSEQ, CDIM, DIN, YSTR, CDIM, NOSPLIT, 0, 0, 0, 0);
  }

  kpe_kernel<<<LSEQ * 160 / 256, 256, 0, stream>>>(gauss, KPE_);
  point_kernel<<<30, 64, 0, stream>>>(coords, labels, gauss, ptab, QPE_, QRY_);

  // ======== transformer phase, both batches per dispatch ========
  for (int i = 0; i < 2; ++i) {
    const float* saw = sa_w + (size_t)i * 4 * CDIM * CDIM;
    const float* sab = sa_b + (size_t)i * 4 * CDIM;
    smallmm<<<240, 256, 0, stream>>>(QRY_, (i == 0) ? nullptr : QPE_,
                                     saw, sab, P3_, 12, 960, CDIM, 0, 0, 640);
    attn_self<<<dim3(4, 2), 128, 0, stream>>>(P3_, PO_);
    smallmm<<<80, 256, 0, stream>>>(PO_, nullptr, saw + 3 * 102400, sab + 3 * CDIM,
                                    QRY_, 12, CDIM, CDIM, (i == 0) ? 0 : 1, 0, 0);
    ln_rows64<<<12, 64, 0, stream>>>(QRY_, norms_w + (size_t)(i * 4 + 0) * CDIM,
                                     norms_b + (size_t)(i * 4 + 0) * CDIM);

    smallmm<<<40, 256, 0, stream>>>(QRY_, QPE_, t2i_w + (size_t)(i * 3 + 0) * 51200,
                                    t2i_b + (size_t)(i * 3 + 0) * 160, Q160_,
                                    12, 160, CDIM, 0, 0, 160);
    gemm_bf<<<dim3(3, 128, 2), 256, 0, stream>>>(
        R_K, t2i_w + (size_t)(i * 3 + 1) * 51200, t2i_b + (size_t)(i * 3 + 1) * 160,
        KPE_, T0_, nullptr, LSEQ, 160, CDIM, CDIM, 160, NOSPLIT, 0, 0, sIMG320, sIMG160);
    gemm_bf<<<dim3(3, 128, 2), 256, 0, stream>>>(
        R_K, t2i_w + (size_t)(i * 3 + 2) * 51200, t2i_b + (size_t)(i * 3 + 2) * 160,
        nullptr, T1_, nullptr, LSEQ, 160, CDIM, CDIM, 160, NOSPLIT, 0, 0, sIMG320, sIMG160);
    attn_t2i_part<<<dim3(64, 24, 2), 256, 0, stream>>>(Q160_, T0_, T1_, PART_);
    attn_t2i_comb<<<dim3(24, 2), 64, 0, stream>>>(PART_, O160_);
    smallmm<<<80, 256, 0, stream>>>(O160_, nullptr, t2i_ow + (size_t)i * 51200,
                                    t2i_ob + (size_t)i * CDIM, QRY_,
                                    12, CDIM, 160, 1, 0, 0);
    ln_rows64<<<12, 64, 0, stream>>>(QRY_, norms_w + (size_t)(i * 4 + 1) * CDIM,
                                     norms_b + (size_t)(i * 4 + 1) * CDIM);

    smallmm<<<256, 256, 0, stream>>>(QRY_, nullptr, mlp_w1 + (size_t)i * 1024 * CDIM,
                                     mlp_b1 + (size_t)i * 1024, H_, 12, 1024, CDIM, 0, 1, 0);
    smallmm<<<80, 256, 0, stream>>>(H_, nullptr, mlp_w2 + (size_t)i * CDIM * 1024,
                                    mlp_b2 + (size_t)i * CDIM, QRY_, 12, CDIM, 1024, 1, 0, 0);
    ln_rows64<<<12, 64, 0, stream>>>(QRY_, norms_w + (size_t)(i * 4 + 2) * CDIM,
                                     norms_b + (size_t)(i * 4 + 2) * CDIM);

    gemm_bf<<<dim3(3, 128, 2), 256, 0, stream>>>(
        R_K, i2t_w + (size_t)(i * 3 + 0) * 51200, i2t_b + (size_t)(i * 3 + 0) * 160,
        KPE_, T0_, nullptr, LSEQ, 160, CDIM, CDIM, 160, NOSPLIT, 0, 0, sIMG320, sIMG160);
    smallmm<<<80, 256, 0, stream>>>(QRY_, QPE_, i2t_w + (size_t)(i * 3 + 1) * 51200,
                                    i2t_b + (size_t)(i * 3 + 1) * 160, KV_,
                                    12, 320, CDIM, 0, 0, 160);
    attn_i2t<<<dim3(LSEQ / 256, 4, 2), 256, 0, stream>>>(T0_, KV_, T2_);
    gemm_bf<<<dim3(5, 128, 2), 256, 0, stream>>>(
        T2_, i2t_ow + (size_t)i * CDIM * 160, i2t_ob + (size_t)i * CDIM,
        nullptr, R_K, nullptr, LSEQ, CDIM, 160, 160, CDIM, NOSPLIT, 0, 1,
        sIMG160, sIMG320);
    ln_rows64<<<2 * LSEQ, 64, 0, stream>>>(R_K, norms_w + (size_t)(i * 4 + 3) * CDIM,
                                           norms_b + (size_t)(i * 4 + 3) * CDIM);
  }

  for (int b = 0; b < 2; ++b) {
    ktranspose<<<dim3(10, 512), dim3(32, 8), 0, stream>>>(
        R_K + (size_t)b * LSEQ * CDIM, out + (size_t)b * CDIM * LSEQ, LSEQ, CDIM);
  }
}

// Round 2
// 1409.074 us; speedup vs baseline: 1.2519x; 1.0362x over previous
//
#include <hip/hip_runtime.h>
#include <math.h>

#define LSEQ 16384
#define CDIM 320
#define DIN 640
#define NHH 8
#define CONVD 704
#define XBCW 712
#define YSTR 704
#define QCH 64
#define NCHUNK 256

typedef __bf16 bf16_t;
typedef __bf16 bf16x8 __attribute__((ext_vector_type(8)));
typedef float f32x4 __attribute__((ext_vector_type(4)));

// ---------------- reduction helpers ----------------
__device__ __forceinline__ float wave_sum(float v) {
#pragma unroll
  for (int o = 32; o > 0; o >>= 1) v += __shfl_down(v, o, 64);
  return v;
}
__device__ __forceinline__ float wave_max(float v) {
#pragma unroll
  for (int o = 32; o > 0; o >>= 1) v = fmaxf(v, __shfl_down(v, o, 64));
  return v;
}
__device__ __forceinline__ float block_sum256(float v, float* red) {
  int tid = threadIdx.x;
  v = wave_sum(v);
  __syncthreads();
  if ((tid & 63) == 0) red[tid >> 6] = v;
  __syncthreads();
  return red[0] + red[1] + red[2] + red[3];
}
__device__ __forceinline__ float block_max256(float v, float* red) {
  int tid = threadIdx.x;
  v = wave_max(v);
  __syncthreads();
  if ((tid & 63) == 0) red[tid >> 6] = v;
  __syncthreads();
  return fmaxf(fmaxf(red[0], red[1]), fmaxf(red[2], red[3]));
}

__global__ void ws_probe(float* out, float v) { out[0] = v; }

// -------- fused transpose + layernorm: x[b] (C,L) -> out (L,C), LN over C ----
__global__ __launch_bounds__(256) void tln(const float* __restrict__ x,
                                           const float* __restrict__ w,
                                           const float* __restrict__ b,
                                           float* __restrict__ out) {
  __shared__ float sT[32][321];
  int t0 = blockIdx.x * 32;
  int tid = threadIdx.x;
  for (int i = tid; i < 2560; i += 256) {
    int c = i >> 3, j4 = i & 7;
    float4 v = *(const float4*)(x + (size_t)c * LSEQ + t0 + j4 * 4);
    sT[j4 * 4 + 0][c] = v.x;
    sT[j4 * 4 + 1][c] = v.y;
    sT[j4 * 4 + 2][c] = v.z;
    sT[j4 * 4 + 3][c] = v.w;
  }
  __syncthreads();
  int wave = tid >> 6, lane = tid & 63;
  for (int tt = wave; tt < 32; tt += 4) {
    float xv[5];
    float s = 0.f;
#pragma unroll
    for (int k = 0; k < 5; ++k) { xv[k] = sT[tt][lane + 64 * k]; s += xv[k]; }
    s = wave_sum(s); s = __shfl(s, 0, 64);
    float mean = s * (1.f / 320.f);
    float v = 0.f;
#pragma unroll
    for (int k = 0; k < 5; ++k) { float d = xv[k] - mean; v += d * d; }
    v = wave_sum(v); v = __shfl(v, 0, 64);
    float rstd = rsqrtf(v * (1.f / 320.f) + 1e-5f);
    float* op = out + (size_t)(t0 + tt) * CDIM;
#pragma unroll
    for (int k = 0; k < 5; ++k) {
      int i = lane + 64 * k;
      op[i] = (xv[k] - mean) * rstd * w[i] + b[i];
    }
  }
}

// -------- fused layernorm + transpose: in (L,C) -> out (C,L), LN over C ------
__global__ __launch_bounds__(256) void lnt(const float* __restrict__ in,
                                           const float* __restrict__ w,
                                           const float* __restrict__ b,
                                           float* __restrict__ out) {
  __shared__ float sT[CDIM][33];
  int t0 = blockIdx.x * 32;
  int tid = threadIdx.x;
  int wave = tid >> 6, lane = tid & 63;
  for (int tt = wave; tt < 32; tt += 4) {
    const float* xp = in + (size_t)(t0 + tt) * CDIM;
    float x[5];
    float s = 0.f;
#pragma unroll
    for (int k = 0; k < 5; ++k) { x[k] = xp[lane + 64 * k]; s += x[k]; }
    s = wave_sum(s); s = __shfl(s, 0, 64);
    float mean = s * (1.f / 320.f);
    float v = 0.f;
#pragma unroll
    for (int k = 0; k < 5; ++k) { float d = x[k] - mean; v += d * d; }
    v = wave_sum(v); v = __shfl(v, 0, 64);
    float rstd = rsqrtf(v * (1.f / 320.f) + 1e-5f);
#pragma unroll
    for (int k = 0; k < 5; ++k) {
      int i = lane + 64 * k;
      sT[i][tt] = (x[k] - mean) * rstd * w[i] + b[i];
    }
  }
  __syncthreads();
  for (int i = tid; i < 320 * 32; i += 256) {
    int cc = i >> 5, t = i & 31;
    out[(size_t)cc * LSEQ + t0 + t] = sT[cc][t];
  }
}

// ---------------- layernorm rows (D=320), one wave per row, 4 rows/block -----
__global__ __launch_bounds__(256) void ln_rows256(float* __restrict__ io,
                                                  const float* __restrict__ w,
                                                  const float* __restrict__ b,
                                                  int nrows) {
  int row = blockIdx.x * 4 + (threadIdx.x >> 6);
  if (row >= nrows) return;
  float* xp = io + (size_t)row * CDIM;
  int lane = threadIdx.x & 63;
  float x[5];
  float s = 0.f;
#pragma unroll
  for (int k = 0; k < 5; ++k) { x[k] = xp[lane + 64 * k]; s += x[k]; }
  s = wave_sum(s); s = __shfl(s, 0, 64);
  float mean = s * (1.f / 320.f);
  float v = 0.f;
#pragma unroll
  for (int k = 0; k < 5; ++k) { float t = x[k] - mean; v += t * t; }
  v = wave_sum(v); v = __shfl(v, 0, 64);
  float rstd = rsqrtf(v * (1.f / 320.f) + 1e-5f);
#pragma unroll
  for (int k = 0; k < 5; ++k) {
    int i = lane + 64 * k;
    xp[i] = (x[k] - mean) * rstd * w[i] + b[i];
  }
}

// ------------- bf16 MFMA GEMM, 128x64 tile, XCD-chunked swizzle --------------
// C[..] = (A (+pe)) @ W^T (+bias) (+=C).  Optional column split at nsplit:
// cols [0,nsplit) -> C (ld=ldc), cols [nsplit,N) -> C2 (ld=ldc2).
__global__ __launch_bounds__(256) void gemm_bf(
    const float* __restrict__ A, const float* __restrict__ W,
    const float* __restrict__ bias, const float* __restrict__ pe,
    float* __restrict__ C, float* __restrict__ C2,
    int M, int N, int K, int lda, int ldc, int nsplit, int ldc2,
    int addC, long long sA, long long sC) {
  int z = blockIdx.z;
  A += (size_t)z * sA;
  C += (size_t)z * sC;
  // bijective XCD-chunked swizzle: XCD k owns a contiguous range of tiles
  int gx = gridDim.x;
  int nwg = gx * gridDim.y;
  int lin = blockIdx.y * gx + blockIdx.x;
  int xcd = lin & 7, idx = lin >> 3;
  int q = nwg >> 3, r = nwg & 7;
  int base = (xcd < r) ? xcd * (q + 1) : r * (q + 1) + (xcd - r) * q;
  int lin2 = base + idx;
  int mblk = lin2 / gx, nblk = lin2 % gx;
  int m0 = mblk << 7, n0 = nblk << 6;

  __shared__ __align__(16) bf16_t As[2][4096];  // 8 groups of 16 rows x 32 k
  __shared__ __align__(16) bf16_t Ws[2][2048];  // 4 groups
  int tid = threadIdx.x;
  int wave = tid >> 6, lane = tid & 63;
  int fm = lane & 15, quad = lane >> 4;
  // staging mapping
  int rA = tid >> 1, hA = tid & 1;  // A row (0..127), col-half (16 floats)
  int rW = tid >> 2, qW = tid & 3;  // W row (0..63), col-quad (8 floats)
  const float* ag = A + (size_t)(m0 + rA) * lda + hA * 16;
  const float* peg = pe ? pe + (size_t)(m0 + rA) * lda + hA * 16 : (const float*)0;
  int wRow = n0 + rW;
  const float* wg = W + (size_t)wRow * K + qW * 8;
  bool wok = wRow < N;
  int aoff = (rA >> 4) * 512 + (hA * 32 + (rA & 15)) * 8;
  int woff = (rW >> 4) * 512 + (qW * 16 + (rW & 15)) * 8;

  f32x4 acc[2][4];
#pragma unroll
  for (int i = 0; i < 2; ++i)
#pragma unroll
    for (int j = 0; j < 4; ++j) acc[i][j] = (f32x4){0.f, 0.f, 0.f, 0.f};

  float4 pa0, pa1, pa2, pa3, pw0, pw1;
  auto loadG = [&](int k0) {
    pa0 = *(const float4*)(ag + k0);
    pa1 = *(const float4*)(ag + k0 + 4);
    pa2 = *(const float4*)(ag + k0 + 8);
    pa3 = *(const float4*)(ag + k0 + 12);
    if (peg) {
      float4 q0 = *(const float4*)(peg + k0);
      float4 q1 = *(const float4*)(peg + k0 + 4);
      float4 q2 = *(const float4*)(peg + k0 + 8);
      float4 q3 = *(const float4*)(peg + k0 + 12);
      pa0.x += q0.x; pa0.y += q0.y; pa0.z += q0.z; pa0.w += q0.w;
      pa1.x += q1.x; pa1.y += q1.y; pa1.z += q1.z; pa1.w += q1.w;
      pa2.x += q2.x; pa2.y += q2.y; pa2.z += q2.z; pa2.w += q2.w;
      pa3.x += q3.x; pa3.y += q3.y; pa3.z += q3.z; pa3.w += q3.w;
    }
    pw0 = make_float4(0.f, 0.f, 0.f, 0.f);
    pw1 = pw0;
    if (wok) {
      pw0 = *(const float4*)(wg + k0);
      pw1 = *(const float4*)(wg + k0 + 4);
    }
  };
  auto packLDS = [&](int buf) {
    bf16x8 v;
    v[0] = (bf16_t)pa0.x; v[1] = (bf16_t)pa0.y; v[2] = (bf16_t)pa0.z; v[3] = (bf16_t)pa0.w;
    v[4] = (bf16_t)pa1.x; v[5] = (bf16_t)pa1.y; v[6] = (bf16_t)pa1.z; v[7] = (bf16_t)pa1.w;
    *(bf16x8*)&As[buf][aoff] = v;
    v[0] = (bf16_t)pa2.x; v[1] = (bf16_t)pa2.y; v[2] = (bf16_t)pa2.z; v[3] = (bf16_t)pa2.w;
    v[4] = (bf16_t)pa3.x; v[5] = (bf16_t)pa3.y; v[6] = (bf16_t)pa3.z; v[7] = (bf16_t)pa3.w;
    *(bf16x8*)&As[buf][aoff + 128] = v;
    v[0] = (bf16_t)pw0.x; v[1] = (bf16_t)pw0.y; v[2] = (bf16_t)pw0.z; v[3] = (bf16_t)pw0.w;
    v[4] = (bf16_t)pw1.x; v[5] = (bf16_t)pw1.y; v[6] = (bf16_t)pw1.z; v[7] = (bf16_t)pw1.w;
    *(bf16x8*)&Ws[buf][woff] = v;
  };

  int nk = K >> 5;
  loadG(0);
  packLDS(0);
  __syncthreads();
  for (int i = 0; i < nk; ++i) {
    int buf = i & 1;
    bool more = (i + 1 < nk);
    if (more) loadG((i + 1) << 5);
    int ab = wave * 1024 + lane * 8;
    bf16x8 af0 = *(bf16x8*)&As[buf][ab];
    bf16x8 af1 = *(bf16x8*)&As[buf][ab + 512];
    bf16x8 b0 = *(bf16x8*)&Ws[buf][lane * 8];
    bf16x8 b1 = *(bf16x8*)&Ws[buf][512 + lane * 8];
    bf16x8 b2 = *(bf16x8*)&Ws[buf][1024 + lane * 8];
    bf16x8 b3 = *(bf16x8*)&Ws[buf][1536 + lane * 8];
    acc[0][0] = __builtin_amdgcn_mfma_f32_16x16x32_bf16(af0, b0, acc[0][0], 0, 0, 0);
    acc[0][1] = __builtin_amdgcn_mfma_f32_16x16x32_bf16(af0, b1, acc[0][1], 0, 0, 0);
    acc[0][2] = __builtin_amdgcn_mfma_f32_16x16x32_bf16(af0, b2, acc[0][2], 0, 0, 0);
    acc[0][3] = __builtin_amdgcn_mfma_f32_16x16x32_bf16(af0, b3, acc[0][3], 0, 0, 0);
    acc[1][0] = __builtin_amdgcn_mfma_f32_16x16x32_bf16(af1, b0, acc[1][0], 0, 0, 0);
    acc[1][1] = __builtin_amdgcn_mfma_f32_16x16x32_bf16(af1, b1, acc[1][1], 0, 0, 0);
    acc[1][2] = __builtin_amdgcn_mfma_f32_16x16x32_bf16(af1, b2, acc[1][2], 0, 0, 0);
    acc[1][3] = __builtin_amdgcn_mfma_f32_16x16x32_bf16(af1, b3, acc[1][3], 0, 0, 0);
    if (more) {
      packLDS(buf ^ 1);
      __syncthreads();
    }
  }
#pragma unroll
  for (int ms = 0; ms < 2; ++ms)
#pragma unroll
    for (int ns = 0; ns < 4; ++ns) {
      int n = n0 + ns * 16 + fm;
      if (n >= N) continue;
      float bv = bias ? bias[n] : 0.f;
      float* Cb;
      int ldcb, nc;
      if (n < nsplit) { Cb = C; ldcb = ldc; nc = n; }
      else           { Cb = C2; ldcb = ldc2; nc = n - nsplit; }
#pragma unroll
      for (int rr = 0; rr < 4; ++rr) {
        int m = m0 + wave * 32 + ms * 16 + quad * 4 + rr;
        float v = acc[ms][ns][rr] + bv;
        size_t off = (size_t)m * ldcb + nc;
        if (addC) v += Cb[off];
        Cb[off] = v;
      }
    }
}

// -------- small matmul (token side), wave-per-output-column ------------------
__global__ __launch_bounds__(256) void smallmm(
    const float* __restrict__ A, const float* __restrict__ A2,
    const float* __restrict__ W, const float* __restrict__ bias,
    float* __restrict__ C, int M, int N, int K, int addC, int relu, int a2lim) {
  int wave = threadIdx.x >> 6, lane = threadIdx.x & 63;
  int n = blockIdx.x * 4 + wave;
  if (n >= N) return;
  const float* w = W + (size_t)n * K;
  float wreg[16];
  int nu = (K + 63) >> 6;
#pragma unroll 4
  for (int u = 0; u < nu; ++u) {
    int k = lane + (u << 6);
    wreg[u] = (k < K) ? w[k] : 0.f;
  }
  bool useA2 = (A2 != nullptr) && (n < a2lim);
  float part[12];
  for (int m = 0; m < M; ++m) part[m] = 0.f;
  for (int u = 0; u < nu; ++u) {
    int k = lane + (u << 6);
    if (k < K) {
      float wv = wreg[u];
      for (int m = 0; m < M; ++m) {
        float av = A[(size_t)m * K + k];
        if (useA2) av += A2[(size_t)m * K + k];
        part[m] += av * wv;
      }
    }
  }
  float bv = bias ? bias[n] : 0.f;
  for (int m = 0; m < M; ++m) {
    float dot = wave_sum(part[m]);
    if (lane == 0) {
      float v = dot + bv;
      if (relu) v = fmaxf(v, 0.f);
      size_t off = (size_t)m * N + n;
      if (addC) v += C[off];
      C[off] = v;
    }
  }
}

// ---------------- dt = softplus(dt_raw + dt_bias), layout (h,t) --------------
__global__ void dt_kernel(const float* __restrict__ XBC, const float* __restrict__ dt_bias,
                          float* __restrict__ dtbuf) {
  int idx = blockIdx.x * 256 + threadIdx.x;
  if (idx >= LSEQ * NHH) return;
  int h = idx & 7;
  int t = idx >> 3;
  float v = XBC[(size_t)t * XBCW + 704 + h] + dt_bias[h];
  float sp = (v > 20.f) ? v : log1pf(expf(v));
  dtbuf[(size_t)h * LSEQ + t] = sp;
}

// ------- causal depthwise conv + silu, sliding-window registers --------------
// grid (11, 128): lane owns channel d = bx*64+lane, wave owns 32 t's.
__global__ __launch_bounds__(256) void conv2(const float* __restrict__ XBC,
                                             const float* __restrict__ conv_w,
                                             const float* __restrict__ conv_b,
                                             float* __restrict__ Cv) {
  int lane = threadIdx.x & 63, wv = threadIdx.x >> 6;
  int d = blockIdx.x * 64 + lane;
  int t0 = (blockIdx.y * 4 + wv) * 32;
  float w0 = conv_w[d * 4 + 0], w1 = conv_w[d * 4 + 1];
  float w2 = conv_w[d * 4 + 2], w3 = conv_w[d * 4 + 3];
  float bv = conv_b[d];
  const float* src = XBC + d;
  float xm3, xm2, xm1;
  if (t0 == 0) {
    xm3 = 0.f; xm2 = 0.f; xm1 = 0.f;
  } else {
    xm3 = src[(size_t)(t0 - 3) * XBCW];
    xm2 = src[(size_t)(t0 - 2) * XBCW];
    xm1 = src[(size_t)(t0 - 1) * XBCW];
  }
#pragma unroll 8
  for (int t = t0; t < t0 + 32; ++t) {
    float xt = src[(size_t)t * XBCW];
    float a = bv + xm3 * w0 + xm2 * w1 + xm1 * w2 + xt * w3;
    Cv[(size_t)t * CONVD + d] = a / (1.f + expf(-a));
    xm3 = xm2; xm2 = xm1; xm1 = xt;
  }
}

// ---------------- scan phase A: per-chunk states + cumulative log-decay ------
__global__ __launch_bounds__(256) void scan_a(const float* __restrict__ Cv,
                                              const float* __restrict__ dtbuf,
                                              const float* __restrict__ A_log,
                                              float* __restrict__ Schunk,
                                              float* __restrict__ cabuf) {
  int c = blockIdx.x, h = blockIdx.y;
  int t0 = c * QCH;
  __shared__ float sdt[64], sca[64], sw[64];
  __shared__ __align__(16) float sB[64][36];
  __shared__ __align__(16) float sXt[80][68];
  int tid = threadIdx.x;
  float Aval = -expf(A_log[h]);
  if (tid < 64) sdt[tid] = dtbuf[(size_t)h * LSEQ + t0 + tid];
  __syncthreads();
  if (tid == 0) {
    float run = 0.f;
    for (int j = 0; j < 64; ++j) { run += sdt[j] * Aval; sca[j] = run; }
  }
  __syncthreads();
  float caend = sca[63];
  if (tid < 64) {
    sw[tid] = expf(caend - sca[tid]) * sdt[tid];
    cabuf[(size_t)h * LSEQ + t0 + tid] = sca[tid];
  }
  for (int i = tid; i < 2048; i += 256) {
    int j = i >> 5, n = i & 31;
    sB[j][n] = Cv[(size_t)(t0 + j) * CONVD + 640 + n];
  }
  for (int i = tid; i < 5120; i += 256) {
    int j = i / 80, p = i % 80;
    sXt[p][j] = Cv[(size_t)(t0 + j) * CONVD + h * 80 + p];
  }
  __syncthreads();
  int n = tid >> 3, pb = tid & 7;
  float acc[10];
#pragma unroll
  for (int u = 0; u < 10; ++u) acc[u] = 0.f;
  for (int jb = 0; jb < 16; ++jb) {
    float wB[4];
#pragma unroll
    for (int jj = 0; jj < 4; ++jj) {
      int j = jb * 4 + jj;
      wB[jj] = sw[j] * sB[j][n];
    }
#pragma unroll
    for (int u = 0; u < 10; ++u) {
      int p = pb * 10 + u;
      float4 x4 = *(const float4*)&sXt[p][jb * 4];
      acc[u] += wB[0] * x4.x + wB[1] * x4.y + wB[2] * x4.z + wB[3] * x4.w;
    }
  }
  float* outp = Schunk + (size_t)(h * NCHUNK + c) * 2560;
#pragma unroll
  for (int u = 0; u < 10; ++u) outp[n * 80 + pb * 10 + u] = acc[u];
}

// ---------------- scan phase B: sequential over chunks, 80 blocks ------------
__global__ __launch_bounds__(256) void scan_b(const float* __restrict__ Schunk,
                                              const float* __restrict__ cabuf,
                                              float* __restrict__ Sprev) {
  int pc = blockIdx.x, h = blockIdx.y;
  __shared__ float sdec[256];
  int tid = threadIdx.x;
  sdec[tid] = expf(cabuf[(size_t)h * LSEQ + tid * 64 + 63]);
  __syncthreads();
  int e = pc * 256 + tid;
  const float* base = Schunk + (size_t)h * NCHUNK * 2560 + e;
  float* pbase = Sprev + (size_t)h * NCHUNK * 2560 + e;
  float s = 0.f;
  float v = base[0];
  for (int c = 0; c < NCHUNK; ++c) {
    float vn = (c < NCHUNK - 1) ? base[(size_t)(c + 1) * 2560] : 0.f;
    pbase[(size_t)c * 2560] = s;
    s = s * sdec[c] + v;
    v = vn;
  }
}

// ---------------- scan phase C: MFMA version; Y written IN-PLACE over the ----
// ---------------- X-portion of Cv (stride YSTR=704, cols 0..640) ------------
__global__ __launch_bounds__(256) void scan_c(const float* __restrict__ Cv,
                                              const float* __restrict__ dtbuf,
                                              const float* __restrict__ cabuf,
                                              const float* __restrict__ Sprev,
                                              const float* __restrict__ Dp,
                                              float* __restrict__ Y) {
  int c = blockIdx.x, h = blockIdx.y;
  int t0 = c * QCH;
  __shared__ float sdt[64], sca[64], sexp[64];
  __shared__ __align__(16) bf16_t sC[64 * 40];   // C[j][n], stride 40
  __shared__ __align__(16) bf16_t sB[64 * 40];   // B[s][n], stride 40
  __shared__ __align__(16) bf16_t sXt[80 * 72];  // X^T [p][j], stride 72
  __shared__ __align__(16) bf16_t sSt[80 * 40];  // Sprev^T [p][n], stride 40
  __shared__ __align__(16) bf16_t sP[64 * 72];   // scores [j][s], stride 72
  int tid = threadIdx.x;
  int wave = tid >> 6, lane = tid & 63;
  int fm = lane & 15, quad = lane >> 4;
  if (tid < 64) {
    sdt[tid] = dtbuf[(size_t)h * LSEQ + t0 + tid];
    float cav = cabuf[(size_t)h * LSEQ + t0 + tid];
    sca[tid] = cav;
    sexp[tid] = expf(cav);
  }
  for (int i = tid; i < 2048; i += 256) {
    int j = i >> 5, n = i & 31;
    size_t base = (size_t)(t0 + j) * CONVD;
    sB[j * 40 + n] = (bf16_t)Cv[base + 640 + n];
    sC[j * 40 + n] = (bf16_t)Cv[base + 672 + n];
  }
  for (int i = tid; i < 5120; i += 256) {
    int j = i / 80, p = i % 80;
    sXt[p * 72 + j] = (bf16_t)Cv[(size_t)(t0 + j) * CONVD + h * 80 + p];
  }
  {
    const float* sp = Sprev + (size_t)(h * NCHUNK + c) * 2560;
    for (int i = tid; i < 2560; i += 256) {
      int n = i / 80, p = i % 80;
      sSt[p * 40 + n] = (bf16_t)sp[i];
    }
  }
  __syncthreads();
  int m0 = wave * 16;
  int jbase = m0 + quad * 4;
  bf16x8 afC = *(bf16x8*)&sC[(m0 + fm) * 40 + quad * 8];
  f32x4 accS[4];
#pragma unroll
  for (int nt = 0; nt < 4; ++nt) {
    bf16x8 bf = *(bf16x8*)&sB[(nt * 16 + fm) * 40 + quad * 8];
    f32x4 zero = (f32x4){0.f, 0.f, 0.f, 0.f};
    accS[nt] = __builtin_amdgcn_mfma_f32_16x16x32_bf16(afC, bf, zero, 0, 0, 0);
  }
  float scaj[4];
#pragma unroll
  for (int r = 0; r < 4; ++r) scaj[r] = sca[jbase + r];
#pragma unroll
  for (int nt = 0; nt < 4; ++nt) {
    int s = nt * 16 + fm;
    float dts = sdt[s], scas = sca[s];
#pragma unroll
    for (int r = 0; r < 4; ++r) {
      int j = jbase + r;
      float v = 0.f;
      if (s <= j) v = accS[nt][r] * dts * expf(scaj[r] - scas);
      sP[j * 72 + s] = (bf16_t)v;
    }
  }
  f32x4 acc[5];
#pragma unroll
  for (int pt = 0; pt < 5; ++pt) {
    bf16x8 bf = *(bf16x8*)&sSt[(pt * 16 + fm) * 40 + quad * 8];
    f32x4 zero = (f32x4){0.f, 0.f, 0.f, 0.f};
    acc[pt] = __builtin_amdgcn_mfma_f32_16x16x32_bf16(afC, bf, zero, 0, 0, 0);
  }
  float gj[4];
#pragma unroll
  for (int r = 0; r < 4; ++r) gj[r] = sexp[jbase + r];
#pragma unroll
  for (int pt = 0; pt < 5; ++pt)
#pragma unroll
    for (int r = 0; r < 4; ++r) acc[pt][r] *= gj[r];
  bf16x8 afP0 = *(bf16x8*)&sP[(m0 + fm) * 72 + 0 + quad * 8];
  bf16x8 afP1 = *(bf16x8*)&sP[(m0 + fm) * 72 + 32 + quad * 8];
#pragma unroll
  for (int pt = 0; pt < 5; ++pt) {
    bf16x8 bx0 = *(bf16x8*)&sXt[(pt * 16 + fm) * 72 + 0 + quad * 8];
    bf16x8 bx1 = *(bf16x8*)&sXt[(pt * 16 + fm) * 72 + 32 + quad * 8];
    acc[pt] = __builtin_amdgcn_mfma_f32_16x16x32_bf16(afP0, bx0, acc[pt], 0, 0, 0);
    acc[pt] = __builtin_amdgcn_mfma_f32_16x16x32_bf16(afP1, bx1, acc[pt], 0, 0, 0);
  }
  float dval = Dp[h];
#pragma unroll
  for (int pt = 0; pt < 5; ++pt) {
    int p = pt * 16 + fm;
#pragma unroll
    for (int r = 0; r < 4; ++r) {
      int j = jbase + r;
      float xv = (float)sXt[p * 72 + j];
      Y[(size_t)(t0 + j) * YSTR + h * 80 + p] = acc[pt][r] + dval * xv;
    }
  }
}

// ------------- y *= silu(z); rmsnorm * rms_w  (Y stride YSTR) ----------------
__global__ __launch_bounds__(256) void gate_rms(float* __restrict__ Y,
                                                const float* __restrict__ Z,
                                                const float* __restrict__ rms_w) {
  __shared__ float red[4];
  size_t row = blockIdx.x;
  float* y = Y + row * YSTR;
  const float* z = Z + row * DIN;
  float ss = 0.f;
  for (int i = threadIdx.x; i < DIN; i += 256) {
    float zi = z[i];
    float g = y[i] * (zi / (1.f + expf(-zi)));
    y[i] = g;
    ss += g * g;
  }
  float tot = block_sum256(ss, red);
  float r = rsqrtf(tot / (float)DIN + 1e-5f);
  for (int i = threadIdx.x; i < DIN; i += 256) y[i] = y[i] * r * rms_w[i];
}

// ---------------- dense image PE ----------------
__global__ void kpe_kernel(const float* __restrict__ gauss, float* __restrict__ KPE) {
  int idx = blockIdx.x * 256 + threadIdx.x;
  if (idx >= LSEQ * 160) return;
  int f = idx % 160, t = idx / 160;
  int d = t >> 10, hh = (t >> 5) & 31, w = t & 31;
  float vx = 2.f * ((d + 0.5f) / 16.f) - 1.f;
  float vy = 2.f * ((hh + 0.5f) / 32.f) - 1.f;
  float vz = 2.f * ((w + 0.5f) / 32.f) - 1.f;
  float cc = 6.28318530717958647692f * (vx * gauss[f] + vy * gauss[160 + f] + vz * gauss[320 + f]);
  KPE[(size_t)t * CDIM + f] = sinf(cc);
  KPE[(size_t)t * CDIM + 160 + f] = cosf(cc);
}

// ---------------- point embeddings (both batches: 12 points) -----------------
__global__ void point_kernel(const float* __restrict__ coords, const int* __restrict__ labels,
                             const float* __restrict__ gauss, const float* __restrict__ ptab,
                             float* __restrict__ qpe, float* __restrict__ queries) {
  int idx = blockIdx.x * 64 + threadIdx.x;
  if (idx >= 12 * 160) return;
  int f = idx % 160, pt = idx / 160;
  const float* co = coords + pt * 3;
  float vx = 2.f * (co[0] / 128.f) - 1.f;
  float vy = 2.f * (co[1] / 256.f) - 1.f;
  float vz = 2.f * (co[2] / 256.f) - 1.f;
  float cc = 6.28318530717958647692f * (vx * gauss[f] + vy * gauss[160 + f] + vz * gauss[320 + f]);
  int lab = labels[pt];
  float sv = sinf(cc) + ptab[lab * CDIM + f];
  float cv = cosf(cc) + ptab[lab * CDIM + 160 + f];
  qpe[pt * CDIM + f] = sv;       qpe[pt * CDIM + 160 + f] = cv;
  queries[pt * CDIM + f] = sv;   queries[pt * CDIM + 160 + f] = cv;
}

// --------- self-attn over 6 tokens from fused P3[12][960], grid (4,2) --------
__global__ void attn_self(const float* __restrict__ P3, float* __restrict__ O) {
  int h = blockIdx.x, b = blockIdx.y;
  __shared__ float sq[6][80], sk[6][80], sv[6][80], sw[6][6];
  int tid = threadIdx.x;  // 128
  for (int i = tid; i < 480; i += 128) {
    int tok = i / 80, p = i % 80;
    const float* base = P3 + (size_t)(b * 6 + tok) * 960 + h * 80 + p;
    sq[tok][p] = base[0]; sk[tok][p] = base[320]; sv[tok][p] = base[640];
  }
  __syncthreads();
  if (tid < 36) {
    int qi = tid / 6, ki = tid % 6;
    float d = 0.f;
    for (int p = 0; p < 80; ++p) d += sq[qi][p] * sk[ki][p];
    sw[qi][ki] = d * 0.11180339887498948f;  // 1/sqrt(80)
  }
  __syncthreads();
  if (tid < 6) {
    float mx = sw[tid][0];
    for (int k = 1; k < 6; ++k) mx = fmaxf(mx, sw[tid][k]);
    float s = 0.f;
    for (int k = 0; k < 6; ++k) { float e = expf(sw[tid][k] - mx); sw[tid][k] = e; s += e; }
    float inv = 1.f / s;
    for (int k = 0; k < 6; ++k) sw[tid][k] *= inv;
  }
  __syncthreads();
  for (int i = tid; i < 480; i += 128) {
    int qi = i / 80, p = i % 80;
    float o = 0.f;
    for (int k = 0; k < 6; ++k) o += sw[qi][k] * sv[k][p];
    O[(size_t)(b * 6 + qi) * CDIM + h * 80 + p] = o;
  }
}

// ------------- t2i attention pass 1: all 6 queries per block -----------------
// grid (64 chunks, 4 h, 2 b): K/V read exactly once.
__global__ __launch_bounds__(256) void attn_t2i_part2(const float* __restrict__ Qp,
                                                      const float* __restrict__ Kp,
                                                      const float* __restrict__ Vp,
                                                      float* __restrict__ Part) {
  int b = blockIdx.z, h = blockIdx.y, c = blockIdx.x;
  Qp += (size_t)b * 960;
  Kp += (size_t)b * LSEQ * 160;
  Vp += (size_t)b * LSEQ * 160;
  Part += (size_t)b * 24 * 64 * 42;
  __shared__ __align__(16) float sq[6][40];
  __shared__ float red[4];
  __shared__ float sOp[4][40];
  int tid = threadIdx.x;
  if (tid < 240) {
    int qi = tid / 40, p = tid % 40;
    sq[qi][p] = Qp[(size_t)qi * 160 + h * 40 + p];
  }
  __syncthreads();
  int t = c * 256 + tid;
  const float* kp = Kp + (size_t)t * 160 + h * 40;
  float kr[40];
#pragma unroll
  for (int v = 0; v < 10; ++v) {
    float4 k4 = *(const float4*)(kp + v * 4);
    kr[v * 4 + 0] = k4.x; kr[v * 4 + 1] = k4.y; kr[v * 4 + 2] = k4.z; kr[v * 4 + 3] = k4.w;
  }
  const float* vp = Vp + (size_t)t * 160 + h * 40;
  float vr[40];
#pragma unroll
  for (int v = 0; v < 10; ++v) {
    float4 v4 = *(const float4*)(vp + v * 4);
    vr[v * 4 + 0] = v4.x; vr[v * 4 + 1] = v4.y; vr[v * 4 + 2] = v4.z; vr[v * 4 + 3] = v4.w;
  }
  float s[6];
#pragma unroll
  for (int qi = 0; qi < 6; ++qi) {
    float d = 0.f;
#pragma unroll
    for (int p = 0; p < 40; ++p) d += sq[qi][p] * kr[p];
    s[qi] = d * 0.15811388300841897f;  // 1/sqrt(40)
  }
  int wave = tid >> 6, lane = tid & 63;
  for (int qi = 0; qi < 6; ++qi) {
    float gmax = block_max256(s[qi], red);
    float e = expf(s[qi] - gmax);
    float ls = block_sum256(e, red);
#pragma unroll
    for (int p = 0; p < 40; ++p) {
      float v = wave_sum(e * vr[p]);
      if (lane == 0) sOp[wave][p] = v;
    }
    __syncthreads();
    float* part = Part + (size_t)((h * 6 + qi) * 64 + c) * 42;
    if (tid == 0) { part[40] = gmax; part[41] = ls; }
    if (tid < 40) part[tid] = sOp[0][tid] + sOp[1][tid] + sOp[2][tid] + sOp[3][tid];
    __syncthreads();
  }
}

// ------------- t2i attention pass 2: combine 64 partials, grid (24,2) --------
__global__ void attn_t2i_comb(const float* __restrict__ Part, float* __restrict__ O) {
  int b = blockIdx.y;
  int blk = blockIdx.x;  // h*6 + qi
  int qi = blk % 6;
  int h = blk / 6;
  int j = threadIdx.x;  // 64
  const float* part = Part + (size_t)b * 24 * 64 * 42 + (size_t)(blk * 64 + j) * 42;
  float m = part[40], l = part[41];
  float gmax = wave_max(m);
  gmax = __shfl(gmax, 0, 64);
  float sc = expf(m - gmax);
  float tot = wave_sum(l * sc);
  tot = __shfl(tot, 0, 64);
  float inv = 1.f / tot;
  for (int p = 0; p < 40; ++p) {
    float v = wave_sum(part[p] * sc);
    if (j == 0) O[(size_t)b * 960 + (size_t)qi * 160 + h * 40 + p] = v * inv;
  }
}

// ------- i2t attention: 16384 q vs 6 k, KV fused [12][320], grid (64,4,2) ----
__global__ __launch_bounds__(256) void attn_i2t(const float* __restrict__ Qp,
                                                const float* __restrict__ KV,
                                                float* __restrict__ O) {
  int h = blockIdx.y, b = blockIdx.z;
  int t = blockIdx.x * 256 + threadIdx.x;
  Qp += (size_t)b * LSEQ * 160;
  O += (size_t)b * LSEQ * 160;
  __shared__ float sk[6][40], sv[6][40];
  if (threadIdx.x < 240) {
    int tok = threadIdx.x / 40, p = threadIdx.x % 40;
    const float* base = KV + (size_t)(b * 6 + tok) * 320 + h * 40 + p;
    sk[tok][p] = base[0];
    sv[tok][p] = base[160];
  }
  __syncthreads();
  const float* q = Qp + (size_t)t * 160 + h * 40;
  float qr[40];
#pragma unroll
  for (int v = 0; v < 10; ++v) {
    float4 q4 = *(const float4*)(q + v * 4);
    qr[v * 4 + 0] = q4.x; qr[v * 4 + 1] = q4.y; qr[v * 4 + 2] = q4.z; qr[v * 4 + 3] = q4.w;
  }
  float s[6];
#pragma unroll
  for (int k = 0; k < 6; ++k) {
    float d = 0.f;
    for (int p = 0; p < 40; ++p) d += qr[p] * sk[k][p];
    s[k] = d * 0.15811388300841897f;
  }
  float mx = s[0];
#pragma unroll
  for (int k = 1; k < 6; ++k) mx = fmaxf(mx, s[k]);
  float sum = 0.f;
#pragma unroll
  for (int k = 0; k < 6; ++k) { s[k] = expf(s[k] - mx); sum += s[k]; }
  float inv = 1.f / sum;
  float* o = O + (size_t)t * 160 + h * 40;
#pragma unroll
  for (int p = 0; p < 40; ++p) {
    float v = 0.f;
    for (int k = 0; k < 6; ++k) v += s[k] * sv[k][p];
    o[p] = v * inv;
  }
}

// =======================================================================
extern "C" void kernel_launch(void* const* d_in, const int* in_sizes, int n_in,
                              void* d_out, int out_size, void* d_ws, size_t ws_size,
                              hipStream_t stream) {
  (void)in_sizes; (void)n_in; (void)out_size;
  const float* x       = (const float*)d_in[0];
  const float* coords  = (const float*)d_in[1];
  const int*   labels  = (const int*)  d_in[2];
  const float* ln_w    = (const float*)d_in[3];
  const float* ln_b    = (const float*)d_in[4];
  const float* in_w    = (const float*)d_in[5];
  const float* conv_w  = (const float*)d_in[6];
  const float* conv_b  = (const float*)d_in[7];
  const float* dt_bias = (const float*)d_in[8];
  const float* A_log   = (const float*)d_in[9];
  const float* Dp      = (const float*)d_in[10];
  const float* rms_w   = (const float*)d_in[11];
  const float* out_w   = (const float*)d_in[12];
  const float* gauss   = (const float*)d_in[13];
  const float* ptab    = (const float*)d_in[14];
  const float* sa_w    = (const float*)d_in[15];
  const float* sa_b    = (const float*)d_in[16];
  const float* t2i_w   = (const float*)d_in[17];
  const float* t2i_b   = (const float*)d_in[18];
  const float* t2i_ow  = (const float*)d_in[19];
  const float* t2i_ob  = (const float*)d_in[20];
  const float* i2t_w   = (const float*)d_in[21];
  const float* i2t_b   = (const float*)d_in[22];
  const float* i2t_ow  = (const float*)d_in[23];
  const float* i2t_ob  = (const float*)d_in[24];
  const float* norms_w = (const float*)d_in[25];
  const float* norms_b = (const float*)d_in[26];
  const float* mlp_w1  = (const float*)d_in[27];
  const float* mlp_b1  = (const float*)d_in[28];
  const float* mlp_w2  = (const float*)d_in[29];
  const float* mlp_b2  = (const float*)d_in[30];
  float* out = (float*)d_out;
  float* ws = (float*)d_ws;

  const size_t NEED = (size_t)(10485760 + 5242880 + 11665408 + 11534336 + 10485760 +
                               131072 + 131072 + 65536) * 4;
  if (ws_size < NEED) {
    ws_probe<<<1, 1, 0, stream>>>(out, (float)ws_size);
    return;
  }
  float* R_K = ws;                         // [2][16384][320]
  float* P   = ws + 10485760;              // scratch pool
  // ---- mamba-phase layout (per batch, reused) ----
  float* XN_     = P;                      // 5,242,880  (LN'd input; dead after in_proj)
  float* SCHUNK_ = P;                      // reuses XN after in_proj
  float* ZB_     = P + 5242880;            // 10,485,760 (z; live until gate_rms)
  float* XBC_    = P + 15728640;           // 11,665,408 (xBC|dt; dead after conv/dt)
  float* SPREV_  = P + 15728640;           // reuses XBC
  float* CV_     = P + 27394048;           // 11,534,336 (conv out; Y written in place)
  float* DT_     = P + 38928384;           // 131,072
  float* CA_     = P + 39059456;           // 131,072
  // ---- transformer-phase layout ----
  float* KPE_  = P;                        // 5,242,880
  float* T0_   = P + 5242880;              // [2][16384][160]
  float* T1_   = P + 15728640;             // [2][16384][160]
  float* T2_   = P + 26214400;             // [2][16384][160]
  float* PART_ = P + 36700160;             // [2][24][64][42] = 129,024
  float* SM_   = P + 36829184;             // small token buffers
  float* QPE_  = SM_;
  float* QRY_  = SM_ + 3840;
  float* P3_   = SM_ + 7680;
  float* PO_   = SM_ + 19200;
  float* H_    = SM_ + 23040;
  float* Q160_ = SM_ + 35328;
  float* O160_ = SM_ + 37248;
  float* KV_   = SM_ + 39168;

  const long long sIMG160 = (long long)LSEQ * 160;
  const long long sIMG320 = (long long)LSEQ * CDIM;
  const int NOSPLIT = 1 << 30;

  // ======== mamba phase, per batch ========
  for (int b = 0; b < 2; ++b) {
    const float* xb = x + (size_t)b * CDIM * LSEQ;
    float* Kb = R_K + (size_t)b * LSEQ * CDIM;

    tln<<<LSEQ / 32, 256, 0, stream>>>(xb, ln_w, ln_b, XN_);

    // fused in_proj: cols [0,640) -> ZB_ (z), cols [640,1352) -> XBC_ (xBC|dt)
    gemm_bf<<<dim3(22, 128, 1), 256, 0, stream>>>(
        XN_, in_w, nullptr, nullptr, ZB_, XBC_,
        LSEQ, 1352, CDIM, CDIM, DIN, DIN, XBCW, 0, 0, 0);

    dt_kernel<<<LSEQ * NHH / 256, 256, 0, stream>>>(XBC_, dt_bias, DT_);
    conv2<<<dim3(11, 128), 256, 0, stream>>>(XBC_, conv_w, conv_b, CV_);

    scan_a<<<dim3(NCHUNK, NHH), 256, 0, stream>>>(CV_, DT_, A_log, SCHUNK_, CA_);
    scan_b<<<dim3(10, NHH), 256, 0, stream>>>(SCHUNK_, CA_, SPREV_);
    scan_c<<<dim3(NCHUNK, NHH), 256, 0, stream>>>(CV_, DT_, CA_, SPREV_, Dp, CV_);

    gate_rms<<<LSEQ, 256, 0, stream>>>(CV_, ZB_, rms_w);

    gemm_bf<<<dim3(5, 128, 1), 256, 0, stream>>>(
        CV_, out_w, nullptr, nullptr, Kb, nullptr,
        LSEQ, CDIM, DIN, YSTR, CDIM, NOSPLIT, 0, 0, 0, 0);
  }

  kpe_kernel<<<LSEQ * 160 / 256, 256, 0, stream>>>(gauss, KPE_);
  point_kernel<<<30, 64, 0, stream>>>(coords, labels, gauss, ptab, QPE_, QRY_);

  // ======== transformer phase, both batches per dispatch ========
  for (int i = 0; i < 2; ++i) {
    const float* saw = sa_w + (size_t)i * 4 * CDIM * CDIM;
    const float* sab = sa_b + (size_t)i * 4 * CDIM;
    smallmm<<<240, 256, 0, stream>>>(QRY_, (i == 0) ? nullptr : QPE_,
                                     saw, sab, P3_, 12, 960, CDIM, 0, 0, 640);
    attn_self<<<dim3(4, 2), 128, 0, stream>>>(P3_, PO_);
    smallmm<<<80, 256, 0, stream>>>(PO_, nullptr, saw + 3 * 102400, sab + 3 * CDIM,
                                    QRY_, 12, CDIM, CDIM, (i == 0) ? 0 : 1, 0, 0);
    ln_rows256<<<3, 256, 0, stream>>>(QRY_, norms_w + (size_t)(i * 4 + 0) * CDIM,
                                      norms_b + (size_t)(i * 4 + 0) * CDIM, 12);

    smallmm<<<40, 256, 0, stream>>>(QRY_, QPE_, t2i_w + (size_t)(i * 3 + 0) * 51200,
                                    t2i_b + (size_t)(i * 3 + 0) * 160, Q160_,
                                    12, 160, CDIM, 0, 0, 160);
    gemm_bf<<<dim3(3, 128, 2), 256, 0, stream>>>(
        R_K, t2i_w + (size_t)(i * 3 + 1) * 51200, t2i_b + (size_t)(i * 3 + 1) * 160,
        KPE_, T0_, nullptr, LSEQ, 160, CDIM, CDIM, 160, NOSPLIT, 0, 0, sIMG320, sIMG160);
    gemm_bf<<<dim3(3, 128, 2), 256, 0, stream>>>(
        R_K, t2i_w + (size_t)(i * 3 + 2) * 51200, t2i_b + (size_t)(i * 3 + 2) * 160,
        nullptr, T1_, nullptr, LSEQ, 160, CDIM, CDIM, 160, NOSPLIT, 0, 0, sIMG320, sIMG160);
    attn_t2i_part2<<<dim3(64, 4, 2), 256, 0, stream>>>(Q160_, T0_, T1_, PART_);
    attn_t2i_comb<<<dim3(24, 2), 64, 0, stream>>>(PART_, O160_);
    smallmm<<<80, 256, 0, stream>>>(O160_, nullptr, t2i_ow + (size_t)i * 51200,
                                    t2i_ob + (size_t)i * CDIM, QRY_,
                                    12, CDIM, 160, 1, 0, 0);
    ln_rows256<<<3, 256, 0, stream>>>(QRY_, norms_w + (size_t)(i * 4 + 1) * CDIM,
                                      norms_b + (size_t)(i * 4 + 1) * CDIM, 12);

    smallmm<<<256, 256, 0, stream>>>(QRY_, nullptr, mlp_w1 + (size_t)i * 1024 * CDIM,
                                     mlp_b1 + (size_t)i * 1024, H_, 12, 1024, CDIM, 0, 1, 0);
    smallmm<<<80, 256, 0, stream>>>(H_, nullptr, mlp_w2 + (size_t)i * CDIM * 1024,
                                    mlp_b2 + (size_t)i * CDIM, QRY_, 12, CDIM, 1024, 1, 0, 0);
    ln_rows256<<<3, 256, 0, stream>>>(QRY_, norms_w + (size_t)(i * 4 + 2) * CDIM,
                                      norms_b + (size_t)(i * 4 + 2) * CDIM, 12);

    gemm_bf<<<dim3(3, 128, 2), 256, 0, stream>>>(
        R_K, i2t_w + (size_t)(i * 3 + 0) * 51200, i2t_b + (size_t)(i * 3 + 0) * 160,
        KPE_, T0_, nullptr, LSEQ, 160, CDIM, CDIM, 160, NOSPLIT, 0, 0, sIMG320, sIMG160);
    smallmm<<<80, 256, 0, stream>>>(QRY_, QPE_, i2t_w + (size_t)(i * 3 + 1) * 51200,
                                    i2t_b + (size_t)(i * 3 + 1) * 160, KV_,
                                    12, 320, CDIM, 0, 0, 160);
    attn_i2t<<<dim3(LSEQ / 256, 4, 2), 256, 0, stream>>>(T0_, KV_, T2_);
    gemm_bf<<<dim3(5, 128, 2), 256, 0, stream>>>(
        T2_, i2t_ow + (size_t)i * CDIM * 160, i2t_ob + (size_t)i * CDIM,
        nullptr, R_K, nullptr, LSEQ, CDIM, 160, 160, CDIM, NOSPLIT, 0, 1,
        sIMG160, sIMG320);
    if (i == 0) {
      ln_rows256<<<2 * LSEQ / 4, 256, 0, stream>>>(
          R_K, norms_w + (size_t)3 * CDIM, norms_b + (size_t)3 * CDIM, 2 * LSEQ);
    }
  }

  // final layernorm fused with transpose to output layout (C,L)
  for (int b = 0; b < 2; ++b) {
    lnt<<<LSEQ / 32, 256, 0, stream>>>(
        R_K + (size_t)b * LSEQ * CDIM, norms_w + (size_t)7 * CDIM,
        norms_b + (size_t)7 * CDIM, out + (size_t)b * CDIM * LSEQ);
  }
}

// Round 3
// 1298.325 us; speedup vs baseline: 1.3587x; 1.0853x over previous
//
#include <hip/hip_runtime.h>
#include <math.h>

#define LSEQ 16384
#define CDIM 320
#define DIN 640
#define NHH 8
#define CONVD 704
#define XBCW 712
#define YSTR 704
#define QCH 64
#define NCHUNK 256

typedef __bf16 bf16_t;
typedef __bf16 bf16x8 __attribute__((ext_vector_type(8)));
typedef float f32x4 __attribute__((ext_vector_type(4)));

// ---------------- reduction helpers ----------------
__device__ __forceinline__ float wave_sum(float v) {
#pragma unroll
  for (int o = 32; o > 0; o >>= 1) v += __shfl_down(v, o, 64);
  return v;
}
__device__ __forceinline__ float wave_max(float v) {
#pragma unroll
  for (int o = 32; o > 0; o >>= 1) v = fmaxf(v, __shfl_down(v, o, 64));
  return v;
}
__device__ __forceinline__ float block_sum256(float v, float* red) {
  int tid = threadIdx.x;
  v = wave_sum(v);
  __syncthreads();
  if ((tid & 63) == 0) red[tid >> 6] = v;
  __syncthreads();
  return red[0] + red[1] + red[2] + red[3];
}

__global__ void ws_probe(float* out, float v) { out[0] = v; }

// -------- fused transpose + layernorm: x[b] (C,L) -> out (L,C), LN over C ----
__global__ __launch_bounds__(256) void tln(const float* __restrict__ x,
                                           const float* __restrict__ w,
                                           const float* __restrict__ b,
                                           float* __restrict__ out) {
  __shared__ float sT[32][321];
  int t0 = blockIdx.x * 32;
  int tid = threadIdx.x;
  for (int i = tid; i < 2560; i += 256) {
    int c = i >> 3, j4 = i & 7;
    float4 v = *(const float4*)(x + (size_t)c * LSEQ + t0 + j4 * 4);
    sT[j4 * 4 + 0][c] = v.x;
    sT[j4 * 4 + 1][c] = v.y;
    sT[j4 * 4 + 2][c] = v.z;
    sT[j4 * 4 + 3][c] = v.w;
  }
  __syncthreads();
  int wave = tid >> 6, lane = tid & 63;
  for (int tt = wave; tt < 32; tt += 4) {
    float xv[5];
    float s = 0.f;
#pragma unroll
    for (int k = 0; k < 5; ++k) { xv[k] = sT[tt][lane + 64 * k]; s += xv[k]; }
    s = wave_sum(s); s = __shfl(s, 0, 64);
    float mean = s * (1.f / 320.f);
    float v = 0.f;
#pragma unroll
    for (int k = 0; k < 5; ++k) { float d = xv[k] - mean; v += d * d; }
    v = wave_sum(v); v = __shfl(v, 0, 64);
    float rstd = rsqrtf(v * (1.f / 320.f) + 1e-5f);
    float* op = out + (size_t)(t0 + tt) * CDIM;
#pragma unroll
    for (int k = 0; k < 5; ++k) {
      int i = lane + 64 * k;
      op[i] = (xv[k] - mean) * rstd * w[i] + b[i];
    }
  }
}

// -------- fused layernorm + transpose: in (L,C) -> out (C,L), LN over C ------
__global__ __launch_bounds__(256) void lnt(const float* __restrict__ in,
                                           const float* __restrict__ w,
                                           const float* __restrict__ b,
                                           float* __restrict__ out) {
  __shared__ float sT[CDIM][33];
  int t0 = blockIdx.x * 32;
  int tid = threadIdx.x;
  int wave = tid >> 6, lane = tid & 63;
  for (int tt = wave; tt < 32; tt += 4) {
    const float* xp = in + (size_t)(t0 + tt) * CDIM;
    float x[5];
    float s = 0.f;
#pragma unroll
    for (int k = 0; k < 5; ++k) { x[k] = xp[lane + 64 * k]; s += x[k]; }
    s = wave_sum(s); s = __shfl(s, 0, 64);
    float mean = s * (1.f / 320.f);
    float v = 0.f;
#pragma unroll
    for (int k = 0; k < 5; ++k) { float d = x[k] - mean; v += d * d; }
    v = wave_sum(v); v = __shfl(v, 0, 64);
    float rstd = rsqrtf(v * (1.f / 320.f) + 1e-5f);
#pragma unroll
    for (int k = 0; k < 5; ++k) {
      int i = lane + 64 * k;
      sT[i][tt] = (x[k] - mean) * rstd * w[i] + b[i];
    }
  }
  __syncthreads();
  for (int i = tid; i < 320 * 32; i += 256) {
    int cc = i >> 5, t = i & 31;
    out[(size_t)cc * LSEQ + t0 + t] = sT[cc][t];
  }
}

// ---------------- layernorm rows (D=320), one wave per row, 4 rows/block -----
__global__ __launch_bounds__(256) void ln_rows256(float* __restrict__ io,
                                                  const float* __restrict__ w,
                                                  const float* __restrict__ b,
                                                  int nrows) {
  int row = blockIdx.x * 4 + (threadIdx.x >> 6);
  if (row >= nrows) return;
  float* xp = io + (size_t)row * CDIM;
  int lane = threadIdx.x & 63;
  float x[5];
  float s = 0.f;
#pragma unroll
  for (int k = 0; k < 5; ++k) { x[k] = xp[lane + 64 * k]; s += x[k]; }
  s = wave_sum(s); s = __shfl(s, 0, 64);
  float mean = s * (1.f / 320.f);
  float v = 0.f;
#pragma unroll
  for (int k = 0; k < 5; ++k) { float t = x[k] - mean; v += t * t; }
  v = wave_sum(v); v = __shfl(v, 0, 64);
  float rstd = rsqrtf(v * (1.f / 320.f) + 1e-5f);
#pragma unroll
  for (int k = 0; k < 5; ++k) {
    int i = lane + 64 * k;
    xp[i] = (x[k] - mean) * rstd * w[i] + b[i];
  }
}

// ------------- bf16 MFMA GEMM, 128x64 tile, XCD-chunked swizzle --------------
// C = (A (+pe)) @ [W;W2]^T (+bias/bias2) (+=C).  Column split at nsplit:
// cols [0,nsplit) -> C (ld=ldc), cols [nsplit,N) -> C2 (ld=ldc2).
// Weight rows >= wsplit come from W2 (row index n - wsplit), bias2 likewise.
__global__ __launch_bounds__(256) void gemm_bf(
    const float* __restrict__ A, const float* __restrict__ W,
    const float* __restrict__ bias, const float* __restrict__ pe,
    float* __restrict__ C, float* __restrict__ C2,
    const float* __restrict__ W2, const float* __restrict__ bias2, int wsplit,
    int M, int N, int K, int lda, int ldc, int nsplit, int ldc2,
    int addC, long long sA, long long sC) {
  int z = blockIdx.z;
  A += (size_t)z * sA;
  C += (size_t)z * sC;
  if (C2) C2 += (size_t)z * sC;
  // bijective XCD-chunked swizzle: XCD k owns a contiguous range of tiles
  int gx = gridDim.x;
  int nwg = gx * gridDim.y;
  int lin = blockIdx.y * gx + blockIdx.x;
  int xcd = lin & 7, idx = lin >> 3;
  int q = nwg >> 3, r = nwg & 7;
  int base = (xcd < r) ? xcd * (q + 1) : r * (q + 1) + (xcd - r) * q;
  int lin2 = base + idx;
  int mblk = lin2 / gx, nblk = lin2 % gx;
  int m0 = mblk << 7, n0 = nblk << 6;

  __shared__ __align__(16) bf16_t As[2][4096];  // 8 groups of 16 rows x 32 k
  __shared__ __align__(16) bf16_t Ws[2][2048];  // 4 groups
  int tid = threadIdx.x;
  int wave = tid >> 6, lane = tid & 63;
  int fm = lane & 15, quad = lane >> 4;
  // staging mapping
  int rA = tid >> 1, hA = tid & 1;  // A row (0..127), col-half (16 floats)
  int rW = tid >> 2, qW = tid & 3;  // W row (0..63), col-quad (8 floats)
  const float* ag = A + (size_t)(m0 + rA) * lda + hA * 16;
  const float* peg = pe ? pe + (size_t)(m0 + rA) * lda + hA * 16 : (const float*)0;
  int wRow = n0 + rW;
  const float* wg;
  if (wRow < wsplit) wg = W + (size_t)wRow * K + qW * 8;
  else               wg = W2 + (size_t)(wRow - wsplit) * K + qW * 8;
  bool wok = wRow < N;
  int aoff = (rA >> 4) * 512 + (hA * 32 + (rA & 15)) * 8;
  int woff = (rW >> 4) * 512 + (qW * 16 + (rW & 15)) * 8;

  f32x4 acc[2][4];
#pragma unroll
  for (int i = 0; i < 2; ++i)
#pragma unroll
    for (int j = 0; j < 4; ++j) acc[i][j] = (f32x4){0.f, 0.f, 0.f, 0.f};

  float4 pa0, pa1, pa2, pa3, pw0, pw1;
  auto loadG = [&](int k0) {
    pa0 = *(const float4*)(ag + k0);
    pa1 = *(const float4*)(ag + k0 + 4);
    pa2 = *(const float4*)(ag + k0 + 8);
    pa3 = *(const float4*)(ag + k0 + 12);
    if (peg) {
      float4 q0 = *(const float4*)(peg + k0);
      float4 q1 = *(const float4*)(peg + k0 + 4);
      float4 q2 = *(const float4*)(peg + k0 + 8);
      float4 q3 = *(const float4*)(peg + k0 + 12);
      pa0.x += q0.x; pa0.y += q0.y; pa0.z += q0.z; pa0.w += q0.w;
      pa1.x += q1.x; pa1.y += q1.y; pa1.z += q1.z; pa1.w += q1.w;
      pa2.x += q2.x; pa2.y += q2.y; pa2.z += q2.z; pa2.w += q2.w;
      pa3.x += q3.x; pa3.y += q3.y; pa3.z += q3.z; pa3.w += q3.w;
    }
    pw0 = make_float4(0.f, 0.f, 0.f, 0.f);
    pw1 = pw0;
    if (wok) {
      pw0 = *(const float4*)(wg + k0);
      pw1 = *(const float4*)(wg + k0 + 4);
    }
  };
  auto packLDS = [&](int buf) {
    bf16x8 v;
    v[0] = (bf16_t)pa0.x; v[1] = (bf16_t)pa0.y; v[2] = (bf16_t)pa0.z; v[3] = (bf16_t)pa0.w;
    v[4] = (bf16_t)pa1.x; v[5] = (bf16_t)pa1.y; v[6] = (bf16_t)pa1.z; v[7] = (bf16_t)pa1.w;
    *(bf16x8*)&As[buf][aoff] = v;
    v[0] = (bf16_t)pa2.x; v[1] = (bf16_t)pa2.y; v[2] = (bf16_t)pa2.z; v[3] = (bf16_t)pa2.w;
    v[4] = (bf16_t)pa3.x; v[5] = (bf16_t)pa3.y; v[6] = (bf16_t)pa3.z; v[7] = (bf16_t)pa3.w;
    *(bf16x8*)&As[buf][aoff + 128] = v;
    v[0] = (bf16_t)pw0.x; v[1] = (bf16_t)pw0.y; v[2] = (bf16_t)pw0.z; v[3] = (bf16_t)pw0.w;
    v[4] = (bf16_t)pw1.x; v[5] = (bf16_t)pw1.y; v[6] = (bf16_t)pw1.z; v[7] = (bf16_t)pw1.w;
    *(bf16x8*)&Ws[buf][woff] = v;
  };

  int nk = K >> 5;
  loadG(0);
  packLDS(0);
  __syncthreads();
  for (int i = 0; i < nk; ++i) {
    int buf = i & 1;
    bool more = (i + 1 < nk);
    if (more) loadG((i + 1) << 5);
    int ab = wave * 1024 + lane * 8;
    bf16x8 af0 = *(bf16x8*)&As[buf][ab];
    bf16x8 af1 = *(bf16x8*)&As[buf][ab + 512];
    bf16x8 b0 = *(bf16x8*)&Ws[buf][lane * 8];
    bf16x8 b1 = *(bf16x8*)&Ws[buf][512 + lane * 8];
    bf16x8 b2 = *(bf16x8*)&Ws[buf][1024 + lane * 8];
    bf16x8 b3 = *(bf16x8*)&Ws[buf][1536 + lane * 8];
    acc[0][0] = __builtin_amdgcn_mfma_f32_16x16x32_bf16(af0, b0, acc[0][0], 0, 0, 0);
    acc[0][1] = __builtin_amdgcn_mfma_f32_16x16x32_bf16(af0, b1, acc[0][1], 0, 0, 0);
    acc[0][2] = __builtin_amdgcn_mfma_f32_16x16x32_bf16(af0, b2, acc[0][2], 0, 0, 0);
    acc[0][3] = __builtin_amdgcn_mfma_f32_16x16x32_bf16(af0, b3, acc[0][3], 0, 0, 0);
    acc[1][0] = __builtin_amdgcn_mfma_f32_16x16x32_bf16(af1, b0, acc[1][0], 0, 0, 0);
    acc[1][1] = __builtin_amdgcn_mfma_f32_16x16x32_bf16(af1, b1, acc[1][1], 0, 0, 0);
    acc[1][2] = __builtin_amdgcn_mfma_f32_16x16x32_bf16(af1, b2, acc[1][2], 0, 0, 0);
    acc[1][3] = __builtin_amdgcn_mfma_f32_16x16x32_bf16(af1, b3, acc[1][3], 0, 0, 0);
    if (more) {
      packLDS(buf ^ 1);
      __syncthreads();
    }
  }
#pragma unroll
  for (int ms = 0; ms < 2; ++ms)
#pragma unroll
    for (int ns = 0; ns < 4; ++ns) {
      int n = n0 + ns * 16 + fm;
      if (n >= N) continue;
      float bv = 0.f;
      if (n < wsplit) { if (bias) bv = bias[n]; }
      else            { if (bias2) bv = bias2[n - wsplit]; }
      float* Cb;
      int ldcb, nc;
      if (n < nsplit) { Cb = C; ldcb = ldc; nc = n; }
      else           { Cb = C2; ldcb = ldc2; nc = n - nsplit; }
#pragma unroll
      for (int rr = 0; rr < 4; ++rr) {
        int m = m0 + wave * 32 + ms * 16 + quad * 4 + rr;
        float v = acc[ms][ns][rr] + bv;
        size_t off = (size_t)m * ldcb + nc;
        if (addC) v += Cb[off];
        Cb[off] = v;
      }
    }
}

// -------- small matmul (token side), wave-per-output-column ------------------
__global__ __launch_bounds__(256) void smallmm(
    const float* __restrict__ A, const float* __restrict__ A2,
    const float* __restrict__ W, const float* __restrict__ bias,
    float* __restrict__ C, int M, int N, int K, int addC, int relu, int a2lim) {
  int wave = threadIdx.x >> 6, lane = threadIdx.x & 63;
  int n = blockIdx.x * 4 + wave;
  if (n >= N) return;
  const float* w = W + (size_t)n * K;
  float wreg[16];
  int nu = (K + 63) >> 6;
#pragma unroll 4
  for (int u = 0; u < nu; ++u) {
    int k = lane + (u << 6);
    wreg[u] = (k < K) ? w[k] : 0.f;
  }
  bool useA2 = (A2 != nullptr) && (n < a2lim);
  float part[12];
  for (int m = 0; m < M; ++m) part[m] = 0.f;
  for (int u = 0; u < nu; ++u) {
    int k = lane + (u << 6);
    if (k < K) {
      float wv = wreg[u];
      for (int m = 0; m < M; ++m) {
        float av = A[(size_t)m * K + k];
        if (useA2) av += A2[(size_t)m * K + k];
        part[m] += av * wv;
      }
    }
  }
  float bv = bias ? bias[n] : 0.f;
  for (int m = 0; m < M; ++m) {
    float dot = wave_sum(part[m]);
    if (lane == 0) {
      float v = dot + bv;
      if (relu) v = fmaxf(v, 0.f);
      size_t off = (size_t)m * N + n;
      if (addC) v += C[off];
      C[off] = v;
    }
  }
}

// ---------------- dt = softplus(dt_raw + dt_bias), layout (h,t) --------------
__global__ void dt_kernel(const float* __restrict__ XBC, const float* __restrict__ dt_bias,
                          float* __restrict__ dtbuf) {
  int idx = blockIdx.x * 256 + threadIdx.x;
  if (idx >= LSEQ * NHH) return;
  int h = idx & 7;
  int t = idx >> 3;
  float v = XBC[(size_t)t * XBCW + 704 + h] + dt_bias[h];
  float sp = (v > 20.f) ? v : log1pf(expf(v));
  dtbuf[(size_t)h * LSEQ + t] = sp;
}

// ------- causal depthwise conv + silu, sliding-window registers --------------
__global__ __launch_bounds__(256) void conv2(const float* __restrict__ XBC,
                                             const float* __restrict__ conv_w,
                                             const float* __restrict__ conv_b,
                                             float* __restrict__ Cv) {
  int lane = threadIdx.x & 63, wv = threadIdx.x >> 6;
  int d = blockIdx.x * 64 + lane;
  int t0 = (blockIdx.y * 4 + wv) * 32;
  float w0 = conv_w[d * 4 + 0], w1 = conv_w[d * 4 + 1];
  float w2 = conv_w[d * 4 + 2], w3 = conv_w[d * 4 + 3];
  float bv = conv_b[d];
  const float* src = XBC + d;
  float xm3, xm2, xm1;
  if (t0 == 0) {
    xm3 = 0.f; xm2 = 0.f; xm1 = 0.f;
  } else {
    xm3 = src[(size_t)(t0 - 3) * XBCW];
    xm2 = src[(size_t)(t0 - 2) * XBCW];
    xm1 = src[(size_t)(t0 - 1) * XBCW];
  }
#pragma unroll 8
  for (int t = t0; t < t0 + 32; ++t) {
    float xt = src[(size_t)t * XBCW];
    float a = bv + xm3 * w0 + xm2 * w1 + xm1 * w2 + xt * w3;
    Cv[(size_t)t * CONVD + d] = a / (1.f + expf(-a));
    xm3 = xm2; xm2 = xm1; xm1 = xt;
  }
}

// ---------------- scan phase A: per-chunk states + cumulative log-decay ------
__global__ __launch_bounds__(256) void scan_a(const float* __restrict__ Cv,
                                              const float* __restrict__ dtbuf,
                                              const float* __restrict__ A_log,
                                              float* __restrict__ Schunk,
                                              float* __restrict__ cabuf) {
  int c = blockIdx.x, h = blockIdx.y;
  int t0 = c * QCH;
  __shared__ float sdt[64], sca[64], sw[64];
  __shared__ __align__(16) float sB[64][36];
  __shared__ __align__(16) float sXt[80][68];
  int tid = threadIdx.x;
  float Aval = -expf(A_log[h]);
  if (tid < 64) sdt[tid] = dtbuf[(size_t)h * LSEQ + t0 + tid];
  __syncthreads();
  if (tid == 0) {
    float run = 0.f;
    for (int j = 0; j < 64; ++j) { run += sdt[j] * Aval; sca[j] = run; }
  }
  __syncthreads();
  float caend = sca[63];
  if (tid < 64) {
    sw[tid] = expf(caend - sca[tid]) * sdt[tid];
    cabuf[(size_t)h * LSEQ + t0 + tid] = sca[tid];
  }
  for (int i = tid; i < 2048; i += 256) {
    int j = i >> 5, n = i & 31;
    sB[j][n] = Cv[(size_t)(t0 + j) * CONVD + 640 + n];
  }
  for (int i = tid; i < 5120; i += 256) {
    int j = i / 80, p = i % 80;
    sXt[p][j] = Cv[(size_t)(t0 + j) * CONVD + h * 80 + p];
  }
  __syncthreads();
  int n = tid >> 3, pb = tid & 7;
  float acc[10];
#pragma unroll
  for (int u = 0; u < 10; ++u) acc[u] = 0.f;
  for (int jb = 0; jb < 16; ++jb) {
    float wB[4];
#pragma unroll
    for (int jj = 0; jj < 4; ++jj) {
      int j = jb * 4 + jj;
      wB[jj] = sw[j] * sB[j][n];
    }
#pragma unroll
    for (int u = 0; u < 10; ++u) {
      int p = pb * 10 + u;
      float4 x4 = *(const float4*)&sXt[p][jb * 4];
      acc[u] += wB[0] * x4.x + wB[1] * x4.y + wB[2] * x4.z + wB[3] * x4.w;
    }
  }
  float* outp = Schunk + (size_t)(h * NCHUNK + c) * 2560;
#pragma unroll
  for (int u = 0; u < 10; ++u) outp[n * 80 + pb * 10 + u] = acc[u];
}

// ---------------- scan phase B: sequential over chunks, 80 blocks ------------
__global__ __launch_bounds__(256) void scan_b(const float* __restrict__ Schunk,
                                              const float* __restrict__ cabuf,
                                              float* __restrict__ Sprev) {
  int pc = blockIdx.x, h = blockIdx.y;
  __shared__ float sdec[256];
  int tid = threadIdx.x;
  sdec[tid] = expf(cabuf[(size_t)h * LSEQ + tid * 64 + 63]);
  __syncthreads();
  int e = pc * 256 + tid;
  const float* base = Schunk + (size_t)h * NCHUNK * 2560 + e;
  float* pbase = Sprev + (size_t)h * NCHUNK * 2560 + e;
  float s = 0.f;
  float v = base[0];
  for (int c = 0; c < NCHUNK; ++c) {
    float vn = (c < NCHUNK - 1) ? base[(size_t)(c + 1) * 2560] : 0.f;
    pbase[(size_t)c * 2560] = s;
    s = s * sdec[c] + v;
    v = vn;
  }
}

// ---------------- scan phase C: MFMA version; Y written IN-PLACE over the ----
// ---------------- X-portion of Cv (stride YSTR=704, cols 0..640) ------------
__global__ __launch_bounds__(256) void scan_c(const float* __restrict__ Cv,
                                              const float* __restrict__ dtbuf,
                                              const float* __restrict__ cabuf,
                                              const float* __restrict__ Sprev,
                                              const float* __restrict__ Dp,
                                              float* __restrict__ Y) {
  int c = blockIdx.x, h = blockIdx.y;
  int t0 = c * QCH;
  __shared__ float sdt[64], sca[64], sexp[64];
  __shared__ __align__(16) bf16_t sC[64 * 40];   // C[j][n], stride 40
  __shared__ __align__(16) bf16_t sB[64 * 40];   // B[s][n], stride 40
  __shared__ __align__(16) bf16_t sXt[80 * 72];  // X^T [p][j], stride 72
  __shared__ __align__(16) bf16_t sSt[80 * 40];  // Sprev^T [p][n], stride 40
  __shared__ __align__(16) bf16_t sP[64 * 72];   // scores [j][s], stride 72
  int tid = threadIdx.x;
  int wave = tid >> 6, lane = tid & 63;
  int fm = lane & 15, quad = lane >> 4;
  if (tid < 64) {
    sdt[tid] = dtbuf[(size_t)h * LSEQ + t0 + tid];
    float cav = cabuf[(size_t)h * LSEQ + t0 + tid];
    sca[tid] = cav;
    sexp[tid] = expf(cav);
  }
  for (int i = tid; i < 2048; i += 256) {
    int j = i >> 5, n = i & 31;
    size_t base = (size_t)(t0 + j) * CONVD;
    sB[j * 40 + n] = (bf16_t)Cv[base + 640 + n];
    sC[j * 40 + n] = (bf16_t)Cv[base + 672 + n];
  }
  for (int i = tid; i < 5120; i += 256) {
    int j = i / 80, p = i % 80;
    sXt[p * 72 + j] = (bf16_t)Cv[(size_t)(t0 + j) * CONVD + h * 80 + p];
  }
  {
    const float* sp = Sprev + (size_t)(h * NCHUNK + c) * 2560;
    for (int i = tid; i < 2560; i += 256) {
      int n = i / 80, p = i % 80;
      sSt[p * 40 + n] = (bf16_t)sp[i];
    }
  }
  __syncthreads();
  int m0 = wave * 16;
  int jbase = m0 + quad * 4;
  bf16x8 afC = *(bf16x8*)&sC[(m0 + fm) * 40 + quad * 8];
  f32x4 accS[4];
#pragma unroll
  for (int nt = 0; nt < 4; ++nt) {
    bf16x8 bf = *(bf16x8*)&sB[(nt * 16 + fm) * 40 + quad * 8];
    f32x4 zero = (f32x4){0.f, 0.f, 0.f, 0.f};
    accS[nt] = __builtin_amdgcn_mfma_f32_16x16x32_bf16(afC, bf, zero, 0, 0, 0);
  }
  float scaj[4];
#pragma unroll
  for (int r = 0; r < 4; ++r) scaj[r] = sca[jbase + r];
#pragma unroll
  for (int nt = 0; nt < 4; ++nt) {
    int s = nt * 16 + fm;
    float dts = sdt[s], scas = sca[s];
#pragma unroll
    for (int r = 0; r < 4; ++r) {
      int j = jbase + r;
      float v = 0.f;
      if (s <= j) v = accS[nt][r] * dts * expf(scaj[r] - scas);
      sP[j * 72 + s] = (bf16_t)v;
    }
  }
  f32x4 acc[5];
#pragma unroll
  for (int pt = 0; pt < 5; ++pt) {
    bf16x8 bf = *(bf16x8*)&sSt[(pt * 16 + fm) * 40 + quad * 8];
    f32x4 zero = (f32x4){0.f, 0.f, 0.f, 0.f};
    acc[pt] = __builtin_amdgcn_mfma_f32_16x16x32_bf16(afC, bf, zero, 0, 0, 0);
  }
  float gj[4];
#pragma unroll
  for (int r = 0; r < 4; ++r) gj[r] = sexp[jbase + r];
#pragma unroll
  for (int pt = 0; pt < 5; ++pt)
#pragma unroll
    for (int r = 0; r < 4; ++r) acc[pt][r] *= gj[r];
  bf16x8 afP0 = *(bf16x8*)&sP[(m0 + fm) * 72 + 0 + quad * 8];
  bf16x8 afP1 = *(bf16x8*)&sP[(m0 + fm) * 72 + 32 + quad * 8];
#pragma unroll
  for (int pt = 0; pt < 5; ++pt) {
    bf16x8 bx0 = *(bf16x8*)&sXt[(pt * 16 + fm) * 72 + 0 + quad * 8];
    bf16x8 bx1 = *(bf16x8*)&sXt[(pt * 16 + fm) * 72 + 32 + quad * 8];
    acc[pt] = __builtin_amdgcn_mfma_f32_16x16x32_bf16(afP0, bx0, acc[pt], 0, 0, 0);
    acc[pt] = __builtin_amdgcn_mfma_f32_16x16x32_bf16(afP1, bx1, acc[pt], 0, 0, 0);
  }
  float dval = Dp[h];
#pragma unroll
  for (int pt = 0; pt < 5; ++pt) {
    int p = pt * 16 + fm;
#pragma unroll
    for (int r = 0; r < 4; ++r) {
      int j = jbase + r;
      float xv = (float)sXt[p * 72 + j];
      Y[(size_t)(t0 + j) * YSTR + h * 80 + p] = acc[pt][r] + dval * xv;
    }
  }
}

// ------------- y *= silu(z); rmsnorm * rms_w  (Y stride YSTR) ----------------
__global__ __launch_bounds__(256) void gate_rms(float* __restrict__ Y,
                                                const float* __restrict__ Z,
                                                const float* __restrict__ rms_w) {
  __shared__ float red[4];
  size_t row = blockIdx.x;
  float* y = Y + row * YSTR;
  const float* z = Z + row * DIN;
  float ss = 0.f;
  for (int i = threadIdx.x; i < DIN; i += 256) {
    float zi = z[i];
    float g = y[i] * (zi / (1.f + expf(-zi)));
    y[i] = g;
    ss += g * g;
  }
  float tot = block_sum256(ss, red);
  float r = rsqrtf(tot / (float)DIN + 1e-5f);
  for (int i = threadIdx.x; i < DIN; i += 256) y[i] = y[i] * r * rms_w[i];
}

// ---------------- dense image PE ----------------
__global__ void kpe_kernel(const float* __restrict__ gauss, float* __restrict__ KPE) {
  int idx = blockIdx.x * 256 + threadIdx.x;
  if (idx >= LSEQ * 160) return;
  int f = idx % 160, t = idx / 160;
  int d = t >> 10, hh = (t >> 5) & 31, w = t & 31;
  float vx = 2.f * ((d + 0.5f) / 16.f) - 1.f;
  float vy = 2.f * ((hh + 0.5f) / 32.f) - 1.f;
  float vz = 2.f * ((w + 0.5f) / 32.f) - 1.f;
  float cc = 6.28318530717958647692f * (vx * gauss[f] + vy * gauss[160 + f] + vz * gauss[320 + f]);
  KPE[(size_t)t * CDIM + f] = sinf(cc);
  KPE[(size_t)t * CDIM + 160 + f] = cosf(cc);
}

// ---------------- point embeddings (both batches: 12 points) -----------------
__global__ void point_kernel(const float* __restrict__ coords, const int* __restrict__ labels,
                             const float* __restrict__ gauss, const float* __restrict__ ptab,
                             float* __restrict__ qpe, float* __restrict__ queries) {
  int idx = blockIdx.x * 64 + threadIdx.x;
  if (idx >= 12 * 160) return;
  int f = idx % 160, pt = idx / 160;
  const float* co = coords + pt * 3;
  float vx = 2.f * (co[0] / 128.f) - 1.f;
  float vy = 2.f * (co[1] / 256.f) - 1.f;
  float vz = 2.f * (co[2] / 256.f) - 1.f;
  float cc = 6.28318530717958647692f * (vx * gauss[f] + vy * gauss[160 + f] + vz * gauss[320 + f]);
  int lab = labels[pt];
  float sv = sinf(cc) + ptab[lab * CDIM + f];
  float cv = cosf(cc) + ptab[lab * CDIM + 160 + f];
  qpe[pt * CDIM + f] = sv;       qpe[pt * CDIM + 160 + f] = cv;
  queries[pt * CDIM + f] = sv;   queries[pt * CDIM + 160 + f] = cv;
}

// --------- self-attn over 6 tokens from fused P3[12][960], grid (4,2) --------
__global__ void attn_self(const float* __restrict__ P3, float* __restrict__ O) {
  int h = blockIdx.x, b = blockIdx.y;
  __shared__ float sq[6][80], sk[6][80], sv[6][80], sw[6][6];
  int tid = threadIdx.x;  // 128
  for (int i = tid; i < 480; i += 128) {
    int tok = i / 80, p = i % 80;
    const float* base = P3 + (size_t)(b * 6 + tok) * 960 + h * 80 + p;
    sq[tok][p] = base[0]; sk[tok][p] = base[320]; sv[tok][p] = base[640];
  }
  __syncthreads();
  if (tid < 36) {
    int qi = tid / 6, ki = tid % 6;
    float d = 0.f;
    for (int p = 0; p < 80; ++p) d += sq[qi][p] * sk[ki][p];
    sw[qi][ki] = d * 0.11180339887498948f;  // 1/sqrt(80)
  }
  __syncthreads();
  if (tid < 6) {
    float mx = sw[tid][0];
    for (int k = 1; k < 6; ++k) mx = fmaxf(mx, sw[tid][k]);
    float s = 0.f;
    for (int k = 0; k < 6; ++k) { float e = expf(sw[tid][k] - mx); sw[tid][k] = e; s += e; }
    float inv = 1.f / s;
    for (int k = 0; k < 6; ++k) sw[tid][k] *= inv;
  }
  __syncthreads();
  for (int i = tid; i < 480; i += 128) {
    int qi = i / 80, p = i % 80;
    float o = 0.f;
    for (int k = 0; k < 6; ++k) o += sw[qi][k] * sv[k][p];
    O[(size_t)(b * 6 + qi) * CDIM + h * 80 + p] = o;
  }
}

// ------------- t2i attention pass 1: LDS + MFMA PV, grid (64,4,2) ------------
// Phase 1: per-thread scores for 6 queries, batched block max/sum; P,V^T -> LDS
// as bf16. Phase 2: wave 0 computes P[16x256] @ V[256x48] with 24 MFMAs.
__global__ __launch_bounds__(256) void attn_t2i_part2(const float* __restrict__ Qp,
                                                      const float* __restrict__ Kp,
                                                      const float* __restrict__ Vp,
                                                      float* __restrict__ Part) {
  int b = blockIdx.z, h = blockIdx.y, c = blockIdx.x;
  Qp += (size_t)b * 960;
  Kp += (size_t)b * LSEQ * 160;
  Vp += (size_t)b * LSEQ * 160;
  Part += (size_t)b * 24 * 64 * 42;
  __shared__ float sq[240];
  __shared__ float redm[4][6], reds[4][6];
  __shared__ __align__(16) bf16_t sPb[16 * 264];   // exp-scores [qi][t]
  __shared__ __align__(16) bf16_t sVtb[48 * 264];  // V^T [p][t]
  int tid = threadIdx.x;
  int wave = tid >> 6, lane = tid & 63;
  if (tid < 240) sq[tid] = Qp[(size_t)(tid / 40) * 160 + h * 40 + (tid % 40)];
  __syncthreads();
  int t = c * 256 + tid;
  const float* kp = Kp + (size_t)t * 160 + h * 40;
  float kr[40];
#pragma unroll
  for (int v = 0; v < 10; ++v) {
    float4 k4 = *(const float4*)(kp + v * 4);
    kr[v * 4 + 0] = k4.x; kr[v * 4 + 1] = k4.y; kr[v * 4 + 2] = k4.z; kr[v * 4 + 3] = k4.w;
  }
  const float* vp = Vp + (size_t)t * 160 + h * 40;
#pragma unroll
  for (int v = 0; v < 10; ++v) {
    float4 v4 = *(const float4*)(vp + v * 4);
    sVtb[(v * 4 + 0) * 264 + tid] = (bf16_t)v4.x;
    sVtb[(v * 4 + 1) * 264 + tid] = (bf16_t)v4.y;
    sVtb[(v * 4 + 2) * 264 + tid] = (bf16_t)v4.z;
    sVtb[(v * 4 + 3) * 264 + tid] = (bf16_t)v4.w;
  }
  float s[6];
#pragma unroll
  for (int qi = 0; qi < 6; ++qi) {
    float d = 0.f;
#pragma unroll
    for (int p = 0; p < 40; ++p) d += sq[qi * 40 + p] * kr[p];
    s[qi] = d * 0.15811388300841897f;  // 1/sqrt(40)
  }
#pragma unroll
  for (int qi = 0; qi < 6; ++qi) {
    float wm = wave_max(s[qi]);
    if (lane == 0) redm[wave][qi] = wm;
  }
  __syncthreads();
  float gmax[6], ls[6];
#pragma unroll
  for (int qi = 0; qi < 6; ++qi)
    gmax[qi] = fmaxf(fmaxf(redm[0][qi], redm[1][qi]), fmaxf(redm[2][qi], redm[3][qi]));
#pragma unroll
  for (int qi = 0; qi < 6; ++qi) {
    float e = expf(s[qi] - gmax[qi]);
    sPb[qi * 264 + tid] = (bf16_t)e;
    float wsum = wave_sum(e);
    if (lane == 0) reds[wave][qi] = wsum;
  }
  __syncthreads();
#pragma unroll
  for (int qi = 0; qi < 6; ++qi)
    ls[qi] = reds[0][qi] + reds[1][qi] + reds[2][qi] + reds[3][qi];
  if (tid == 0) {
#pragma unroll
    for (int qi = 0; qi < 6; ++qi) {
      float* pml = Part + (size_t)((h * 6 + qi) * 64 + c) * 42;
      pml[40] = gmax[qi];
      pml[41] = ls[qi];
    }
  }
  if (wave == 0) {
    int fm = lane & 15, quad = lane >> 4;
    f32x4 acc[3];
#pragma unroll
    for (int nt = 0; nt < 3; ++nt) acc[nt] = (f32x4){0.f, 0.f, 0.f, 0.f};
#pragma unroll
    for (int ks = 0; ks < 8; ++ks) {
      bf16x8 a = *(bf16x8*)&sPb[fm * 264 + ks * 32 + quad * 8];
#pragma unroll
      for (int nt = 0; nt < 3; ++nt) {
        bf16x8 bb = *(bf16x8*)&sVtb[(nt * 16 + fm) * 264 + ks * 32 + quad * 8];
        acc[nt] = __builtin_amdgcn_mfma_f32_16x16x32_bf16(a, bb, acc[nt], 0, 0, 0);
      }
    }
#pragma unroll
    for (int nt = 0; nt < 3; ++nt)
#pragma unroll
      for (int r = 0; r < 4; ++r) {
        int qi = quad * 4 + r;
        int p = nt * 16 + fm;
        if (qi < 6 && p < 40)
          Part[(size_t)((h * 6 + qi) * 64 + c) * 42 + p] = acc[nt][r];
      }
  }
}

// ------------- t2i attention pass 2: combine 64 partials, grid (24,2) --------
__global__ void attn_t2i_comb(const float* __restrict__ Part, float* __restrict__ O) {
  int b = blockIdx.y;
  int blk = blockIdx.x;  // h*6 + qi
  int qi = blk % 6;
  int h = blk / 6;
  int j = threadIdx.x;  // 64
  const float* part = Part + (size_t)b * 24 * 64 * 42 + (size_t)(blk * 64 + j) * 42;
  float m = part[40], l = part[41];
  float gmax = wave_max(m);
  gmax = __shfl(gmax, 0, 64);
  float sc = expf(m - gmax);
  float tot = wave_sum(l * sc);
  tot = __shfl(tot, 0, 64);
  float inv = 1.f / tot;
  for (int p = 0; p < 40; ++p) {
    float v = wave_sum(part[p] * sc);
    if (j == 0) O[(size_t)b * 960 + (size_t)qi * 160 + h * 40 + p] = v * inv;
  }
}

// ------- i2t attention: 16384 q vs 6 k, KV fused [12][320], grid (64,4,2) ----
__global__ __launch_bounds__(256) void attn_i2t(const float* __restrict__ Qp,
                                                const float* __restrict__ KV,
                                                float* __restrict__ O) {
  int h = blockIdx.y, b = blockIdx.z;
  int t = blockIdx.x * 256 + threadIdx.x;
  Qp += (size_t)b * LSEQ * 160;
  O += (size_t)b * LSEQ * 160;
  __shared__ float sk[6][40], sv[6][40];
  if (threadIdx.x < 240) {
    int tok = threadIdx.x / 40, p = threadIdx.x % 40;
    const float* base = KV + (size_t)(b * 6 + tok) * 320 + h * 40 + p;
    sk[tok][p] = base[0];
    sv[tok][p] = base[160];
  }
  __syncthreads();
  const float* q = Qp + (size_t)t * 160 + h * 40;
  float qr[40];
#pragma unroll
  for (int v = 0; v < 10; ++v) {
    float4 q4 = *(const float4*)(q + v * 4);
    qr[v * 4 + 0] = q4.x; qr[v * 4 + 1] = q4.y; qr[v * 4 + 2] = q4.z; qr[v * 4 + 3] = q4.w;
  }
  float s[6];
#pragma unroll
  for (int k = 0; k < 6; ++k) {
    float d = 0.f;
    for (int p = 0; p < 40; ++p) d += qr[p] * sk[k][p];
    s[k] = d * 0.15811388300841897f;
  }
  float mx = s[0];
#pragma unroll
  for (int k = 1; k < 6; ++k) mx = fmaxf(mx, s[k]);
  float sum = 0.f;
#pragma unroll
  for (int k = 0; k < 6; ++k) { s[k] = expf(s[k] - mx); sum += s[k]; }
  float inv = 1.f / sum;
  float* o = O + (size_t)t * 160 + h * 40;
#pragma unroll
  for (int v = 0; v < 10; ++v) {
    float o0 = 0.f, o1 = 0.f, o2 = 0.f, o3 = 0.f;
#pragma unroll
    for (int k = 0; k < 6; ++k) {
      float w = s[k];
      o0 += w * sv[k][v * 4 + 0];
      o1 += w * sv[k][v * 4 + 1];
      o2 += w * sv[k][v * 4 + 2];
      o3 += w * sv[k][v * 4 + 3];
    }
    *(float4*)(o + v * 4) = make_float4(o0 * inv, o1 * inv, o2 * inv, o3 * inv);
  }
}

// =======================================================================
extern "C" void kernel_launch(void* const* d_in, const int* in_sizes, int n_in,
                              void* d_out, int out_size, void* d_ws, size_t ws_size,
                              hipStream_t stream) {
  (void)in_sizes; (void)n_in; (void)out_size;
  const float* x       = (const float*)d_in[0];
  const float* coords  = (const float*)d_in[1];
  const int*   labels  = (const int*)  d_in[2];
  const float* ln_w    = (const float*)d_in[3];
  const float* ln_b    = (const float*)d_in[4];
  const float* in_w    = (const float*)d_in[5];
  const float* conv_w  = (const float*)d_in[6];
  const float* conv_b  = (const float*)d_in[7];
  const float* dt_bias = (const float*)d_in[8];
  const float* A_log   = (const float*)d_in[9];
  const float* Dp      = (const float*)d_in[10];
  const float* rms_w   = (const float*)d_in[11];
  const float* out_w   = (const float*)d_in[12];
  const float* gauss   = (const float*)d_in[13];
  const float* ptab    = (const float*)d_in[14];
  const float* sa_w    = (const float*)d_in[15];
  const float* sa_b    = (const float*)d_in[16];
  const float* t2i_w   = (const float*)d_in[17];
  const float* t2i_b   = (const float*)d_in[18];
  const float* t2i_ow  = (const float*)d_in[19];
  const float* t2i_ob  = (const float*)d_in[20];
  const float* i2t_w   = (const float*)d_in[21];
  const float* i2t_b   = (const float*)d_in[22];
  const float* i2t_ow  = (const float*)d_in[23];
  const float* i2t_ob  = (const float*)d_in[24];
  const float* norms_w = (const float*)d_in[25];
  const float* norms_b = (const float*)d_in[26];
  const float* mlp_w1  = (const float*)d_in[27];
  const float* mlp_b1  = (const float*)d_in[28];
  const float* mlp_w2  = (const float*)d_in[29];
  const float* mlp_b2  = (const float*)d_in[30];
  float* out = (float*)d_out;
  float* ws = (float*)d_ws;

  const size_t NEED = (size_t)(10485760 + 5242880 + 11665408 + 11534336 + 10485760 +
                               131072 + 131072 + 65536) * 4;
  if (ws_size < NEED) {
    ws_probe<<<1, 1, 0, stream>>>(out, (float)ws_size);
    return;
  }
  float* R_K = ws;                         // [2][16384][320]
  float* P   = ws + 10485760;              // scratch pool
  // ---- mamba-phase layout (per batch, reused) ----
  float* XN_     = P;                      // 5,242,880  (LN'd input; dead after in_proj)
  float* SCHUNK_ = P;                      // reuses XN after in_proj
  float* ZB_     = P + 5242880;            // (z; live until gate_rms)
  float* XBC_    = P + 15728640;           // (xBC|dt; dead after conv/dt)
  float* SPREV_  = P + 15728640;           // reuses XBC
  float* CV_     = P + 27394048;           // (conv out; Y written in place)
  float* DT_     = P + 38928384;           // 131,072
  float* CA_     = P + 39059456;           // 131,072
  // ---- transformer-phase layout ----
  float* KPE_  = P;                        // 5,242,880
  float* T0_   = P + 5242880;              // [2][16384][160] t2i-K
  float* T3_   = P + 10485760;             // [2][16384][160] i2t-Q
  float* T1_   = P + 15728640;             // [2][16384][160] t2i-V
  float* T2_   = P + 26214400;             // [2][16384][160] i2t attn out
  float* PART_ = P + 36700160;             // [2][24][64][42]
  float* SM_   = P + 36829184;             // small token buffers
  float* QPE_  = SM_;
  float* QRY_  = SM_ + 3840;
  float* P3_   = SM_ + 7680;
  float* PO_   = SM_ + 19200;
  float* H_    = SM_ + 23040;
  float* Q160_ = SM_ + 35328;
  float* O160_ = SM_ + 37248;
  float* KV_   = SM_ + 39168;

  const long long sIMG160 = (long long)LSEQ * 160;
  const long long sIMG320 = (long long)LSEQ * CDIM;
  const int NOSPLIT = 1 << 30;

  // ======== mamba phase, per batch ========
  for (int b = 0; b < 2; ++b) {
    const float* xb = x + (size_t)b * CDIM * LSEQ;
    float* Kb = R_K + (size_t)b * LSEQ * CDIM;

    tln<<<LSEQ / 32, 256, 0, stream>>>(xb, ln_w, ln_b, XN_);

    // fused in_proj: cols [0,640) -> ZB_ (z), cols [640,1352) -> XBC_ (xBC|dt)
    gemm_bf<<<dim3(22, 128, 1), 256, 0, stream>>>(
        XN_, in_w, nullptr, nullptr, ZB_, XBC_, nullptr, nullptr, NOSPLIT,
        LSEQ, 1352, CDIM, CDIM, DIN, DIN, XBCW, 0, 0, 0);

    dt_kernel<<<LSEQ * NHH / 256, 256, 0, stream>>>(XBC_, dt_bias, DT_);
    conv2<<<dim3(11, 128), 256, 0, stream>>>(XBC_, conv_w, conv_b, CV_);

    scan_a<<<dim3(NCHUNK, NHH), 256, 0, stream>>>(CV_, DT_, A_log, SCHUNK_, CA_);
    scan_b<<<dim3(10, NHH), 256, 0, stream>>>(SCHUNK_, CA_, SPREV_);
    scan_c<<<dim3(NCHUNK, NHH), 256, 0, stream>>>(CV_, DT_, CA_, SPREV_, Dp, CV_);

    gate_rms<<<LSEQ, 256, 0, stream>>>(CV_, ZB_, rms_w);

    gemm_bf<<<dim3(5, 128, 1), 256, 0, stream>>>(
        CV_, out_w, nullptr, nullptr, Kb, nullptr, nullptr, nullptr, NOSPLIT,
        LSEQ, CDIM, DIN, YSTR, CDIM, NOSPLIT, 0, 0, 0, 0);
  }

  kpe_kernel<<<LSEQ * 160 / 256, 256, 0, stream>>>(gauss, KPE_);
  point_kernel<<<30, 64, 0, stream>>>(coords, labels, gauss, ptab, QPE_, QRY_);

  // ======== transformer phase, both batches per dispatch ========
  for (int i = 0; i < 2; ++i) {
    const float* saw = sa_w + (size_t)i * 4 * CDIM * CDIM;
    const float* sab = sa_b + (size_t)i * 4 * CDIM;
    smallmm<<<240, 256, 0, stream>>>(QRY_, (i == 0) ? nullptr : QPE_,
                                     saw, sab, P3_, 12, 960, CDIM, 0, 0, 640);
    attn_self<<<dim3(4, 2), 128, 0, stream>>>(P3_, PO_);
    smallmm<<<80, 256, 0, stream>>>(PO_, nullptr, saw + 3 * 102400, sab + 3 * CDIM,
                                    QRY_, 12, CDIM, CDIM, (i == 0) ? 0 : 1, 0, 0);
    ln_rows256<<<3, 256, 0, stream>>>(QRY_, norms_w + (size_t)(i * 4 + 0) * CDIM,
                                      norms_b + (size_t)(i * 4 + 0) * CDIM, 12);

    smallmm<<<40, 256, 0, stream>>>(QRY_, QPE_, t2i_w + (size_t)(i * 3 + 0) * 51200,
                                    t2i_b + (size_t)(i * 3 + 0) * 160, Q160_,
                                    12, 160, CDIM, 0, 0, 160);
    // fused: cols 0-159 = t2i-K (W=t2i_w[i,1]) -> T0; cols 160-319 = i2t-Q
    // (W2=i2t_w[i,0]) -> T3.  Both use A = R_K + KPE.
    gemm_bf<<<dim3(5, 128, 2), 256, 0, stream>>>(
        R_K, t2i_w + (size_t)(i * 3 + 1) * 51200, t2i_b + (size_t)(i * 3 + 1) * 160,
        KPE_, T0_, T3_, i2t_w + (size_t)(i * 3 + 0) * 51200,
        i2t_b + (size_t)(i * 3 + 0) * 160, 160,
        LSEQ, 320, CDIM, CDIM, 160, 160, 160, 0, sIMG320, sIMG160);
    gemm_bf<<<dim3(3, 128, 2), 256, 0, stream>>>(
        R_K, t2i_w + (size_t)(i * 3 + 2) * 51200, t2i_b + (size_t)(i * 3 + 2) * 160,
        nullptr, T1_, nullptr, nullptr, nullptr, NOSPLIT,
        LSEQ, 160, CDIM, CDIM, 160, NOSPLIT, 0, 0, sIMG320, sIMG160);
    attn_t2i_part2<<<dim3(64, 4, 2), 256, 0, stream>>>(Q160_, T0_, T1_, PART_);
    attn_t2i_comb<<<dim3(24, 2), 64, 0, stream>>>(PART_, O160_);
    smallmm<<<80, 256, 0, stream>>>(O160_, nullptr, t2i_ow + (size_t)i * 51200,
                                    t2i_ob + (size_t)i * CDIM, QRY_,
                                    12, CDIM, 160, 1, 0, 0);
    ln_rows256<<<3, 256, 0, stream>>>(QRY_, norms_w + (size_t)(i * 4 + 1) * CDIM,
                                      norms_b + (size_t)(i * 4 + 1) * CDIM, 12);

    smallmm<<<256, 256, 0, stream>>>(QRY_, nullptr, mlp_w1 + (size_t)i * 1024 * CDIM,
                                     mlp_b1 + (size_t)i * 1024, H_, 12, 1024, CDIM, 0, 1, 0);
    smallmm<<<80, 256, 0, stream>>>(H_, nullptr, mlp_w2 + (size_t)i * CDIM * 1024,
                                    mlp_b2 + (size_t)i * CDIM, QRY_, 12, CDIM, 1024, 1, 0, 0);
    ln_rows256<<<3, 256, 0, stream>>>(QRY_, norms_w + (size_t)(i * 4 + 2) * CDIM,
                                      norms_b + (size_t)(i * 4 + 2) * CDIM, 12);

    smallmm<<<80, 256, 0, stream>>>(QRY_, QPE_, i2t_w + (size_t)(i * 3 + 1) * 51200,
                                    i2t_b + (size_t)(i * 3 + 1) * 160, KV_,
                                    12, 320, CDIM, 0, 0, 160);
    attn_i2t<<<dim3(LSEQ / 256, 4, 2), 256, 0, stream>>>(T3_, KV_, T2_);
    gemm_bf<<<dim3(5, 128, 2), 256, 0, stream>>>(
        T2_, i2t_ow + (size_t)i * CDIM * 160, i2t_ob + (size_t)i * CDIM,
        nullptr, R_K, nullptr, nullptr, nullptr, NOSPLIT,
        LSEQ, CDIM, 160, 160, CDIM, NOSPLIT, 0, 1, sIMG160, sIMG320);
    if (i == 0) {
      ln_rows256<<<2 * LSEQ / 4, 256, 0, stream>>>(
          R_K, norms_w + (size_t)3 * CDIM, norms_b + (size_t)3 * CDIM, 2 * LSEQ);
    }
  }

  // final layernorm fused with transpose to output layout (C,L)
  for (int b = 0; b < 2; ++b) {
    lnt<<<LSEQ / 32, 256, 0, stream>>>(
        R_K + (size_t)b * LSEQ * CDIM, norms_w + (size_t)7 * CDIM,
        norms_b + (size_t)7 * CDIM, out + (size_t)b * CDIM * LSEQ);
  }
}

// Round 4
// 1036.794 us; speedup vs baseline: 1.7015x; 1.2522x over previous
//
#include <hip/hip_runtime.h>
#include <math.h>

#define LSEQ 16384
#define CDIM 320
#define DIN 640
#define NHH 8
#define CONVD 704
#define XBCW 712
#define YSTR 704
#define QCH 64
#define NCHUNK 256

typedef __bf16 bf16_t;
typedef __bf16 bf16x8 __attribute__((ext_vector_type(8)));
typedef float f32x4 __attribute__((ext_vector_type(4)));

// ---------------- reduction helpers ----------------
__device__ __forceinline__ float wave_sum(float v) {
#pragma unroll
  for (int o = 32; o > 0; o >>= 1) v += __shfl_down(v, o, 64);
  return v;
}
__device__ __forceinline__ float wave_max(float v) {
#pragma unroll
  for (int o = 32; o > 0; o >>= 1) v = fmaxf(v, __shfl_down(v, o, 64));
  return v;
}
__device__ __forceinline__ float block_sum256(float v, float* red) {
  int tid = threadIdx.x;
  v = wave_sum(v);
  __syncthreads();
  if ((tid & 63) == 0) red[tid >> 6] = v;
  __syncthreads();
  return red[0] + red[1] + red[2] + red[3];
}

__global__ void ws_probe(float* out, float v) { out[0] = v; }

// -------- fused transpose + layernorm: x[b] (C,L) -> out (L,C), LN over C ----
__global__ __launch_bounds__(256) void tln(const float* __restrict__ x,
                                           const float* __restrict__ w,
                                           const float* __restrict__ b,
                                           float* __restrict__ out) {
  __shared__ float sT[32][321];
  int t0 = blockIdx.x * 32;
  int tid = threadIdx.x;
  for (int i = tid; i < 2560; i += 256) {
    int c = i >> 3, j4 = i & 7;
    float4 v = *(const float4*)(x + (size_t)c * LSEQ + t0 + j4 * 4);
    sT[j4 * 4 + 0][c] = v.x;
    sT[j4 * 4 + 1][c] = v.y;
    sT[j4 * 4 + 2][c] = v.z;
    sT[j4 * 4 + 3][c] = v.w;
  }
  __syncthreads();
  int wave = tid >> 6, lane = tid & 63;
  for (int tt = wave; tt < 32; tt += 4) {
    float xv[5];
    float s = 0.f;
#pragma unroll
    for (int k = 0; k < 5; ++k) { xv[k] = sT[tt][lane + 64 * k]; s += xv[k]; }
    s = wave_sum(s); s = __shfl(s, 0, 64);
    float mean = s * (1.f / 320.f);
    float v = 0.f;
#pragma unroll
    for (int k = 0; k < 5; ++k) { float d = xv[k] - mean; v += d * d; }
    v = wave_sum(v); v = __shfl(v, 0, 64);
    float rstd = rsqrtf(v * (1.f / 320.f) + 1e-5f);
    float* op = out + (size_t)(t0 + tt) * CDIM;
#pragma unroll
    for (int k = 0; k < 5; ++k) {
      int i = lane + 64 * k;
      op[i] = (xv[k] - mean) * rstd * w[i] + b[i];
    }
  }
}

// -------- fused layernorm + transpose: in (L,C) -> out (C,L), LN over C ------
__global__ __launch_bounds__(256) void lnt(const float* __restrict__ in,
                                           const float* __restrict__ w,
                                           const float* __restrict__ b,
                                           float* __restrict__ out) {
  __shared__ float sT[CDIM][33];
  int t0 = blockIdx.x * 32;
  int tid = threadIdx.x;
  int wave = tid >> 6, lane = tid & 63;
  for (int tt = wave; tt < 32; tt += 4) {
    const float* xp = in + (size_t)(t0 + tt) * CDIM;
    float x[5];
    float s = 0.f;
#pragma unroll
    for (int k = 0; k < 5; ++k) { x[k] = xp[lane + 64 * k]; s += x[k]; }
    s = wave_sum(s); s = __shfl(s, 0, 64);
    float mean = s * (1.f / 320.f);
    float v = 0.f;
#pragma unroll
    for (int k = 0; k < 5; ++k) { float d = x[k] - mean; v += d * d; }
    v = wave_sum(v); v = __shfl(v, 0, 64);
    float rstd = rsqrtf(v * (1.f / 320.f) + 1e-5f);
#pragma unroll
    for (int k = 0; k < 5; ++k) {
      int i = lane + 64 * k;
      sT[i][tt] = (x[k] - mean) * rstd * w[i] + b[i];
    }
  }
  __syncthreads();
  for (int i = tid; i < 320 * 32; i += 256) {
    int cc = i >> 5, t = i & 31;
    out[(size_t)cc * LSEQ + t0 + t] = sT[cc][t];
  }
}

// ---------------- layernorm rows (D=320), one wave per row, 4 rows/block -----
__global__ __launch_bounds__(256) void ln_rows256(float* __restrict__ io,
                                                  const float* __restrict__ w,
                                                  const float* __restrict__ b,
                                                  int nrows) {
  int row = blockIdx.x * 4 + (threadIdx.x >> 6);
  if (row >= nrows) return;
  float* xp = io + (size_t)row * CDIM;
  int lane = threadIdx.x & 63;
  float x[5];
  float s = 0.f;
#pragma unroll
  for (int k = 0; k < 5; ++k) { x[k] = xp[lane + 64 * k]; s += x[k]; }
  s = wave_sum(s); s = __shfl(s, 0, 64);
  float mean = s * (1.f / 320.f);
  float v = 0.f;
#pragma unroll
  for (int k = 0; k < 5; ++k) { float t = x[k] - mean; v += t * t; }
  v = wave_sum(v); v = __shfl(v, 0, 64);
  float rstd = rsqrtf(v * (1.f / 320.f) + 1e-5f);
#pragma unroll
  for (int k = 0; k < 5; ++k) {
    int i = lane + 64 * k;
    xp[i] = (x[k] - mean) * rstd * w[i] + b[i];
  }
}

// ------------- bf16 MFMA GEMM, 128x64 tile, XCD-chunked swizzle --------------
// C = (A (+pe)) @ [W;W2]^T (+bias/bias2) (+=C).  Column split at nsplit:
// cols [0,nsplit) -> C (ld=ldc), cols [nsplit,N) -> C2 (ld=ldc2).
// Weight rows >= wsplit come from W2 (row index n - wsplit), bias2 likewise.
__global__ __launch_bounds__(256) void gemm_bf(
    const float* __restrict__ A, const float* __restrict__ W,
    const float* __restrict__ bias, const float* __restrict__ pe,
    float* __restrict__ C, float* __restrict__ C2,
    const float* __restrict__ W2, const float* __restrict__ bias2, int wsplit,
    int M, int N, int K, int lda, int ldc, int nsplit, int ldc2,
    int addC, long long sA, long long sC) {
  int z = blockIdx.z;
  A += (size_t)z * sA;
  C += (size_t)z * sC;
  if (C2) C2 += (size_t)z * sC;
  // bijective XCD-chunked swizzle: XCD k owns a contiguous range of tiles
  int gx = gridDim.x;
  int nwg = gx * gridDim.y;
  int lin = blockIdx.y * gx + blockIdx.x;
  int xcd = lin & 7, idx = lin >> 3;
  int q = nwg >> 3, r = nwg & 7;
  int base = (xcd < r) ? xcd * (q + 1) : r * (q + 1) + (xcd - r) * q;
  int lin2 = base + idx;
  int mblk = lin2 / gx, nblk = lin2 % gx;
  int m0 = mblk << 7, n0 = nblk << 6;

  __shared__ __align__(16) bf16_t As[2][4096];  // 8 groups of 16 rows x 32 k
  __shared__ __align__(16) bf16_t Ws[2][2048];  // 4 groups
  int tid = threadIdx.x;
  int wave = tid >> 6, lane = tid & 63;
  int fm = lane & 15, quad = lane >> 4;
  // staging mapping
  int rA = tid >> 1, hA = tid & 1;  // A row (0..127), col-half (16 floats)
  int rW = tid >> 2, qW = tid & 3;  // W row (0..63), col-quad (8 floats)
  const float* ag = A + (size_t)(m0 + rA) * lda + hA * 16;
  const float* peg = pe ? pe + (size_t)(m0 + rA) * lda + hA * 16 : (const float*)0;
  int wRow = n0 + rW;
  const float* wg;
  if (wRow < wsplit) wg = W + (size_t)wRow * K + qW * 8;
  else               wg = W2 + (size_t)(wRow - wsplit) * K + qW * 8;
  bool wok = wRow < N;
  int aoff = (rA >> 4) * 512 + (hA * 32 + (rA & 15)) * 8;
  int woff = (rW >> 4) * 512 + (qW * 16 + (rW & 15)) * 8;

  f32x4 acc[2][4];
#pragma unroll
  for (int i = 0; i < 2; ++i)
#pragma unroll
    for (int j = 0; j < 4; ++j) acc[i][j] = (f32x4){0.f, 0.f, 0.f, 0.f};

  float4 pa0, pa1, pa2, pa3, pw0, pw1;
  auto loadG = [&](int k0) {
    pa0 = *(const float4*)(ag + k0);
    pa1 = *(const float4*)(ag + k0 + 4);
    pa2 = *(const float4*)(ag + k0 + 8);
    pa3 = *(const float4*)(ag + k0 + 12);
    if (peg) {
      float4 q0 = *(const float4*)(peg + k0);
      float4 q1 = *(const float4*)(peg + k0 + 4);
      float4 q2 = *(const float4*)(peg + k0 + 8);
      float4 q3 = *(const float4*)(peg + k0 + 12);
      pa0.x += q0.x; pa0.y += q0.y; pa0.z += q0.z; pa0.w += q0.w;
      pa1.x += q1.x; pa1.y += q1.y; pa1.z += q1.z; pa1.w += q1.w;
      pa2.x += q2.x; pa2.y += q2.y; pa2.z += q2.z; pa2.w += q2.w;
      pa3.x += q3.x; pa3.y += q3.y; pa3.z += q3.z; pa3.w += q3.w;
    }
    pw0 = make_float4(0.f, 0.f, 0.f, 0.f);
    pw1 = pw0;
    if (wok) {
      pw0 = *(const float4*)(wg + k0);
      pw1 = *(const float4*)(wg + k0 + 4);
    }
  };
  auto packLDS = [&](int buf) {
    bf16x8 v;
    v[0] = (bf16_t)pa0.x; v[1] = (bf16_t)pa0.y; v[2] = (bf16_t)pa0.z; v[3] = (bf16_t)pa0.w;
    v[4] = (bf16_t)pa1.x; v[5] = (bf16_t)pa1.y; v[6] = (bf16_t)pa1.z; v[7] = (bf16_t)pa1.w;
    *(bf16x8*)&As[buf][aoff] = v;
    v[0] = (bf16_t)pa2.x; v[1] = (bf16_t)pa2.y; v[2] = (bf16_t)pa2.z; v[3] = (bf16_t)pa2.w;
    v[4] = (bf16_t)pa3.x; v[5] = (bf16_t)pa3.y; v[6] = (bf16_t)pa3.z; v[7] = (bf16_t)pa3.w;
    *(bf16x8*)&As[buf][aoff + 128] = v;
    v[0] = (bf16_t)pw0.x; v[1] = (bf16_t)pw0.y; v[2] = (bf16_t)pw0.z; v[3] = (bf16_t)pw0.w;
    v[4] = (bf16_t)pw1.x; v[5] = (bf16_t)pw1.y; v[6] = (bf16_t)pw1.z; v[7] = (bf16_t)pw1.w;
    *(bf16x8*)&Ws[buf][woff] = v;
  };

  int nk = K >> 5;
  loadG(0);
  packLDS(0);
  __syncthreads();
  for (int i = 0; i < nk; ++i) {
    int buf = i & 1;
    bool more = (i + 1 < nk);
    if (more) loadG((i + 1) << 5);
    int ab = wave * 1024 + lane * 8;
    bf16x8 af0 = *(bf16x8*)&As[buf][ab];
    bf16x8 af1 = *(bf16x8*)&As[buf][ab + 512];
    bf16x8 b0 = *(bf16x8*)&Ws[buf][lane * 8];
    bf16x8 b1 = *(bf16x8*)&Ws[buf][512 + lane * 8];
    bf16x8 b2 = *(bf16x8*)&Ws[buf][1024 + lane * 8];
    bf16x8 b3 = *(bf16x8*)&Ws[buf][1536 + lane * 8];
    acc[0][0] = __builtin_amdgcn_mfma_f32_16x16x32_bf16(af0, b0, acc[0][0], 0, 0, 0);
    acc[0][1] = __builtin_amdgcn_mfma_f32_16x16x32_bf16(af0, b1, acc[0][1], 0, 0, 0);
    acc[0][2] = __builtin_amdgcn_mfma_f32_16x16x32_bf16(af0, b2, acc[0][2], 0, 0, 0);
    acc[0][3] = __builtin_amdgcn_mfma_f32_16x16x32_bf16(af0, b3, acc[0][3], 0, 0, 0);
    acc[1][0] = __builtin_amdgcn_mfma_f32_16x16x32_bf16(af1, b0, acc[1][0], 0, 0, 0);
    acc[1][1] = __builtin_amdgcn_mfma_f32_16x16x32_bf16(af1, b1, acc[1][1], 0, 0, 0);
    acc[1][2] = __builtin_amdgcn_mfma_f32_16x16x32_bf16(af1, b2, acc[1][2], 0, 0, 0);
    acc[1][3] = __builtin_amdgcn_mfma_f32_16x16x32_bf16(af1, b3, acc[1][3], 0, 0, 0);
    if (more) {
      packLDS(buf ^ 1);
      __syncthreads();
    }
  }
#pragma unroll
  for (int ms = 0; ms < 2; ++ms)
#pragma unroll
    for (int ns = 0; ns < 4; ++ns) {
      int n = n0 + ns * 16 + fm;
      if (n >= N) continue;
      float bv = 0.f;
      if (n < wsplit) { if (bias) bv = bias[n]; }
      else            { if (bias2) bv = bias2[n - wsplit]; }
      float* Cb;
      int ldcb, nc;
      if (n < nsplit) { Cb = C; ldcb = ldc; nc = n; }
      else           { Cb = C2; ldcb = ldc2; nc = n - nsplit; }
#pragma unroll
      for (int rr = 0; rr < 4; ++rr) {
        int m = m0 + wave * 32 + ms * 16 + quad * 4 + rr;
        float v = acc[ms][ns][rr] + bv;
        size_t off = (size_t)m * ldcb + nc;
        if (addC) v += Cb[off];
        Cb[off] = v;
      }
    }
}

// -------- small matmul (token side), M=12 fixed, wave-per-output-column ------
// part[12] fully unrolled -> stays in VGPRs (no scratch).
__global__ __launch_bounds__(256) void smallmm(
    const float* __restrict__ A, const float* __restrict__ A2,
    const float* __restrict__ W, const float* __restrict__ bias,
    float* __restrict__ C, int N, int K, int addC, int relu, int a2lim) {
  int wave = threadIdx.x >> 6, lane = threadIdx.x & 63;
  int n = blockIdx.x * 4 + wave;
  if (n >= N) return;
  const float* w = W + (size_t)n * K;
  bool useA2 = (A2 != nullptr) && (n < a2lim);
  float part[12];
#pragma unroll
  for (int m = 0; m < 12; ++m) part[m] = 0.f;
  for (int k0 = 0; k0 < K; k0 += 64) {
    int k = k0 + lane;
    if (k < K) {
      float wv = w[k];
      const float* ap = A + k;
      if (useA2) {
        const float* ap2 = A2 + k;
#pragma unroll
        for (int m = 0; m < 12; ++m)
          part[m] = fmaf(ap[(size_t)m * K] + ap2[(size_t)m * K], wv, part[m]);
      } else {
#pragma unroll
        for (int m = 0; m < 12; ++m)
          part[m] = fmaf(ap[(size_t)m * K], wv, part[m]);
      }
    }
  }
  float bv = bias ? bias[n] : 0.f;
#pragma unroll
  for (int m = 0; m < 12; ++m) {
    float dot = wave_sum(part[m]);
    if (lane == 0) {
      float v = dot + bv;
      if (relu) v = fmaxf(v, 0.f);
      size_t off = (size_t)m * N + n;
      if (addC) v += C[off];
      C[off] = v;
    }
  }
}

// ---------------- dt = softplus(dt_raw + dt_bias), layout (h,t) --------------
__global__ void dt_kernel(const float* __restrict__ XBC, const float* __restrict__ dt_bias,
                          float* __restrict__ dtbuf) {
  int idx = blockIdx.x * 256 + threadIdx.x;
  if (idx >= LSEQ * NHH) return;
  int h = idx & 7;
  int t = idx >> 3;
  float v = XBC[(size_t)t * XBCW + 704 + h] + dt_bias[h];
  float sp = (v > 20.f) ? v : log1pf(expf(v));
  dtbuf[(size_t)h * LSEQ + t] = sp;
}

// ------- causal depthwise conv + silu, sliding-window registers --------------
__global__ __launch_bounds__(256) void conv2(const float* __restrict__ XBC,
                                             const float* __restrict__ conv_w,
                                             const float* __restrict__ conv_b,
                                             float* __restrict__ Cv) {
  int lane = threadIdx.x & 63, wv = threadIdx.x >> 6;
  int d = blockIdx.x * 64 + lane;
  int t0 = (blockIdx.y * 4 + wv) * 32;
  float w0 = conv_w[d * 4 + 0], w1 = conv_w[d * 4 + 1];
  float w2 = conv_w[d * 4 + 2], w3 = conv_w[d * 4 + 3];
  float bv = conv_b[d];
  const float* src = XBC + d;
  float xm3, xm2, xm1;
  if (t0 == 0) {
    xm3 = 0.f; xm2 = 0.f; xm1 = 0.f;
  } else {
    xm3 = src[(size_t)(t0 - 3) * XBCW];
    xm2 = src[(size_t)(t0 - 2) * XBCW];
    xm1 = src[(size_t)(t0 - 1) * XBCW];
  }
#pragma unroll 8
  for (int t = t0; t < t0 + 32; ++t) {
    float xt = src[(size_t)t * XBCW];
    float a = bv + xm3 * w0 + xm2 * w1 + xm1 * w2 + xt * w3;
    Cv[(size_t)t * CONVD + d] = a / (1.f + expf(-a));
    xm3 = xm2; xm2 = xm1; xm1 = xt;
  }
}

// ---------------- scan phase A: per-chunk states + cumulative log-decay ------
__global__ __launch_bounds__(256) void scan_a(const float* __restrict__ Cv,
                                              const float* __restrict__ dtbuf,
                                              const float* __restrict__ A_log,
                                              float* __restrict__ Schunk,
                                              float* __restrict__ cabuf) {
  int c = blockIdx.x, h = blockIdx.y;
  int t0 = c * QCH;
  __shared__ float sdt[64], sca[64], sw[64];
  __shared__ __align__(16) float sB[64][36];
  __shared__ __align__(16) float sXt[80][68];
  int tid = threadIdx.x;
  float Aval = -expf(A_log[h]);
  if (tid < 64) sdt[tid] = dtbuf[(size_t)h * LSEQ + t0 + tid];
  __syncthreads();
  if (tid == 0) {
    float run = 0.f;
    for (int j = 0; j < 64; ++j) { run += sdt[j] * Aval; sca[j] = run; }
  }
  __syncthreads();
  float caend = sca[63];
  if (tid < 64) {
    sw[tid] = expf(caend - sca[tid]) * sdt[tid];
    cabuf[(size_t)h * LSEQ + t0 + tid] = sca[tid];
  }
  for (int i = tid; i < 2048; i += 256) {
    int j = i >> 5, n = i & 31;
    sB[j][n] = Cv[(size_t)(t0 + j) * CONVD + 640 + n];
  }
  for (int i = tid; i < 5120; i += 256) {
    int j = i / 80, p = i % 80;
    sXt[p][j] = Cv[(size_t)(t0 + j) * CONVD + h * 80 + p];
  }
  __syncthreads();
  int n = tid >> 3, pb = tid & 7;
  float acc[10];
#pragma unroll
  for (int u = 0; u < 10; ++u) acc[u] = 0.f;
  for (int jb = 0; jb < 16; ++jb) {
    float wB[4];
#pragma unroll
    for (int jj = 0; jj < 4; ++jj) {
      int j = jb * 4 + jj;
      wB[jj] = sw[j] * sB[j][n];
    }
#pragma unroll
    for (int u = 0; u < 10; ++u) {
      int p = pb * 10 + u;
      float4 x4 = *(const float4*)&sXt[p][jb * 4];
      acc[u] += wB[0] * x4.x + wB[1] * x4.y + wB[2] * x4.z + wB[3] * x4.w;
    }
  }
  float* outp = Schunk + (size_t)(h * NCHUNK + c) * 2560;
#pragma unroll
  for (int u = 0; u < 10; ++u) outp[n * 80 + pb * 10 + u] = acc[u];
}

// ---------------- scan phase B: sequential over chunks, 80 blocks ------------
__global__ __launch_bounds__(256) void scan_b(const float* __restrict__ Schunk,
                                              const float* __restrict__ cabuf,
                                              float* __restrict__ Sprev) {
  int pc = blockIdx.x, h = blockIdx.y;
  __shared__ float sdec[256];
  int tid = threadIdx.x;
  sdec[tid] = expf(cabuf[(size_t)h * LSEQ + tid * 64 + 63]);
  __syncthreads();
  int e = pc * 256 + tid;
  const float* base = Schunk + (size_t)h * NCHUNK * 2560 + e;
  float* pbase = Sprev + (size_t)h * NCHUNK * 2560 + e;
  float s = 0.f;
  float v = base[0];
  for (int c = 0; c < NCHUNK; ++c) {
    float vn = (c < NCHUNK - 1) ? base[(size_t)(c + 1) * 2560] : 0.f;
    pbase[(size_t)c * 2560] = s;
    s = s * sdec[c] + v;
    v = vn;
  }
}

// ---------------- scan phase C: MFMA version; Y written IN-PLACE over the ----
// ---------------- X-portion of Cv (stride YSTR=704, cols 0..640) ------------
__global__ __launch_bounds__(256) void scan_c(const float* __restrict__ Cv,
                                              const float* __restrict__ dtbuf,
                                              const float* __restrict__ cabuf,
                                              const float* __restrict__ Sprev,
                                              const float* __restrict__ Dp,
                                              float* __restrict__ Y) {
  int c = blockIdx.x, h = blockIdx.y;
  int t0 = c * QCH;
  __shared__ float sdt[64], sca[64], sexp[64];
  __shared__ __align__(16) bf16_t sC[64 * 40];   // C[j][n], stride 40
  __shared__ __align__(16) bf16_t sB[64 * 40];   // B[s][n], stride 40
  __shared__ __align__(16) bf16_t sXt[80 * 72];  // X^T [p][j], stride 72
  __shared__ __align__(16) bf16_t sSt[80 * 40];  // Sprev^T [p][n], stride 40
  __shared__ __align__(16) bf16_t sP[64 * 72];   // scores [j][s], stride 72
  int tid = threadIdx.x;
  int wave = tid >> 6, lane = tid & 63;
  int fm = lane & 15, quad = lane >> 4;
  if (tid < 64) {
    sdt[tid] = dtbuf[(size_t)h * LSEQ + t0 + tid];
    float cav = cabuf[(size_t)h * LSEQ + t0 + tid];
    sca[tid] = cav;
    sexp[tid] = expf(cav);
  }
  for (int i = tid; i < 2048; i += 256) {
    int j = i >> 5, n = i & 31;
    size_t base = (size_t)(t0 + j) * CONVD;
    sB[j * 40 + n] = (bf16_t)Cv[base + 640 + n];
    sC[j * 40 + n] = (bf16_t)Cv[base + 672 + n];
  }
  for (int i = tid; i < 5120; i += 256) {
    int j = i / 80, p = i % 80;
    sXt[p * 72 + j] = (bf16_t)Cv[(size_t)(t0 + j) * CONVD + h * 80 + p];
  }
  {
    const float* sp = Sprev + (size_t)(h * NCHUNK + c) * 2560;
    for (int i = tid; i < 2560; i += 256) {
      int n = i / 80, p = i % 80;
      sSt[p * 40 + n] = (bf16_t)sp[i];
    }
  }
  __syncthreads();
  int m0 = wave * 16;
  int jbase = m0 + quad * 4;
  bf16x8 afC = *(bf16x8*)&sC[(m0 + fm) * 40 + quad * 8];
  f32x4 accS[4];
#pragma unroll
  for (int nt = 0; nt < 4; ++nt) {
    bf16x8 bf = *(bf16x8*)&sB[(nt * 16 + fm) * 40 + quad * 8];
    f32x4 zero = (f32x4){0.f, 0.f, 0.f, 0.f};
    accS[nt] = __builtin_amdgcn_mfma_f32_16x16x32_bf16(afC, bf, zero, 0, 0, 0);
  }
  float scaj[4];
#pragma unroll
  for (int r = 0; r < 4; ++r) scaj[r] = sca[jbase + r];
#pragma unroll
  for (int nt = 0; nt < 4; ++nt) {
    int s = nt * 16 + fm;
    float dts = sdt[s], scas = sca[s];
#pragma unroll
    for (int r = 0; r < 4; ++r) {
      int j = jbase + r;
      float v = 0.f;
      if (s <= j) v = accS[nt][r] * dts * expf(scaj[r] - scas);
      sP[j * 72 + s] = (bf16_t)v;
    }
  }
  f32x4 acc[5];
#pragma unroll
  for (int pt = 0; pt < 5; ++pt) {
    bf16x8 bf = *(bf16x8*)&sSt[(pt * 16 + fm) * 40 + quad * 8];
    f32x4 zero = (f32x4){0.f, 0.f, 0.f, 0.f};
    acc[pt] = __builtin_amdgcn_mfma_f32_16x16x32_bf16(afC, bf, zero, 0, 0, 0);
  }
  float gj[4];
#pragma unroll
  for (int r = 0; r < 4; ++r) gj[r] = sexp[jbase + r];
#pragma unroll
  for (int pt = 0; pt < 5; ++pt)
#pragma unroll
    for (int r = 0; r < 4; ++r) acc[pt][r] *= gj[r];
  bf16x8 afP0 = *(bf16x8*)&sP[(m0 + fm) * 72 + 0 + quad * 8];
  bf16x8 afP1 = *(bf16x8*)&sP[(m0 + fm) * 72 + 32 + quad * 8];
#pragma unroll
  for (int pt = 0; pt < 5; ++pt) {
    bf16x8 bx0 = *(bf16x8*)&sXt[(pt * 16 + fm) * 72 + 0 + quad * 8];
    bf16x8 bx1 = *(bf16x8*)&sXt[(pt * 16 + fm) * 72 + 32 + quad * 8];
    acc[pt] = __builtin_amdgcn_mfma_f32_16x16x32_bf16(afP0, bx0, acc[pt], 0, 0, 0);
    acc[pt] = __builtin_amdgcn_mfma_f32_16x16x32_bf16(afP1, bx1, acc[pt], 0, 0, 0);
  }
  float dval = Dp[h];
#pragma unroll
  for (int pt = 0; pt < 5; ++pt) {
    int p = pt * 16 + fm;
#pragma unroll
    for (int r = 0; r < 4; ++r) {
      int j = jbase + r;
      float xv = (float)sXt[p * 72 + j];
      Y[(size_t)(t0 + j) * YSTR + h * 80 + p] = acc[pt][r] + dval * xv;
    }
  }
}

// ------------- y *= silu(z); rmsnorm * rms_w  (Y stride YSTR) ----------------
__global__ __launch_bounds__(256) void gate_rms(float* __restrict__ Y,
                                                const float* __restrict__ Z,
                                                const float* __restrict__ rms_w) {
  __shared__ float red[4];
  size_t row = blockIdx.x;
  float* y = Y + row * YSTR;
  const float* z = Z + row * DIN;
  float ss = 0.f;
  for (int i = threadIdx.x; i < DIN; i += 256) {
    float zi = z[i];
    float g = y[i] * (zi / (1.f + expf(-zi)));
    y[i] = g;
    ss += g * g;
  }
  float tot = block_sum256(ss, red);
  float r = rsqrtf(tot / (float)DIN + 1e-5f);
  for (int i = threadIdx.x; i < DIN; i += 256) y[i] = y[i] * r * rms_w[i];
}

// ---------------- dense image PE ----------------
__global__ void kpe_kernel(const float* __restrict__ gauss, float* __restrict__ KPE) {
  int idx = blockIdx.x * 256 + threadIdx.x;
  if (idx >= LSEQ * 160) return;
  int f = idx % 160, t = idx / 160;
  int d = t >> 10, hh = (t >> 5) & 31, w = t & 31;
  float vx = 2.f * ((d + 0.5f) / 16.f) - 1.f;
  float vy = 2.f * ((hh + 0.5f) / 32.f) - 1.f;
  float vz = 2.f * ((w + 0.5f) / 32.f) - 1.f;
  float cc = 6.28318530717958647692f * (vx * gauss[f] + vy * gauss[160 + f] + vz * gauss[320 + f]);
  KPE[(size_t)t * CDIM + f] = sinf(cc);
  KPE[(size_t)t * CDIM + 160 + f] = cosf(cc);
}

// ---------------- point embeddings (both batches: 12 points) -----------------
__global__ void point_kernel(const float* __restrict__ coords, const int* __restrict__ labels,
                             const float* __restrict__ gauss, const float* __restrict__ ptab,
                             float* __restrict__ qpe, float* __restrict__ queries) {
  int idx = blockIdx.x * 64 + threadIdx.x;
  if (idx >= 12 * 160) return;
  int f = idx % 160, pt = idx / 160;
  const float* co = coords + pt * 3;
  float vx = 2.f * (co[0] / 128.f) - 1.f;
  float vy = 2.f * (co[1] / 256.f) - 1.f;
  float vz = 2.f * (co[2] / 256.f) - 1.f;
  float cc = 6.28318530717958647692f * (vx * gauss[f] + vy * gauss[160 + f] + vz * gauss[320 + f]);
  int lab = labels[pt];
  float sv = sinf(cc) + ptab[lab * CDIM + f];
  float cv = cosf(cc) + ptab[lab * CDIM + 160 + f];
  qpe[pt * CDIM + f] = sv;       qpe[pt * CDIM + 160 + f] = cv;
  queries[pt * CDIM + f] = sv;   queries[pt * CDIM + 160 + f] = cv;
}

// --------- self-attn over 6 tokens from fused P3[12][960], grid (4,2) --------
__global__ void attn_self(const float* __restrict__ P3, float* __restrict__ O) {
  int h = blockIdx.x, b = blockIdx.y;
  __shared__ float sq[6][80], sk[6][80], sv[6][80], sw[6][6];
  int tid = threadIdx.x;  // 128
  for (int i = tid; i < 480; i += 128) {
    int tok = i / 80, p = i % 80;
    const float* base = P3 + (size_t)(b * 6 + tok) * 960 + h * 80 + p;
    sq[tok][p] = base[0]; sk[tok][p] = base[320]; sv[tok][p] = base[640];
  }
  __syncthreads();
  if (tid < 36) {
    int qi = tid / 6, ki = tid % 6;
    float d = 0.f;
    for (int p = 0; p < 80; ++p) d += sq[qi][p] * sk[ki][p];
    sw[qi][ki] = d * 0.11180339887498948f;  // 1/sqrt(80)
  }
  __syncthreads();
  if (tid < 6) {
    float mx = sw[tid][0];
    for (int k = 1; k < 6; ++k) mx = fmaxf(mx, sw[tid][k]);
    float s = 0.f;
    for (int k = 0; k < 6; ++k) { float e = expf(sw[tid][k] - mx); sw[tid][k] = e; s += e; }
    float inv = 1.f / s;
    for (int k = 0; k < 6; ++k) sw[tid][k] *= inv;
  }
  __syncthreads();
  for (int i = tid; i < 480; i += 128) {
    int qi = i / 80, p = i % 80;
    float o = 0.f;
    for (int k = 0; k < 6; ++k) o += sw[qi][k] * sv[k][p];
    O[(size_t)(b * 6 + qi) * CDIM + h * 80 + p] = o;
  }
}

// ------------- t2i attention pass 1: LDS + MFMA PV, grid (64,4,2) ------------
__global__ __launch_bounds__(256) void attn_t2i_part2(const float* __restrict__ Qp,
                                                      const float* __restrict__ Kp,
                                                      const float* __restrict__ Vp,
                                                      float* __restrict__ Part) {
  int b = blockIdx.z, h = blockIdx.y, c = blockIdx.x;
  Qp += (size_t)b * 960;
  Kp += (size_t)b * LSEQ * 160;
  Vp += (size_t)b * LSEQ * 160;
  Part += (size_t)b * 24 * 64 * 42;
  __shared__ float sq[240];
  __shared__ float redm[4][6], reds[4][6];
  __shared__ __align__(16) bf16_t sPb[16 * 264];   // exp-scores [qi][t]
  __shared__ __align__(16) bf16_t sVtb[48 * 264];  // V^T [p][t]
  int tid = threadIdx.x;
  int wave = tid >> 6, lane = tid & 63;
  if (tid < 240) sq[tid] = Qp[(size_t)(tid / 40) * 160 + h * 40 + (tid % 40)];
  __syncthreads();
  int t = c * 256 + tid;
  const float* kp = Kp + (size_t)t * 160 + h * 40;
  float kr[40];
#pragma unroll
  for (int v = 0; v < 10; ++v) {
    float4 k4 = *(const float4*)(kp + v * 4);
    kr[v * 4 + 0] = k4.x; kr[v * 4 + 1] = k4.y; kr[v * 4 + 2] = k4.z; kr[v * 4 + 3] = k4.w;
  }
  const float* vp = Vp + (size_t)t * 160 + h * 40;
#pragma unroll
  for (int v = 0; v < 10; ++v) {
    float4 v4 = *(const float4*)(vp + v * 4);
    sVtb[(v * 4 + 0) * 264 + tid] = (bf16_t)v4.x;
    sVtb[(v * 4 + 1) * 264 + tid] = (bf16_t)v4.y;
    sVtb[(v * 4 + 2) * 264 + tid] = (bf16_t)v4.z;
    sVtb[(v * 4 + 3) * 264 + tid] = (bf16_t)v4.w;
  }
  float s[6];
#pragma unroll
  for (int qi = 0; qi < 6; ++qi) {
    float d = 0.f;
#pragma unroll
    for (int p = 0; p < 40; ++p) d += sq[qi * 40 + p] * kr[p];
    s[qi] = d * 0.15811388300841897f;  // 1/sqrt(40)
  }
#pragma unroll
  for (int qi = 0; qi < 6; ++qi) {
    float wm = wave_max(s[qi]);
    if (lane == 0) redm[wave][qi] = wm;
  }
  __syncthreads();
  float gmax[6], ls[6];
#pragma unroll
  for (int qi = 0; qi < 6; ++qi)
    gmax[qi] = fmaxf(fmaxf(redm[0][qi], redm[1][qi]), fmaxf(redm[2][qi], redm[3][qi]));
#pragma unroll
  for (int qi = 0; qi < 6; ++qi) {
    float e = expf(s[qi] - gmax[qi]);
    sPb[qi * 264 + tid] = (bf16_t)e;
    float wsum = wave_sum(e);
    if (lane == 0) reds[wave][qi] = wsum;
  }
  __syncthreads();
#pragma unroll
  for (int qi = 0; qi < 6; ++qi)
    ls[qi] = reds[0][qi] + reds[1][qi] + reds[2][qi] + reds[3][qi];
  if (tid == 0) {
#pragma unroll
    for (int qi = 0; qi < 6; ++qi) {
      float* pml = Part + (size_t)((h * 6 + qi) * 64 + c) * 42;
      pml[40] = gmax[qi];
      pml[41] = ls[qi];
    }
  }
  if (wave == 0) {
    int fm = lane & 15, quad = lane >> 4;
    f32x4 acc[3];
#pragma unroll
    for (int nt = 0; nt < 3; ++nt) acc[nt] = (f32x4){0.f, 0.f, 0.f, 0.f};
#pragma unroll
    for (int ks = 0; ks < 8; ++ks) {
      bf16x8 a = *(bf16x8*)&sPb[fm * 264 + ks * 32 + quad * 8];
#pragma unroll
      for (int nt = 0; nt < 3; ++nt) {
        bf16x8 bb = *(bf16x8*)&sVtb[(nt * 16 + fm) * 264 + ks * 32 + quad * 8];
        acc[nt] = __builtin_amdgcn_mfma_f32_16x16x32_bf16(a, bb, acc[nt], 0, 0, 0);
      }
    }
#pragma unroll
    for (int nt = 0; nt < 3; ++nt)
#pragma unroll
      for (int r = 0; r < 4; ++r) {
        int qi = quad * 4 + r;
        int p = nt * 16 + fm;
        if (qi < 6 && p < 40)
          Part[(size_t)((h * 6 + qi) * 64 + c) * 42 + p] = acc[nt][r];
      }
  }
}

// ------------- t2i attention pass 2: combine 64 partials, grid (24,2) --------
// lane p accumulates over the 64 chunk-partials (coalesced reads, 4-way ILP).
__global__ void attn_t2i_comb(const float* __restrict__ Part, float* __restrict__ O) {
  int b = blockIdx.y;
  int blk = blockIdx.x;  // h*6 + qi
  int qi = blk % 6;
  int h = blk / 6;
  int j = threadIdx.x;  // 64
  const float* base = Part + (size_t)b * 24 * 64 * 42 + (size_t)blk * 64 * 42;
  float m = base[j * 42 + 40], l = base[j * 42 + 41];
  float gmax = wave_max(m);
  gmax = __shfl(gmax, 0, 64);
  float sc = expf(m - gmax);
  float tot = wave_sum(l * sc);
  tot = __shfl(tot, 0, 64);
  float inv = 1.f / tot;
  __shared__ float ssc[64];
  ssc[j] = sc;
  __syncthreads();
  if (j < 40) {
    float a0 = 0.f, a1 = 0.f, a2 = 0.f, a3 = 0.f;
    for (int jj = 0; jj < 64; jj += 4) {
      a0 = fmaf(base[(jj + 0) * 42 + j], ssc[jj + 0], a0);
      a1 = fmaf(base[(jj + 1) * 42 + j], ssc[jj + 1], a1);
      a2 = fmaf(base[(jj + 2) * 42 + j], ssc[jj + 2], a2);
      a3 = fmaf(base[(jj + 3) * 42 + j], ssc[jj + 3], a3);
    }
    O[(size_t)b * 960 + (size_t)qi * 160 + h * 40 + j] = (a0 + a1 + a2 + a3) * inv;
  }
}

// ------- i2t attention: 16384 q vs 6 k, KV fused [12][320], grid (64,4,2) ----
__global__ __launch_bounds__(256) void attn_i2t(const float* __restrict__ Qp,
                                                const float* __restrict__ KV,
                                                float* __restrict__ O) {
  int h = blockIdx.y, b = blockIdx.z;
  int t = blockIdx.x * 256 + threadIdx.x;
  Qp += (size_t)b * LSEQ * 160;
  O += (size_t)b * LSEQ * 160;
  __shared__ float sk[6][40], sv[6][40];
  if (threadIdx.x < 240) {
    int tok = threadIdx.x / 40, p = threadIdx.x % 40;
    const float* base = KV + (size_t)(b * 6 + tok) * 320 + h * 40 + p;
    sk[tok][p] = base[0];
    sv[tok][p] = base[160];
  }
  __syncthreads();
  const float* q = Qp + (size_t)t * 160 + h * 40;
  float qr[40];
#pragma unroll
  for (int v = 0; v < 10; ++v) {
    float4 q4 = *(const float4*)(q + v * 4);
    qr[v * 4 + 0] = q4.x; qr[v * 4 + 1] = q4.y; qr[v * 4 + 2] = q4.z; qr[v * 4 + 3] = q4.w;
  }
  float s[6];
#pragma unroll
  for (int k = 0; k < 6; ++k) {
    float d = 0.f;
    for (int p = 0; p < 40; ++p) d += qr[p] * sk[k][p];
    s[k] = d * 0.15811388300841897f;
  }
  float mx = s[0];
#pragma unroll
  for (int k = 1; k < 6; ++k) mx = fmaxf(mx, s[k]);
  float sum = 0.f;
#pragma unroll
  for (int k = 0; k < 6; ++k) { s[k] = expf(s[k] - mx); sum += s[k]; }
  float inv = 1.f / sum;
  float* o = O + (size_t)t * 160 + h * 40;
#pragma unroll
  for (int v = 0; v < 10; ++v) {
    float o0 = 0.f, o1 = 0.f, o2 = 0.f, o3 = 0.f;
#pragma unroll
    for (int k = 0; k < 6; ++k) {
      float w = s[k];
      o0 += w * sv[k][v * 4 + 0];
      o1 += w * sv[k][v * 4 + 1];
      o2 += w * sv[k][v * 4 + 2];
      o3 += w * sv[k][v * 4 + 3];
    }
    *(float4*)(o + v * 4) = make_float4(o0 * inv, o1 * inv, o2 * inv, o3 * inv);
  }
}

// =======================================================================
extern "C" void kernel_launch(void* const* d_in, const int* in_sizes, int n_in,
                              void* d_out, int out_size, void* d_ws, size_t ws_size,
                              hipStream_t stream) {
  (void)in_sizes; (void)n_in; (void)out_size;
  const float* x       = (const float*)d_in[0];
  const float* coords  = (const float*)d_in[1];
  const int*   labels  = (const int*)  d_in[2];
  const float* ln_w    = (const float*)d_in[3];
  const float* ln_b    = (const float*)d_in[4];
  const float* in_w    = (const float*)d_in[5];
  const float* conv_w  = (const float*)d_in[6];
  const float* conv_b  = (const float*)d_in[7];
  const float* dt_bias = (const float*)d_in[8];
  const float* A_log   = (const float*)d_in[9];
  const float* Dp      = (const float*)d_in[10];
  const float* rms_w   = (const float*)d_in[11];
  const float* out_w   = (const float*)d_in[12];
  const float* gauss   = (const float*)d_in[13];
  const float* ptab    = (const float*)d_in[14];
  const float* sa_w    = (const float*)d_in[15];
  const float* sa_b    = (const float*)d_in[16];
  const float* t2i_w   = (const float*)d_in[17];
  const float* t2i_b   = (const float*)d_in[18];
  const float* t2i_ow  = (const float*)d_in[19];
  const float* t2i_ob  = (const float*)d_in[20];
  const float* i2t_w   = (const float*)d_in[21];
  const float* i2t_b   = (const float*)d_in[22];
  const float* i2t_ow  = (const float*)d_in[23];
  const float* i2t_ob  = (const float*)d_in[24];
  const float* norms_w = (const float*)d_in[25];
  const float* norms_b = (const float*)d_in[26];
  const float* mlp_w1  = (const float*)d_in[27];
  const float* mlp_b1  = (const float*)d_in[28];
  const float* mlp_w2  = (const float*)d_in[29];
  const float* mlp_b2  = (const float*)d_in[30];
  float* out = (float*)d_out;
  float* ws = (float*)d_ws;

  const size_t NEED = (size_t)(10485760 + 5242880 + 11665408 + 11534336 + 10485760 +
                               131072 + 131072 + 65536) * 4;
  if (ws_size < NEED) {
    ws_probe<<<1, 1, 0, stream>>>(out, (float)ws_size);
    return;
  }
  float* R_K = ws;                         // [2][16384][320]
  float* P   = ws + 10485760;              // scratch pool
  // ---- mamba-phase layout (per batch, reused) ----
  float* XN_     = P;                      // (LN'd input; dead after in_proj)
  float* SCHUNK_ = P;                      // reuses XN after in_proj
  float* ZB_     = P + 5242880;            // (z; live until gate_rms)
  float* XBC_    = P + 15728640;           // (xBC|dt; dead after conv/dt)
  float* SPREV_  = P + 15728640;           // reuses XBC
  float* CV_     = P + 27394048;           // (conv out; Y written in place)
  float* DT_     = P + 38928384;           // 131,072
  float* CA_     = P + 39059456;           // 131,072
  // ---- transformer-phase layout ----
  float* KPE_  = P;                        // 5,242,880
  float* T0_   = P + 5242880;              // [2][16384][160] t2i-K
  float* T3_   = P + 10485760;             // [2][16384][160] i2t-Q
  float* T1_   = P + 15728640;             // [2][16384][160] t2i-V
  float* T2_   = P + 26214400;             // [2][16384][160] i2t attn out
  float* PART_ = P + 36700160;             // [2][24][64][42]
  float* SM_   = P + 36829184;             // small token buffers
  float* QPE_  = SM_;
  float* QRY_  = SM_ + 3840;
  float* P3_   = SM_ + 7680;
  float* PO_   = SM_ + 19200;
  float* H_    = SM_ + 23040;
  float* Q160_ = SM_ + 35328;
  float* O160_ = SM_ + 37248;
  float* KV_   = SM_ + 39168;

  const long long sIMG160 = (long long)LSEQ * 160;
  const long long sIMG320 = (long long)LSEQ * CDIM;
  const int NOSPLIT = 1 << 30;

  // ======== mamba phase, per batch ========
  for (int b = 0; b < 2; ++b) {
    const float* xb = x + (size_t)b * CDIM * LSEQ;
    float* Kb = R_K + (size_t)b * LSEQ * CDIM;

    tln<<<LSEQ / 32, 256, 0, stream>>>(xb, ln_w, ln_b, XN_);

    // fused in_proj: cols [0,640) -> ZB_ (z), cols [640,1352) -> XBC_ (xBC|dt)
    gemm_bf<<<dim3(22, 128, 1), 256, 0, stream>>>(
        XN_, in_w, nullptr, nullptr, ZB_, XBC_, nullptr, nullptr, NOSPLIT,
        LSEQ, 1352, CDIM, CDIM, DIN, DIN, XBCW, 0, 0, 0);

    dt_kernel<<<LSEQ * NHH / 256, 256, 0, stream>>>(XBC_, dt_bias, DT_);
    conv2<<<dim3(11, 128), 256, 0, stream>>>(XBC_, conv_w, conv_b, CV_);

    scan_a<<<dim3(NCHUNK, NHH), 256, 0, stream>>>(CV_, DT_, A_log, SCHUNK_, CA_);
    scan_b<<<dim3(10, NHH), 256, 0, stream>>>(SCHUNK_, CA_, SPREV_);
    scan_c<<<dim3(NCHUNK, NHH), 256, 0, stream>>>(CV_, DT_, CA_, SPREV_, Dp, CV_);

    gate_rms<<<LSEQ, 256, 0, stream>>>(CV_, ZB_, rms_w);

    gemm_bf<<<dim3(5, 128, 1), 256, 0, stream>>>(
        CV_, out_w, nullptr, nullptr, Kb, nullptr, nullptr, nullptr, NOSPLIT,
        LSEQ, CDIM, DIN, YSTR, CDIM, NOSPLIT, 0, 0, 0, 0);
  }

  kpe_kernel<<<LSEQ * 160 / 256, 256, 0, stream>>>(gauss, KPE_);
  point_kernel<<<30, 64, 0, stream>>>(coords, labels, gauss, ptab, QPE_, QRY_);

  // ======== transformer phase, both batches per dispatch ========
  for (int i = 0; i < 2; ++i) {
    const float* saw = sa_w + (size_t)i * 4 * CDIM * CDIM;
    const float* sab = sa_b + (size_t)i * 4 * CDIM;
    smallmm<<<240, 256, 0, stream>>>(QRY_, (i == 0) ? nullptr : QPE_,
                                     saw, sab, P3_, 960, CDIM, 0, 0, 640);
    attn_self<<<dim3(4, 2), 128, 0, stream>>>(P3_, PO_);
    smallmm<<<80, 256, 0, stream>>>(PO_, nullptr, saw + 3 * 102400, sab + 3 * CDIM,
                                    QRY_, CDIM, CDIM, (i == 0) ? 0 : 1, 0, 0);
    ln_rows256<<<3, 256, 0, stream>>>(QRY_, norms_w + (size_t)(i * 4 + 0) * CDIM,
                                      norms_b + (size_t)(i * 4 + 0) * CDIM, 12);

    smallmm<<<40, 256, 0, stream>>>(QRY_, QPE_, t2i_w + (size_t)(i * 3 + 0) * 51200,
                                    t2i_b + (size_t)(i * 3 + 0) * 160, Q160_,
                                    160, CDIM, 0, 0, 160);
    // fused: cols 0-159 = t2i-K -> T0; cols 160-319 = i2t-Q -> T3.
    gemm_bf<<<dim3(5, 128, 2), 256, 0, stream>>>(
        R_K, t2i_w + (size_t)(i * 3 + 1) * 51200, t2i_b + (size_t)(i * 3 + 1) * 160,
        KPE_, T0_, T3_, i2t_w + (size_t)(i * 3 + 0) * 51200,
        i2t_b + (size_t)(i * 3 + 0) * 160, 160,
        LSEQ, 320, CDIM, CDIM, 160, 160, 160, 0, sIMG320, sIMG160);
    gemm_bf<<<dim3(3, 128, 2), 256, 0, stream>>>(
        R_K, t2i_w + (size_t)(i * 3 + 2) * 51200, t2i_b + (size_t)(i * 3 + 2) * 160,
        nullptr, T1_, nullptr, nullptr, nullptr, NOSPLIT,
        LSEQ, 160, CDIM, CDIM, 160, NOSPLIT, 0, 0, sIMG320, sIMG160);
    attn_t2i_part2<<<dim3(64, 4, 2), 256, 0, stream>>>(Q160_, T0_, T1_, PART_);
    attn_t2i_comb<<<dim3(24, 2), 64, 0, stream>>>(PART_, O160_);
    smallmm<<<80, 256, 0, stream>>>(O160_, nullptr, t2i_ow + (size_t)i * 51200,
                                    t2i_ob + (size_t)i * CDIM, QRY_,
                                    CDIM, 160, 1, 0, 0);
    ln_rows256<<<3, 256, 0, stream>>>(QRY_, norms_w + (size_t)(i * 4 + 1) * CDIM,
                                      norms_b + (size_t)(i * 4 + 1) * CDIM, 12);

    smallmm<<<256, 256, 0, stream>>>(QRY_, nullptr, mlp_w1 + (size_t)i * 1024 * CDIM,
                                     mlp_b1 + (size_t)i * 1024, H_, 1024, CDIM, 0, 1, 0);
    smallmm<<<80, 256, 0, stream>>>(H_, nullptr, mlp_w2 + (size_t)i * CDIM * 1024,
                                    mlp_b2 + (size_t)i * CDIM, QRY_, CDIM, 1024, 1, 0, 0);
    ln_rows256<<<3, 256, 0, stream>>>(QRY_, norms_w + (size_t)(i * 4 + 2) * CDIM,
                                      norms_b + (size_t)(i * 4 + 2) * CDIM, 12);

    smallmm<<<80, 256, 0, stream>>>(QRY_, QPE_, i2t_w + (size_t)(i * 3 + 1) * 51200,
                                    i2t_b + (size_t)(i * 3 + 1) * 160, KV_,
                                    320, CDIM, 0, 0, 160);
    attn_i2t<<<dim3(LSEQ / 256, 4, 2), 256, 0, stream>>>(T3_, KV_, T2_);
    gemm_bf<<<dim3(5, 128, 2), 256, 0, stream>>>(
        T2_, i2t_ow + (size_t)i * CDIM * 160, i2t_ob + (size_t)i * CDIM,
        nullptr, R_K, nullptr, nullptr, nullptr, NOSPLIT,
        LSEQ, CDIM, 160, 160, CDIM, NOSPLIT, 0, 1, sIMG160, sIMG320);
    if (i == 0) {
      ln_rows256<<<2 * LSEQ / 4, 256, 0, stream>>>(
          R_K, norms_w + (size_t)3 * CDIM, norms_b + (size_t)3 * CDIM, 2 * LSEQ);
    }
  }

  // final layernorm fused with transpose to output layout (C,L)
  for (int b = 0; b < 2; ++b) {
    lnt<<<LSEQ / 32, 256, 0, stream>>>(
        R_K + (size_t)b * LSEQ * CDIM, norms_w + (size_t)7 * CDIM,
        norms_b + (size_t)7 * CDIM, out + (size_t)b * CDIM * LSEQ);
  }
}

// Round 5
// 1035.561 us; speedup vs baseline: 1.7035x; 1.0012x over previous
//
#include <hip/hip_runtime.h>
#include <math.h>

#define LSEQ 16384
#define CDIM 320
#define DIN 640
#define NHH 8
#define CONVD 704
#define XBCW 712
#define YSTR 704
#define QCH 64
#define NCHUNK 256

typedef __bf16 bf16_t;
typedef __bf16 bf16x8 __attribute__((ext_vector_type(8)));
typedef __bf16 bf16x4 __attribute__((ext_vector_type(4)));
typedef float f32x4 __attribute__((ext_vector_type(4)));

// ---------------- reduction helpers ----------------
__device__ __forceinline__ float wave_sum(float v) {
#pragma unroll
  for (int o = 32; o > 0; o >>= 1) v += __shfl_down(v, o, 64);
  return v;
}
__device__ __forceinline__ float wave_max(float v) {
#pragma unroll
  for (int o = 32; o > 0; o >>= 1) v = fmaxf(v, __shfl_down(v, o, 64));
  return v;
}
__device__ __forceinline__ float block_sum256(float v, float* red) {
  int tid = threadIdx.x;
  v = wave_sum(v);
  __syncthreads();
  if ((tid & 63) == 0) red[tid >> 6] = v;
  __syncthreads();
  return red[0] + red[1] + red[2] + red[3];
}

__global__ void ws_probe(float* out, float v) { out[0] = v; }

// ---------------- fp32 -> bf16 elementwise (n % 4 == 0) ----------------
__global__ void cvt_bf(const float* __restrict__ src, bf16_t* __restrict__ dst, int n) {
  int i = (blockIdx.x * 256 + threadIdx.x) * 4;
  if (i >= n) return;
  float4 v = *(const float4*)(src + i);
  bf16x4 o;
  o[0] = (bf16_t)v.x; o[1] = (bf16_t)v.y; o[2] = (bf16_t)v.z; o[3] = (bf16_t)v.w;
  *(bf16x4*)(dst + i) = o;
}

// -------- fused transpose + layernorm: x[b] (C,L) -> out (L,C) bf16 ----------
__global__ __launch_bounds__(256) void tln(const float* __restrict__ x,
                                           const float* __restrict__ w,
                                           const float* __restrict__ b,
                                           bf16_t* __restrict__ out) {
  __shared__ float sT[32][321];
  int t0 = blockIdx.x * 32;
  int tid = threadIdx.x;
  for (int i = tid; i < 2560; i += 256) {
    int c = i >> 3, j4 = i & 7;
    float4 v = *(const float4*)(x + (size_t)c * LSEQ + t0 + j4 * 4);
    sT[j4 * 4 + 0][c] = v.x;
    sT[j4 * 4 + 1][c] = v.y;
    sT[j4 * 4 + 2][c] = v.z;
    sT[j4 * 4 + 3][c] = v.w;
  }
  __syncthreads();
  int wave = tid >> 6, lane = tid & 63;
  for (int tt = wave; tt < 32; tt += 4) {
    float xv[5];
    float s = 0.f;
#pragma unroll
    for (int k = 0; k < 5; ++k) { xv[k] = sT[tt][lane + 64 * k]; s += xv[k]; }
    s = wave_sum(s); s = __shfl(s, 0, 64);
    float mean = s * (1.f / 320.f);
    float v = 0.f;
#pragma unroll
    for (int k = 0; k < 5; ++k) { float d = xv[k] - mean; v += d * d; }
    v = wave_sum(v); v = __shfl(v, 0, 64);
    float rstd = rsqrtf(v * (1.f / 320.f) + 1e-5f);
    bf16_t* op = out + (size_t)(t0 + tt) * CDIM;
#pragma unroll
    for (int k = 0; k < 5; ++k) {
      int i = lane + 64 * k;
      op[i] = (bf16_t)((xv[k] - mean) * rstd * w[i] + b[i]);
    }
  }
}

// -------- fused layernorm + transpose: in (L,C) -> out (C,L), LN over C ------
__global__ __launch_bounds__(256) void lnt(const float* __restrict__ in,
                                           const float* __restrict__ w,
                                           const float* __restrict__ b,
                                           float* __restrict__ out) {
  __shared__ float sT[CDIM][33];
  int t0 = blockIdx.x * 32;
  int tid = threadIdx.x;
  int wave = tid >> 6, lane = tid & 63;
  for (int tt = wave; tt < 32; tt += 4) {
    const float* xp = in + (size_t)(t0 + tt) * CDIM;
    float x[5];
    float s = 0.f;
#pragma unroll
    for (int k = 0; k < 5; ++k) { x[k] = xp[lane + 64 * k]; s += x[k]; }
    s = wave_sum(s); s = __shfl(s, 0, 64);
    float mean = s * (1.f / 320.f);
    float v = 0.f;
#pragma unroll
    for (int k = 0; k < 5; ++k) { float d = x[k] - mean; v += d * d; }
    v = wave_sum(v); v = __shfl(v, 0, 64);
    float rstd = rsqrtf(v * (1.f / 320.f) + 1e-5f);
#pragma unroll
    for (int k = 0; k < 5; ++k) {
      int i = lane + 64 * k;
      sT[i][tt] = (x[k] - mean) * rstd * w[i] + b[i];
    }
  }
  __syncthreads();
  for (int i = tid; i < 320 * 32; i += 256) {
    int cc = i >> 5, t = i & 31;
    out[(size_t)cc * LSEQ + t0 + t] = sT[cc][t];
  }
}

// ---------------- layernorm rows (D=320), one wave per row, 4 rows/block -----
__global__ __launch_bounds__(256) void ln_rows256(float* __restrict__ io,
                                                  const float* __restrict__ w,
                                                  const float* __restrict__ b,
                                                  int nrows) {
  int row = blockIdx.x * 4 + (threadIdx.x >> 6);
  if (row >= nrows) return;
  float* xp = io + (size_t)row * CDIM;
  int lane = threadIdx.x & 63;
  float x[5];
  float s = 0.f;
#pragma unroll
  for (int k = 0; k < 5; ++k) { x[k] = xp[lane + 64 * k]; s += x[k]; }
  s = wave_sum(s); s = __shfl(s, 0, 64);
  float mean = s * (1.f / 320.f);
  float v = 0.f;
#pragma unroll
  for (int k = 0; k < 5; ++k) { float t = x[k] - mean; v += t * t; }
  v = wave_sum(v); v = __shfl(v, 0, 64);
  float rstd = rsqrtf(v * (1.f / 320.f) + 1e-5f);
#pragma unroll
  for (int k = 0; k < 5; ++k) {
    int i = lane + 64 * k;
    xp[i] = (x[k] - mean) * rstd * w[i] + b[i];
  }
}

// ------------- bf16 MFMA GEMM, 128x64 tile, XCD-chunked swizzle --------------
// C = (A (+pe)) @ [W;W2]^T (+bias/bias2) (+=C).  Column split at nsplit.
// abf: A is bf16 (pe must be null).  wbf: W/W2 are bf16.
__global__ __launch_bounds__(256) void gemm_bf(
    const void* __restrict__ A, const void* __restrict__ W,
    const float* __restrict__ bias, const float* __restrict__ pe,
    float* __restrict__ C, float* __restrict__ C2,
    const void* __restrict__ W2, const float* __restrict__ bias2, int wsplit,
    int M, int N, int K, int lda, int ldc, int nsplit, int ldc2,
    int addC, int abf, int wbf, long long sA, long long sC) {
  int z = blockIdx.z;
  C += (size_t)z * sC;
  if (C2) C2 += (size_t)z * sC;
  // bijective XCD-chunked swizzle
  int gx = gridDim.x;
  int nwg = gx * gridDim.y;
  int lin = blockIdx.y * gx + blockIdx.x;
  int xcd = lin & 7, idx = lin >> 3;
  int q = nwg >> 3, r = nwg & 7;
  int base = (xcd < r) ? xcd * (q + 1) : r * (q + 1) + (xcd - r) * q;
  int lin2 = base + idx;
  int mblk = lin2 / gx, nblk = lin2 % gx;
  int m0 = mblk << 7, n0 = nblk << 6;

  __shared__ __align__(16) bf16_t As[2][4096];
  __shared__ __align__(16) bf16_t Ws[2][2048];
  int tid = threadIdx.x;
  int wave = tid >> 6, lane = tid & 63;
  int fm = lane & 15, quad = lane >> 4;
  int rA = tid >> 1, hA = tid & 1;  // A row (0..127), col-half (16 elems)
  int rW = tid >> 2, qW = tid & 3;  // W row (0..63), col-quad (8 elems)
  const float* ag = nullptr;
  const bf16_t* agb = nullptr;
  const float* peg = nullptr;
  if (abf) {
    agb = (const bf16_t*)A + (size_t)z * sA + (size_t)(m0 + rA) * lda + hA * 16;
  } else {
    ag = (const float*)A + (size_t)z * sA + (size_t)(m0 + rA) * lda + hA * 16;
    if (pe) peg = pe + (size_t)(m0 + rA) * lda + hA * 16;
  }
  int wRow = n0 + rW;
  bool wok = wRow < N;
  const float* wg = nullptr;
  const bf16_t* wgb = nullptr;
  {
    const void* Wsel = (wRow < wsplit) ? W : W2;
    int wr = (wRow < wsplit) ? wRow : wRow - wsplit;
    if (wbf) wgb = (const bf16_t*)Wsel + (size_t)wr * K + qW * 8;
    else     wg  = (const float*)Wsel + (size_t)wr * K + qW * 8;
  }
  int aoff = (rA >> 4) * 512 + (hA * 32 + (rA & 15)) * 8;
  int woff = (rW >> 4) * 512 + (qW * 16 + (rW & 15)) * 8;

  f32x4 acc[2][4];
#pragma unroll
  for (int i = 0; i < 2; ++i)
#pragma unroll
    for (int j = 0; j < 4; ++j) acc[i][j] = (f32x4){0.f, 0.f, 0.f, 0.f};

  bf16x8 ra0, ra1, rw;
  float4 pa0, pa1, pa2, pa3, pw0, pw1;
  auto loadG = [&](int k0) {
    if (abf) {
      ra0 = *(const bf16x8*)(agb + k0);
      ra1 = *(const bf16x8*)(agb + k0 + 8);
    } else {
      pa0 = *(const float4*)(ag + k0);
      pa1 = *(const float4*)(ag + k0 + 4);
      pa2 = *(const float4*)(ag + k0 + 8);
      pa3 = *(const float4*)(ag + k0 + 12);
      if (peg) {
        float4 q0 = *(const float4*)(peg + k0);
        float4 q1 = *(const float4*)(peg + k0 + 4);
        float4 q2 = *(const float4*)(peg + k0 + 8);
        float4 q3 = *(const float4*)(peg + k0 + 12);
        pa0.x += q0.x; pa0.y += q0.y; pa0.z += q0.z; pa0.w += q0.w;
        pa1.x += q1.x; pa1.y += q1.y; pa1.z += q1.z; pa1.w += q1.w;
        pa2.x += q2.x; pa2.y += q2.y; pa2.z += q2.z; pa2.w += q2.w;
        pa3.x += q3.x; pa3.y += q3.y; pa3.z += q3.z; pa3.w += q3.w;
      }
    }
    if (wbf) {
      if (wok) rw = *(const bf16x8*)(wgb + k0);
      else {
#pragma unroll
        for (int j = 0; j < 8; ++j) rw[j] = (bf16_t)0.f;
      }
    } else {
      pw0 = make_float4(0.f, 0.f, 0.f, 0.f);
      pw1 = pw0;
      if (wok) {
        pw0 = *(const float4*)(wg + k0);
        pw1 = *(const float4*)(wg + k0 + 4);
      }
    }
  };
  auto packLDS = [&](int buf) {
    if (!abf) {
      ra0[0] = (bf16_t)pa0.x; ra0[1] = (bf16_t)pa0.y; ra0[2] = (bf16_t)pa0.z; ra0[3] = (bf16_t)pa0.w;
      ra0[4] = (bf16_t)pa1.x; ra0[5] = (bf16_t)pa1.y; ra0[6] = (bf16_t)pa1.z; ra0[7] = (bf16_t)pa1.w;
      ra1[0] = (bf16_t)pa2.x; ra1[1] = (bf16_t)pa2.y; ra1[2] = (bf16_t)pa2.z; ra1[3] = (bf16_t)pa2.w;
      ra1[4] = (bf16_t)pa3.x; ra1[5] = (bf16_t)pa3.y; ra1[6] = (bf16_t)pa3.z; ra1[7] = (bf16_t)pa3.w;
    }
    *(bf16x8*)&As[buf][aoff] = ra0;
    *(bf16x8*)&As[buf][aoff + 128] = ra1;
    if (!wbf) {
      rw[0] = (bf16_t)pw0.x; rw[1] = (bf16_t)pw0.y; rw[2] = (bf16_t)pw0.z; rw[3] = (bf16_t)pw0.w;
      rw[4] = (bf16_t)pw1.x; rw[5] = (bf16_t)pw1.y; rw[6] = (bf16_t)pw1.z; rw[7] = (bf16_t)pw1.w;
    }
    *(bf16x8*)&Ws[buf][woff] = rw;
  };

  int nk = K >> 5;
  loadG(0);
  packLDS(0);
  __syncthreads();
  for (int i = 0; i < nk; ++i) {
    int buf = i & 1;
    bool more = (i + 1 < nk);
    if (more) loadG((i + 1) << 5);
    int ab = wave * 1024 + lane * 8;
    bf16x8 af0 = *(bf16x8*)&As[buf][ab];
    bf16x8 af1 = *(bf16x8*)&As[buf][ab + 512];
    bf16x8 b0 = *(bf16x8*)&Ws[buf][lane * 8];
    bf16x8 b1 = *(bf16x8*)&Ws[buf][512 + lane * 8];
    bf16x8 b2 = *(bf16x8*)&Ws[buf][1024 + lane * 8];
    bf16x8 b3 = *(bf16x8*)&Ws[buf][1536 + lane * 8];
    acc[0][0] = __builtin_amdgcn_mfma_f32_16x16x32_bf16(af0, b0, acc[0][0], 0, 0, 0);
    acc[0][1] = __builtin_amdgcn_mfma_f32_16x16x32_bf16(af0, b1, acc[0][1], 0, 0, 0);
    acc[0][2] = __builtin_amdgcn_mfma_f32_16x16x32_bf16(af0, b2, acc[0][2], 0, 0, 0);
    acc[0][3] = __builtin_amdgcn_mfma_f32_16x16x32_bf16(af0, b3, acc[0][3], 0, 0, 0);
    acc[1][0] = __builtin_amdgcn_mfma_f32_16x16x32_bf16(af1, b0, acc[1][0], 0, 0, 0);
    acc[1][1] = __builtin_amdgcn_mfma_f32_16x16x32_bf16(af1, b1, acc[1][1], 0, 0, 0);
    acc[1][2] = __builtin_amdgcn_mfma_f32_16x16x32_bf16(af1, b2, acc[1][2], 0, 0, 0);
    acc[1][3] = __builtin_amdgcn_mfma_f32_16x16x32_bf16(af1, b3, acc[1][3], 0, 0, 0);
    if (more) {
      packLDS(buf ^ 1);
      __syncthreads();
    }
  }
#pragma unroll
  for (int ms = 0; ms < 2; ++ms)
#pragma unroll
    for (int ns = 0; ns < 4; ++ns) {
      int n = n0 + ns * 16 + fm;
      if (n >= N) continue;
      float bv = 0.f;
      if (n < wsplit) { if (bias) bv = bias[n]; }
      else            { if (bias2) bv = bias2[n - wsplit]; }
      float* Cb;
      int ldcb, nc;
      if (n < nsplit) { Cb = C; ldcb = ldc; nc = n; }
      else           { Cb = C2; ldcb = ldc2; nc = n - nsplit; }
#pragma unroll
      for (int rr = 0; rr < 4; ++rr) {
        int m = m0 + wave * 32 + ms * 16 + quad * 4 + rr;
        float v = acc[ms][ns][rr] + bv;
        size_t off = (size_t)m * ldcb + nc;
        if (addC) v += Cb[off];
        Cb[off] = v;
      }
    }
}

// -------- small matmul (token side), M=12 fixed, wave-per-output-column ------
__global__ __launch_bounds__(256) void smallmm(
    const float* __restrict__ A, const float* __restrict__ A2,
    const float* __restrict__ W, const float* __restrict__ bias,
    float* __restrict__ C, int N, int K, int addC, int relu, int a2lim) {
  int wave = threadIdx.x >> 6, lane = threadIdx.x & 63;
  int n = blockIdx.x * 4 + wave;
  if (n >= N) return;
  const float* w = W + (size_t)n * K;
  bool useA2 = (A2 != nullptr) && (n < a2lim);
  float part[12];
#pragma unroll
  for (int m = 0; m < 12; ++m) part[m] = 0.f;
  for (int k0 = 0; k0 < K; k0 += 64) {
    int k = k0 + lane;
    if (k < K) {
      float wv = w[k];
      const float* ap = A + k;
      if (useA2) {
        const float* ap2 = A2 + k;
#pragma unroll
        for (int m = 0; m < 12; ++m)
          part[m] = fmaf(ap[(size_t)m * K] + ap2[(size_t)m * K], wv, part[m]);
      } else {
#pragma unroll
        for (int m = 0; m < 12; ++m)
          part[m] = fmaf(ap[(size_t)m * K], wv, part[m]);
      }
    }
  }
  float bv = bias ? bias[n] : 0.f;
#pragma unroll
  for (int m = 0; m < 12; ++m) {
    float dot = wave_sum(part[m]);
    if (lane == 0) {
      float v = dot + bv;
      if (relu) v = fmaxf(v, 0.f);
      size_t off = (size_t)m * N + n;
      if (addC) v += C[off];
      C[off] = v;
    }
  }
}

// ---------------- dt = softplus(dt_raw + dt_bias), layout (h,t) --------------
__global__ void dt_kernel(const float* __restrict__ XBC, const float* __restrict__ dt_bias,
                          float* __restrict__ dtbuf) {
  int idx = blockIdx.x * 256 + threadIdx.x;
  if (idx >= LSEQ * NHH) return;
  int h = idx & 7;
  int t = idx >> 3;
  float v = XBC[(size_t)t * XBCW + 704 + h] + dt_bias[h];
  float sp = (v > 20.f) ? v : log1pf(expf(v));
  dtbuf[(size_t)h * LSEQ + t] = sp;
}

// ------- causal depthwise conv + silu, sliding-window registers --------------
__global__ __launch_bounds__(256) void conv2(const float* __restrict__ XBC,
                                             const float* __restrict__ conv_w,
                                             const float* __restrict__ conv_b,
                                             float* __restrict__ Cv) {
  int lane = threadIdx.x & 63, wv = threadIdx.x >> 6;
  int d = blockIdx.x * 64 + lane;
  int t0 = (blockIdx.y * 4 + wv) * 32;
  float w0 = conv_w[d * 4 + 0], w1 = conv_w[d * 4 + 1];
  float w2 = conv_w[d * 4 + 2], w3 = conv_w[d * 4 + 3];
  float bv = conv_b[d];
  const float* src = XBC + d;
  float xm3, xm2, xm1;
  if (t0 == 0) {
    xm3 = 0.f; xm2 = 0.f; xm1 = 0.f;
  } else {
    xm3 = src[(size_t)(t0 - 3) * XBCW];
    xm2 = src[(size_t)(t0 - 2) * XBCW];
    xm1 = src[(size_t)(t0 - 1) * XBCW];
  }
#pragma unroll 8
  for (int t = t0; t < t0 + 32; ++t) {
    float xt = src[(size_t)t * XBCW];
    float a = bv + xm3 * w0 + xm2 * w1 + xm1 * w2 + xt * w3;
    Cv[(size_t)t * CONVD + d] = a / (1.f + expf(-a));
    xm3 = xm2; xm2 = xm1; xm1 = xt;
  }
}

// ---------------- scan phase A: per-chunk states + cumulative log-decay ------
__global__ __launch_bounds__(256) void scan_a(const float* __restrict__ Cv,
                                              const float* __restrict__ dtbuf,
                                              const float* __restrict__ A_log,
                                              float* __restrict__ Schunk,
                                              float* __restrict__ cabuf) {
  int c = blockIdx.x, h = blockIdx.y;
  int t0 = c * QCH;
  __shared__ float sdt[64], sca[64], sw[64];
  __shared__ __align__(16) float sB[64][36];
  __shared__ __align__(16) float sXt[80][68];
  int tid = threadIdx.x;
  float Aval = -expf(A_log[h]);
  if (tid < 64) sdt[tid] = dtbuf[(size_t)h * LSEQ + t0 + tid];
  __syncthreads();
  if (tid == 0) {
    float run = 0.f;
    for (int j = 0; j < 64; ++j) { run += sdt[j] * Aval; sca[j] = run; }
  }
  __syncthreads();
  float caend = sca[63];
  if (tid < 64) {
    sw[tid] = expf(caend - sca[tid]) * sdt[tid];
    cabuf[(size_t)h * LSEQ + t0 + tid] = sca[tid];
  }
  for (int i = tid; i < 2048; i += 256) {
    int j = i >> 5, n = i & 31;
    sB[j][n] = Cv[(size_t)(t0 + j) * CONVD + 640 + n];
  }
  for (int i = tid; i < 5120; i += 256) {
    int j = i / 80, p = i % 80;
    sXt[p][j] = Cv[(size_t)(t0 + j) * CONVD + h * 80 + p];
  }
  __syncthreads();
  int n = tid >> 3, pb = tid & 7;
  float acc[10];
#pragma unroll
  for (int u = 0; u < 10; ++u) acc[u] = 0.f;
  for (int jb = 0; jb < 16; ++jb) {
    float wB[4];
#pragma unroll
    for (int jj = 0; jj < 4; ++jj) {
      int j = jb * 4 + jj;
      wB[jj] = sw[j] * sB[j][n];
    }
#pragma unroll
    for (int u = 0; u < 10; ++u) {
      int p = pb * 10 + u;
      float4 x4 = *(const float4*)&sXt[p][jb * 4];
      acc[u] += wB[0] * x4.x + wB[1] * x4.y + wB[2] * x4.z + wB[3] * x4.w;
    }
  }
  float* outp = Schunk + (size_t)(h * NCHUNK + c) * 2560;
#pragma unroll
  for (int u = 0; u < 10; ++u) outp[n * 80 + pb * 10 + u] = acc[u];
}

// ---------------- scan phase B: sequential over chunks, 80 blocks ------------
__global__ __launch_bounds__(256) void scan_b(const float* __restrict__ Schunk,
                                              const float* __restrict__ cabuf,
                                              float* __restrict__ Sprev) {
  int pc = blockIdx.x, h = blockIdx.y;
  __shared__ float sdec[256];
  int tid = threadIdx.x;
  sdec[tid] = expf(cabuf[(size_t)h * LSEQ + tid * 64 + 63]);
  __syncthreads();
  int e = pc * 256 + tid;
  const float* base = Schunk + (size_t)h * NCHUNK * 2560 + e;
  float* pbase = Sprev + (size_t)h * NCHUNK * 2560 + e;
  float s = 0.f;
  float v = base[0];
  for (int c = 0; c < NCHUNK; ++c) {
    float vn = (c < NCHUNK - 1) ? base[(size_t)(c + 1) * 2560] : 0.f;
    pbase[(size_t)c * 2560] = s;
    s = s * sdec[c] + v;
    v = vn;
  }
}

// ---------------- scan phase C: MFMA version; Y in-place over Cv X-cols ------
__global__ __launch_bounds__(256) void scan_c(const float* __restrict__ Cv,
                                              const float* __restrict__ dtbuf,
                                              const float* __restrict__ cabuf,
                                              const float* __restrict__ Sprev,
                                              const float* __restrict__ Dp,
                                              float* __restrict__ Y) {
  int c = blockIdx.x, h = blockIdx.y;
  int t0 = c * QCH;
  __shared__ float sdt[64], sca[64], sexp[64];
  __shared__ __align__(16) bf16_t sC[64 * 40];
  __shared__ __align__(16) bf16_t sB[64 * 40];
  __shared__ __align__(16) bf16_t sXt[80 * 72];
  __shared__ __align__(16) bf16_t sSt[80 * 40];
  __shared__ __align__(16) bf16_t sP[64 * 72];
  int tid = threadIdx.x;
  int wave = tid >> 6, lane = tid & 63;
  int fm = lane & 15, quad = lane >> 4;
  if (tid < 64) {
    sdt[tid] = dtbuf[(size_t)h * LSEQ + t0 + tid];
    float cav = cabuf[(size_t)h * LSEQ + t0 + tid];
    sca[tid] = cav;
    sexp[tid] = expf(cav);
  }
  for (int i = tid; i < 2048; i += 256) {
    int j = i >> 5, n = i & 31;
    size_t base = (size_t)(t0 + j) * CONVD;
    sB[j * 40 + n] = (bf16_t)Cv[base + 640 + n];
    sC[j * 40 + n] = (bf16_t)Cv[base + 672 + n];
  }
  for (int i = tid; i < 5120; i += 256) {
    int j = i / 80, p = i % 80;
    sXt[p * 72 + j] = (bf16_t)Cv[(size_t)(t0 + j) * CONVD + h * 80 + p];
  }
  {
    const float* sp = Sprev + (size_t)(h * NCHUNK + c) * 2560;
    for (int i = tid; i < 2560; i += 256) {
      int n = i / 80, p = i % 80;
      sSt[p * 40 + n] = (bf16_t)sp[i];
    }
  }
  __syncthreads();
  int m0 = wave * 16;
  int jbase = m0 + quad * 4;
  bf16x8 afC = *(bf16x8*)&sC[(m0 + fm) * 40 + quad * 8];
  f32x4 accS[4];
#pragma unroll
  for (int nt = 0; nt < 4; ++nt) {
    bf16x8 bf = *(bf16x8*)&sB[(nt * 16 + fm) * 40 + quad * 8];
    f32x4 zero = (f32x4){0.f, 0.f, 0.f, 0.f};
    accS[nt] = __builtin_amdgcn_mfma_f32_16x16x32_bf16(afC, bf, zero, 0, 0, 0);
  }
  float scaj[4];
#pragma unroll
  for (int r = 0; r < 4; ++r) scaj[r] = sca[jbase + r];
#pragma unroll
  for (int nt = 0; nt < 4; ++nt) {
    int s = nt * 16 + fm;
    float dts = sdt[s], scas = sca[s];
#pragma unroll
    for (int r = 0; r < 4; ++r) {
      int j = jbase + r;
      float v = 0.f;
      if (s <= j) v = accS[nt][r] * dts * expf(scaj[r] - scas);
      sP[j * 72 + s] = (bf16_t)v;
    }
  }
  f32x4 acc[5];
#pragma unroll
  for (int pt = 0; pt < 5; ++pt) {
    bf16x8 bf = *(bf16x8*)&sSt[(pt * 16 + fm) * 40 + quad * 8];
    f32x4 zero = (f32x4){0.f, 0.f, 0.f, 0.f};
    acc[pt] = __builtin_amdgcn_mfma_f32_16x16x32_bf16(afC, bf, zero, 0, 0, 0);
  }
  float gj[4];
#pragma unroll
  for (int r = 0; r < 4; ++r) gj[r] = sexp[jbase + r];
#pragma unroll
  for (int pt = 0; pt < 5; ++pt)
#pragma unroll
    for (int r = 0; r < 4; ++r) acc[pt][r] *= gj[r];
  bf16x8 afP0 = *(bf16x8*)&sP[(m0 + fm) * 72 + 0 + quad * 8];
  bf16x8 afP1 = *(bf16x8*)&sP[(m0 + fm) * 72 + 32 + quad * 8];
#pragma unroll
  for (int pt = 0; pt < 5; ++pt) {
    bf16x8 bx0 = *(bf16x8*)&sXt[(pt * 16 + fm) * 72 + 0 + quad * 8];
    bf16x8 bx1 = *(bf16x8*)&sXt[(pt * 16 + fm) * 72 + 32 + quad * 8];
    acc[pt] = __builtin_amdgcn_mfma_f32_16x16x32_bf16(afP0, bx0, acc[pt], 0, 0, 0);
    acc[pt] = __builtin_amdgcn_mfma_f32_16x16x32_bf16(afP1, bx1, acc[pt], 0, 0, 0);
  }
  float dval = Dp[h];
#pragma unroll
  for (int pt = 0; pt < 5; ++pt) {
    int p = pt * 16 + fm;
#pragma unroll
    for (int r = 0; r < 4; ++r) {
      int j = jbase + r;
      float xv = (float)sXt[p * 72 + j];
      Y[(size_t)(t0 + j) * YSTR + h * 80 + p] = acc[pt][r] + dval * xv;
    }
  }
}

// ------- y *= silu(z); rmsnorm * rms_w -> bf16 out (register-resident) -------
__global__ __launch_bounds__(256) void gate_rms(const float* __restrict__ Y,
                                                const float* __restrict__ Z,
                                                const float* __restrict__ rms_w,
                                                bf16_t* __restrict__ YB) {
  __shared__ float red[4];
  size_t row = blockIdx.x;
  const float* y = Y + row * YSTR;
  const float* z = Z + row * DIN;
  bf16_t* yo = YB + row * DIN;
  int tid = threadIdx.x;
  float g0, g1, g2 = 0.f;
  {
    float zi = z[tid];
    g0 = y[tid] * (zi / (1.f + expf(-zi)));
    zi = z[tid + 256];
    g1 = y[tid + 256] * (zi / (1.f + expf(-zi)));
    if (tid + 512 < DIN) {
      zi = z[tid + 512];
      g2 = y[tid + 512] * (zi / (1.f + expf(-zi)));
    }
  }
  float ss = g0 * g0 + g1 * g1 + g2 * g2;
  float tot = block_sum256(ss, red);
  float r = rsqrtf(tot / (float)DIN + 1e-5f);
  yo[tid] = (bf16_t)(g0 * r * rms_w[tid]);
  yo[tid + 256] = (bf16_t)(g1 * r * rms_w[tid + 256]);
  if (tid + 512 < DIN) yo[tid + 512] = (bf16_t)(g2 * r * rms_w[tid + 512]);
}

// ---------------- dense image PE ----------------
__global__ void kpe_kernel(const float* __restrict__ gauss, float* __restrict__ KPE) {
  int idx = blockIdx.x * 256 + threadIdx.x;
  if (idx >= LSEQ * 160) return;
  int f = idx % 160, t = idx / 160;
  int d = t >> 10, hh = (t >> 5) & 31, w = t & 31;
  float vx = 2.f * ((d + 0.5f) / 16.f) - 1.f;
  float vy = 2.f * ((hh + 0.5f) / 32.f) - 1.f;
  float vz = 2.f * ((w + 0.5f) / 32.f) - 1.f;
  float cc = 6.28318530717958647692f * (vx * gauss[f] + vy * gauss[160 + f] + vz * gauss[320 + f]);
  KPE[(size_t)t * CDIM + f] = sinf(cc);
  KPE[(size_t)t * CDIM + 160 + f] = cosf(cc);
}

// ---------------- point embeddings (both batches: 12 points) -----------------
__global__ void point_kernel(const float* __restrict__ coords, const int* __restrict__ labels,
                             const float* __restrict__ gauss, const float* __restrict__ ptab,
                             float* __restrict__ qpe, float* __restrict__ queries) {
  int idx = blockIdx.x * 64 + threadIdx.x;
  if (idx >= 12 * 160) return;
  int f = idx % 160, pt = idx / 160;
  const float* co = coords + pt * 3;
  float vx = 2.f * (co[0] / 128.f) - 1.f;
  float vy = 2.f * (co[1] / 256.f) - 1.f;
  float vz = 2.f * (co[2] / 256.f) - 1.f;
  float cc = 6.28318530717958647692f * (vx * gauss[f] + vy * gauss[160 + f] + vz * gauss[320 + f]);
  int lab = labels[pt];
  float sv = sinf(cc) + ptab[lab * CDIM + f];
  float cv = cosf(cc) + ptab[lab * CDIM + 160 + f];
  qpe[pt * CDIM + f] = sv;       qpe[pt * CDIM + 160 + f] = cv;
  queries[pt * CDIM + f] = sv;   queries[pt * CDIM + 160 + f] = cv;
}

// --------- self-attn over 6 tokens from fused P3[12][960], grid (4,2) --------
__global__ void attn_self(const float* __restrict__ P3, float* __restrict__ O) {
  int h = blockIdx.x, b = blockIdx.y;
  __shared__ float sq[6][80], sk[6][80], sv[6][80], sw[6][6];
  int tid = threadIdx.x;  // 128
  for (int i = tid; i < 480; i += 128) {
    int tok = i / 80, p = i % 80;
    const float* base = P3 + (size_t)(b * 6 + tok) * 960 + h * 80 + p;
    sq[tok][p] = base[0]; sk[tok][p] = base[320]; sv[tok][p] = base[640];
  }
  __syncthreads();
  if (tid < 36) {
    int qi = tid / 6, ki = tid % 6;
    float d = 0.f;
    for (int p = 0; p < 80; ++p) d += sq[qi][p] * sk[ki][p];
    sw[qi][ki] = d * 0.11180339887498948f;  // 1/sqrt(80)
  }
  __syncthreads();
  if (tid < 6) {
    float mx = sw[tid][0];
    for (int k = 1; k < 6; ++k) mx = fmaxf(mx, sw[tid][k]);
    float s = 0.f;
    for (int k = 0; k < 6; ++k) { float e = expf(sw[tid][k] - mx); sw[tid][k] = e; s += e; }
    float inv = 1.f / s;
    for (int k = 0; k < 6; ++k) sw[tid][k] *= inv;
  }
  __syncthreads();
  for (int i = tid; i < 480; i += 128) {
    int qi = i / 80, p = i % 80;
    float o = 0.f;
    for (int k = 0; k < 6; ++k) o += sw[qi][k] * sv[k][p];
    O[(size_t)(b * 6 + qi) * CDIM + h * 80 + p] = o;
  }
}

// ------------- t2i attention pass 1: LDS + MFMA PV, grid (64,4,2) ------------
__global__ __launch_bounds__(256) void attn_t2i_part2(const float* __restrict__ Qp,
                                                      const float* __restrict__ Kp,
                                                      const float* __restrict__ Vp,
                                                      float* __restrict__ Part) {
  int b = blockIdx.z, h = blockIdx.y, c = blockIdx.x;
  Qp += (size_t)b * 960;
  Kp += (size_t)b * LSEQ * 160;
  Vp += (size_t)b * LSEQ * 160;
  Part += (size_t)b * 24 * 64 * 42;
  __shared__ float sq[240];
  __shared__ float redm[4][6], reds[4][6];
  __shared__ __align__(16) bf16_t sPb[16 * 264];
  __shared__ __align__(16) bf16_t sVtb[48 * 264];
  int tid = threadIdx.x;
  int wave = tid >> 6, lane = tid & 63;
  if (tid < 240) sq[tid] = Qp[(size_t)(tid / 40) * 160 + h * 40 + (tid % 40)];
  __syncthreads();
  int t = c * 256 + tid;
  const float* kp = Kp + (size_t)t * 160 + h * 40;
  float kr[40];
#pragma unroll
  for (int v = 0; v < 10; ++v) {
    float4 k4 = *(const float4*)(kp + v * 4);
    kr[v * 4 + 0] = k4.x; kr[v * 4 + 1] = k4.y; kr[v * 4 + 2] = k4.z; kr[v * 4 + 3] = k4.w;
  }
  const float* vp = Vp + (size_t)t * 160 + h * 40;
#pragma unroll
  for (int v = 0; v < 10; ++v) {
    float4 v4 = *(const float4*)(vp + v * 4);
    sVtb[(v * 4 + 0) * 264 + tid] = (bf16_t)v4.x;
    sVtb[(v * 4 + 1) * 264 + tid] = (bf16_t)v4.y;
    sVtb[(v * 4 + 2) * 264 + tid] = (bf16_t)v4.z;
    sVtb[(v * 4 + 3) * 264 + tid] = (bf16_t)v4.w;
  }
  float s[6];
#pragma unroll
  for (int qi = 0; qi < 6; ++qi) {
    float d = 0.f;
#pragma unroll
    for (int p = 0; p < 40; ++p) d += sq[qi * 40 + p] * kr[p];
    s[qi] = d * 0.15811388300841897f;  // 1/sqrt(40)
  }
#pragma unroll
  for (int qi = 0; qi < 6; ++qi) {
    float wm = wave_max(s[qi]);
    if (lane == 0) redm[wave][qi] = wm;
  }
  __syncthreads();
  float gmax[6], ls[6];
#pragma unroll
  for (int qi = 0; qi < 6; ++qi)
    gmax[qi] = fmaxf(fmaxf(redm[0][qi], redm[1][qi]), fmaxf(redm[2][qi], redm[3][qi]));
#pragma unroll
  for (int qi = 0; qi < 6; ++qi) {
    float e = expf(s[qi] - gmax[qi]);
    sPb[qi * 264 + tid] = (bf16_t)e;
    float wsum = wave_sum(e);
    if (lane == 0) reds[wave][qi] = wsum;
  }
  __syncthreads();
#pragma unroll
  for (int qi = 0; qi < 6; ++qi)
    ls[qi] = reds[0][qi] + reds[1][qi] + reds[2][qi] + reds[3][qi];
  if (tid == 0) {
#pragma unroll
    for (int qi = 0; qi < 6; ++qi) {
      float* pml = Part + (size_t)((h * 6 + qi) * 64 + c) * 42;
      pml[40] = gmax[qi];
      pml[41] = ls[qi];
    }
  }
  if (wave == 0) {
    int fm = lane & 15, quad = lane >> 4;
    f32x4 acc[3];
#pragma unroll
    for (int nt = 0; nt < 3; ++nt) acc[nt] = (f32x4){0.f, 0.f, 0.f, 0.f};
#pragma unroll
    for (int ks = 0; ks < 8; ++ks) {
      bf16x8 a = *(bf16x8*)&sPb[fm * 264 + ks * 32 + quad * 8];
#pragma unroll
      for (int nt = 0; nt < 3; ++nt) {
        bf16x8 bb = *(bf16x8*)&sVtb[(nt * 16 + fm) * 264 + ks * 32 + quad * 8];
        acc[nt] = __builtin_amdgcn_mfma_f32_16x16x32_bf16(a, bb, acc[nt], 0, 0, 0);
      }
    }
#pragma unroll
    for (int nt = 0; nt < 3; ++nt)
#pragma unroll
      for (int r = 0; r < 4; ++r) {
        int qi = quad * 4 + r;
        int p = nt * 16 + fm;
        if (qi < 6 && p < 40)
          Part[(size_t)((h * 6 + qi) * 64 + c) * 42 + p] = acc[nt][r];
      }
  }
}

// ------------- t2i attention pass 2: combine 64 partials, grid (24,2) --------
__global__ void attn_t2i_comb(const float* __restrict__ Part, float* __restrict__ O) {
  int b = blockIdx.y;
  int blk = blockIdx.x;  // h*6 + qi
  int qi = blk % 6;
  int h = blk / 6;
  int j = threadIdx.x;  // 64
  const float* base = Part + (size_t)b * 24 * 64 * 42 + (size_t)blk * 64 * 42;
  float m = base[j * 42 + 40], l = base[j * 42 + 41];
  float gmax = wave_max(m);
  gmax = __shfl(gmax, 0, 64);
  float sc = expf(m - gmax);
  float tot = wave_sum(l * sc);
  tot = __shfl(tot, 0, 64);
  float inv = 1.f / tot;
  __shared__ float ssc[64];
  ssc[j] = sc;
  __syncthreads();
  if (j < 40) {
    float a0 = 0.f, a1 = 0.f, a2 = 0.f, a3 = 0.f;
    for (int jj = 0; jj < 64; jj += 4) {
      a0 = fmaf(base[(jj + 0) * 42 + j], ssc[jj + 0], a0);
      a1 = fmaf(base[(jj + 1) * 42 + j], ssc[jj + 1], a1);
      a2 = fmaf(base[(jj + 2) * 42 + j], ssc[jj + 2], a2);
      a3 = fmaf(base[(jj + 3) * 42 + j], ssc[jj + 3], a3);
    }
    O[(size_t)b * 960 + (size_t)qi * 160 + h * 40 + j] = (a0 + a1 + a2 + a3) * inv;
  }
}

// ------- i2t attention: out bf16, grid (64,4,2) ------------------------------
__global__ __launch_bounds__(256) void attn_i2t(const float* __restrict__ Qp,
                                                const float* __restrict__ KV,
                                                bf16_t* __restrict__ O) {
  int h = blockIdx.y, b = blockIdx.z;
  int t = blockIdx.x * 256 + threadIdx.x;
  Qp += (size_t)b * LSEQ * 160;
  O += (size_t)b * LSEQ * 160;
  __shared__ float sk[6][40], sv[6][40];
  if (threadIdx.x < 240) {
    int tok = threadIdx.x / 40, p = threadIdx.x % 40;
    const float* base = KV + (size_t)(b * 6 + tok) * 320 + h * 40 + p;
    sk[tok][p] = base[0];
    sv[tok][p] = base[160];
  }
  __syncthreads();
  const float* q = Qp + (size_t)t * 160 + h * 40;
  float qr[40];
#pragma unroll
  for (int v = 0; v < 10; ++v) {
    float4 q4 = *(const float4*)(q + v * 4);
    qr[v * 4 + 0] = q4.x; qr[v * 4 + 1] = q4.y; qr[v * 4 + 2] = q4.z; qr[v * 4 + 3] = q4.w;
  }
  float s[6];
#pragma unroll
  for (int k = 0; k < 6; ++k) {
    float d = 0.f;
    for (int p = 0; p < 40; ++p) d += qr[p] * sk[k][p];
    s[k] = d * 0.15811388300841897f;
  }
  float mx = s[0];
#pragma unroll
  for (int k = 1; k < 6; ++k) mx = fmaxf(mx, s[k]);
  float sum = 0.f;
#pragma unroll
  for (int k = 0; k < 6; ++k) { s[k] = expf(s[k] - mx); sum += s[k]; }
  float inv = 1.f / sum;
  bf16_t* o = O + (size_t)t * 160 + h * 40;
#pragma unroll
  for (int v = 0; v < 10; ++v) {
    float o0 = 0.f, o1 = 0.f, o2 = 0.f, o3 = 0.f;
#pragma unroll
    for (int k = 0; k < 6; ++k) {
      float w = s[k];
      o0 += w * sv[k][v * 4 + 0];
      o1 += w * sv[k][v * 4 + 1];
      o2 += w * sv[k][v * 4 + 2];
      o3 += w * sv[k][v * 4 + 3];
    }
    bf16x4 ov;
    ov[0] = (bf16_t)(o0 * inv); ov[1] = (bf16_t)(o1 * inv);
    ov[2] = (bf16_t)(o2 * inv); ov[3] = (bf16_t)(o3 * inv);
    *(bf16x4*)(o + v * 4) = ov;
  }
}

// =======================================================================
extern "C" void kernel_launch(void* const* d_in, const int* in_sizes, int n_in,
                              void* d_out, int out_size, void* d_ws, size_t ws_size,
                              hipStream_t stream) {
  (void)in_sizes; (void)n_in; (void)out_size;
  const float* x       = (const float*)d_in[0];
  const float* coords  = (const float*)d_in[1];
  const int*   labels  = (const int*)  d_in[2];
  const float* ln_w    = (const float*)d_in[3];
  const float* ln_b    = (const float*)d_in[4];
  const float* in_w    = (const float*)d_in[5];
  const float* conv_w  = (const float*)d_in[6];
  const float* conv_b  = (const float*)d_in[7];
  const float* dt_bias = (const float*)d_in[8];
  const float* A_log   = (const float*)d_in[9];
  const float* Dp      = (const float*)d_in[10];
  const float* rms_w   = (const float*)d_in[11];
  const float* out_w   = (const float*)d_in[12];
  const float* gauss   = (const float*)d_in[13];
  const float* ptab    = (const float*)d_in[14];
  const float* sa_w    = (const float*)d_in[15];
  const float* sa_b    = (const float*)d_in[16];
  const float* t2i_w   = (const float*)d_in[17];
  const float* t2i_b   = (const float*)d_in[18];
  const float* t2i_ow  = (const float*)d_in[19];
  const float* t2i_ob  = (const float*)d_in[20];
  const float* i2t_w   = (const float*)d_in[21];
  const float* i2t_b   = (const float*)d_in[22];
  const float* i2t_ow  = (const float*)d_in[23];
  const float* i2t_ob  = (const float*)d_in[24];
  const float* norms_w = (const float*)d_in[25];
  const float* norms_b = (const float*)d_in[26];
  const float* mlp_w1  = (const float*)d_in[27];
  const float* mlp_b1  = (const float*)d_in[28];
  const float* mlp_w2  = (const float*)d_in[29];
  const float* mlp_b2  = (const float*)d_in[30];
  float* out = (float*)d_out;
  float* ws = (float*)d_ws;

  const size_t NEED = (size_t)(10485760 + 5242880 + 11665408 + 11534336 + 10485760 +
                               131072 + 131072 + 65536) * 4;
  if (ws_size < NEED) {
    ws_probe<<<1, 1, 0, stream>>>(out, (float)ws_size);
    return;
  }
  float* R_K = ws;                          // [2][16384][320]
  float* P   = ws + 10485760;               // scratch pool
  // ---- mamba-phase layout (per batch, reused) ----
  bf16_t* XNB_   = (bf16_t*)P;              // LN'd input bf16 [16384][320]
  float* SCHUNK_ = P;                       // reuses XNB after in_proj
  float* ZB_     = P + 5242880;             // z fp32 [16384][640]
  float* XBC_    = P + 15728640;            // xBC|dt fp32 [16384][712]
  float* SPREV_  = P + 15728640;            // reuses XBC (first 5.24M)
  bf16_t* YB_    = (bf16_t*)(P + 20971520); // gated bf16 [16384][640]
  float* CV_     = P + 27394048;            // conv out fp32 (Y in place)
  float* DT_     = P + 38928384;            // 131,072
  float* CA_     = P + 39059456;            // 131,072
  bf16_t* WBM_   = (bf16_t*)(P + 38928384); // bf16 weights (aliases DT/CA)
  // ---- transformer-phase layout ----
  float* KPE_   = P;                        // 5,242,880
  float* T0_    = P + 5242880;              // [2][16384][160] t2i-K
  float* T3_    = P + 10485760;             // [2][16384][160] i2t-Q
  float* T1_    = P + 15728640;             // [2][16384][160] t2i-V
  bf16_t* T2B_  = (bf16_t*)(P + 26214400);  // [2][16384][160] bf16 i2t attn out
  float* PART_  = P + 36700160;             // [2][24][64][42]
  float* SM_    = P + 36829184;
  float* QPE_  = SM_;
  float* QRY_  = SM_ + 3840;
  float* P3_   = SM_ + 7680;
  float* PO_   = SM_ + 19200;
  float* H_    = SM_ + 23040;
  float* Q160_ = SM_ + 35328;
  float* O160_ = SM_ + 37248;
  float* KV_   = SM_ + 39168;

  const long long sIMG160 = (long long)LSEQ * 160;
  const long long sIMG320 = (long long)LSEQ * CDIM;
  const int NOSPLIT = 1 << 30;

  // ======== mamba phase, per batch ========
  for (int b = 0; b < 2; ++b) {
    const float* xb = x + (size_t)b * CDIM * LSEQ;
    float* Kb = R_K + (size_t)b * LSEQ * CDIM;

    tln<<<LSEQ / 32, 256, 0, stream>>>(xb, ln_w, ln_b, XNB_);
    cvt_bf<<<(432640 / 4 + 255) / 256, 256, 0, stream>>>(in_w, WBM_, 432640);

    // fused in_proj: cols [0,640) -> ZB_ (z), cols [640,1352) -> XBC_
    gemm_bf<<<dim3(22, 128, 1), 256, 0, stream>>>(
        XNB_, WBM_, nullptr, nullptr, ZB_, XBC_, nullptr, nullptr, NOSPLIT,
        LSEQ, 1352, CDIM, CDIM, DIN, DIN, XBCW, 0, 1, 1, 0, 0);

    dt_kernel<<<LSEQ * NHH / 256, 256, 0, stream>>>(XBC_, dt_bias, DT_);
    conv2<<<dim3(11, 128), 256, 0, stream>>>(XBC_, conv_w, conv_b, CV_);

    scan_a<<<dim3(NCHUNK, NHH), 256, 0, stream>>>(CV_, DT_, A_log, SCHUNK_, CA_);
    scan_b<<<dim3(10, NHH), 256, 0, stream>>>(SCHUNK_, CA_, SPREV_);
    scan_c<<<dim3(NCHUNK, NHH), 256, 0, stream>>>(CV_, DT_, CA_, SPREV_, Dp, CV_);

    cvt_bf<<<(204800 / 4 + 255) / 256, 256, 0, stream>>>(out_w, WBM_, 204800);
    gate_rms<<<LSEQ, 256, 0, stream>>>(CV_, ZB_, rms_w, YB_);

    gemm_bf<<<dim3(5, 128, 1), 256, 0, stream>>>(
        YB_, WBM_, nullptr, nullptr, Kb, nullptr, nullptr, nullptr, NOSPLIT,
        LSEQ, CDIM, DIN, DIN, CDIM, NOSPLIT, 0, 0, 1, 1, 0, 0);
  }

  kpe_kernel<<<LSEQ * 160 / 256, 256, 0, stream>>>(gauss, KPE_);
  point_kernel<<<30, 64, 0, stream>>>(coords, labels, gauss, ptab, QPE_, QRY_);

  // ======== transformer phase, both batches per dispatch ========
  for (int i = 0; i < 2; ++i) {
    const float* saw = sa_w + (size_t)i * 4 * CDIM * CDIM;
    const float* sab = sa_b + (size_t)i * 4 * CDIM;
    smallmm<<<240, 256, 0, stream>>>(QRY_, (i == 0) ? nullptr : QPE_,
                                     saw, sab, P3_, 960, CDIM, 0, 0, 640);
    attn_self<<<dim3(4, 2), 128, 0, stream>>>(P3_, PO_);
    smallmm<<<80, 256, 0, stream>>>(PO_, nullptr, saw + 3 * 102400, sab + 3 * CDIM,
                                    QRY_, CDIM, CDIM, (i == 0) ? 0 : 1, 0, 0);
    ln_rows256<<<3, 256, 0, stream>>>(QRY_, norms_w + (size_t)(i * 4 + 0) * CDIM,
                                      norms_b + (size_t)(i * 4 + 0) * CDIM, 12);

    smallmm<<<40, 256, 0, stream>>>(QRY_, QPE_, t2i_w + (size_t)(i * 3 + 0) * 51200,
                                    t2i_b + (size_t)(i * 3 + 0) * 160, Q160_,
                                    160, CDIM, 0, 0, 160);
    // fused: cols 0-159 = t2i-K -> T0; cols 160-319 = i2t-Q -> T3.
    gemm_bf<<<dim3(5, 128, 2), 256, 0, stream>>>(
        R_K, t2i_w + (size_t)(i * 3 + 1) * 51200, t2i_b + (size_t)(i * 3 + 1) * 160,
        KPE_, T0_, T3_, i2t_w + (size_t)(i * 3 + 0) * 51200,
        i2t_b + (size_t)(i * 3 + 0) * 160, 160,
        LSEQ, 320, CDIM, CDIM, 160, 160, 160, 0, 0, 0, sIMG320, sIMG160);
    gemm_bf<<<dim3(3, 128, 2), 256, 0, stream>>>(
        R_K, t2i_w + (size_t)(i * 3 + 2) * 51200, t2i_b + (size_t)(i * 3 + 2) * 160,
        nullptr, T1_, nullptr, nullptr, nullptr, NOSPLIT,
        LSEQ, 160, CDIM, CDIM, 160, NOSPLIT, 0, 0, 0, 0, sIMG320, sIMG160);
    attn_t2i_part2<<<dim3(64, 4, 2), 256, 0, stream>>>(Q160_, T0_, T1_, PART_);
    attn_t2i_comb<<<dim3(24, 2), 64, 0, stream>>>(PART_, O160_);
    smallmm<<<80, 256, 0, stream>>>(O160_, nullptr, t2i_ow + (size_t)i * 51200,
                                    t2i_ob + (size_t)i * CDIM, QRY_,
                                    CDIM, 160, 1, 0, 0);
    ln_rows256<<<3, 256, 0, stream>>>(QRY_, norms_w + (size_t)(i * 4 + 1) * CDIM,
                                      norms_b + (size_t)(i * 4 + 1) * CDIM, 12);

    smallmm<<<256, 256, 0, stream>>>(QRY_, nullptr, mlp_w1 + (size_t)i * 1024 * CDIM,
                                     mlp_b1 + (size_t)i * 1024, H_, 1024, CDIM, 0, 1, 0);
    smallmm<<<80, 256, 0, stream>>>(H_, nullptr, mlp_w2 + (size_t)i * CDIM * 1024,
                                    mlp_b2 + (size_t)i * CDIM, QRY_, CDIM, 1024, 1, 0, 0);
    ln_rows256<<<3, 256, 0, stream>>>(QRY_, norms_w + (size_t)(i * 4 + 2) * CDIM,
                                      norms_b + (size_t)(i * 4 + 2) * CDIM, 12);

    smallmm<<<80, 256, 0, stream>>>(QRY_, QPE_, i2t_w + (size_t)(i * 3 + 1) * 51200,
                                    i2t_b + (size_t)(i * 3 + 1) * 160, KV_,
                                    320, CDIM, 0, 0, 160);
    attn_i2t<<<dim3(LSEQ / 256, 4, 2), 256, 0, stream>>>(T3_, KV_, T2B_);
    gemm_bf<<<dim3(5, 128, 2), 256, 0, stream>>>(
        T2B_, i2t_ow + (size_t)i * CDIM * 160, i2t_ob + (size_t)i * CDIM,
        nullptr, R_K, nullptr, nullptr, nullptr, NOSPLIT,
        LSEQ, CDIM, 160, 160, CDIM, NOSPLIT, 0, 1, 1, 0, sIMG160, sIMG320);
    if (i == 0) {
      ln_rows256<<<2 * LSEQ / 4, 256, 0, stream>>>(
          R_K, norms_w + (size_t)3 * CDIM, norms_b + (size_t)3 * CDIM, 2 * LSEQ);
    }
  }

  // final layernorm fused with transpose to output layout (C,L)
  for (int b = 0; b < 2; ++b) {
    lnt<<<LSEQ / 32, 256, 0, stream>>>(
        R_K + (size_t)b * LSEQ * CDIM, norms_w + (size_t)7 * CDIM,
        norms_b + (size_t)7 * CDIM, out + (size_t)b * CDIM * LSEQ);
  }
}

// Round 7
// 1001.139 us; speedup vs baseline: 1.7621x; 1.0344x over previous
//
#include <hip/hip_runtime.h>
#include <math.h>

#define LSEQ 16384
#define CDIM 320
#define DIN 640
#define NHH 8
#define CONVD 704
#define XBCW 712
#define QCH 64
#define NCHUNK 256

typedef __bf16 bf16_t;
typedef __bf16 bf16x8 __attribute__((ext_vector_type(8)));
typedef __bf16 bf16x4 __attribute__((ext_vector_type(4)));
typedef float f32x4 __attribute__((ext_vector_type(4)));

// ---------------- reduction helpers ----------------
__device__ __forceinline__ float wave_sum(float v) {
#pragma unroll
  for (int o = 32; o > 0; o >>= 1) v += __shfl_down(v, o, 64);
  return v;
}
__device__ __forceinline__ float wave_max(float v) {
#pragma unroll
  for (int o = 32; o > 0; o >>= 1) v = fmaxf(v, __shfl_down(v, o, 64));
  return v;
}
__device__ __forceinline__ float block_sum256(float v, float* red) {
  int tid = threadIdx.x;
  v = wave_sum(v);
  __syncthreads();
  if ((tid & 63) == 0) red[tid >> 6] = v;
  __syncthreads();
  return red[0] + red[1] + red[2] + red[3];
}

__global__ void ws_probe(float* out, float v) { out[0] = v; }

// ---------------- fp32 -> bf16 elementwise (n % 4 == 0) ----------------
__global__ void cvt_bf(const float* __restrict__ src, bf16_t* __restrict__ dst, int n) {
  int i = (blockIdx.x * 256 + threadIdx.x) * 4;
  if (i >= n) return;
  float4 v = *(const float4*)(src + i);
  bf16x4 o;
  o[0] = (bf16_t)v.x; o[1] = (bf16_t)v.y; o[2] = (bf16_t)v.z; o[3] = (bf16_t)v.w;
  *(bf16x4*)(dst + i) = o;
}

// -------- fused transpose + layernorm: x[b] (C,L) -> out (L,C) bf16 ----------
__global__ __launch_bounds__(256) void tln(const float* __restrict__ x,
                                           const float* __restrict__ w,
                                           const float* __restrict__ b,
                                           bf16_t* __restrict__ out) {
  __shared__ float sT[32][321];
  int t0 = blockIdx.x * 32;
  int tid = threadIdx.x;
  for (int i = tid; i < 2560; i += 256) {
    int c = i >> 3, j4 = i & 7;
    float4 v = *(const float4*)(x + (size_t)c * LSEQ + t0 + j4 * 4);
    sT[j4 * 4 + 0][c] = v.x;
    sT[j4 * 4 + 1][c] = v.y;
    sT[j4 * 4 + 2][c] = v.z;
    sT[j4 * 4 + 3][c] = v.w;
  }
  __syncthreads();
  int wave = tid >> 6, lane = tid & 63;
  for (int tt = wave; tt < 32; tt += 4) {
    float xv[5];
    float s = 0.f;
#pragma unroll
    for (int k = 0; k < 5; ++k) { xv[k] = sT[tt][lane + 64 * k]; s += xv[k]; }
    s = wave_sum(s); s = __shfl(s, 0, 64);
    float mean = s * (1.f / 320.f);
    float v = 0.f;
#pragma unroll
    for (int k = 0; k < 5; ++k) { float d = xv[k] - mean; v += d * d; }
    v = wave_sum(v); v = __shfl(v, 0, 64);
    float rstd = rsqrtf(v * (1.f / 320.f) + 1e-5f);
    bf16_t* op = out + (size_t)(t0 + tt) * CDIM;
#pragma unroll
    for (int k = 0; k < 5; ++k) {
      int i = lane + 64 * k;
      op[i] = (bf16_t)((xv[k] - mean) * rstd * w[i] + b[i]);
    }
  }
}

// -------- fused layernorm + transpose: in (L,C) -> out (C,L), LN over C ------
__global__ __launch_bounds__(256) void lnt(const float* __restrict__ in,
                                           const float* __restrict__ w,
                                           const float* __restrict__ b,
                                           float* __restrict__ out) {
  __shared__ float sT[CDIM][33];
  int t0 = blockIdx.x * 32;
  int tid = threadIdx.x;
  int wave = tid >> 6, lane = tid & 63;
  for (int tt = wave; tt < 32; tt += 4) {
    const float* xp = in + (size_t)(t0 + tt) * CDIM;
    float x[5];
    float s = 0.f;
#pragma unroll
    for (int k = 0; k < 5; ++k) { x[k] = xp[lane + 64 * k]; s += x[k]; }
    s = wave_sum(s); s = __shfl(s, 0, 64);
    float mean = s * (1.f / 320.f);
    float v = 0.f;
#pragma unroll
    for (int k = 0; k < 5; ++k) { float d = x[k] - mean; v += d * d; }
    v = wave_sum(v); v = __shfl(v, 0, 64);
    float rstd = rsqrtf(v * (1.f / 320.f) + 1e-5f);
#pragma unroll
    for (int k = 0; k < 5; ++k) {
      int i = lane + 64 * k;
      sT[i][tt] = (x[k] - mean) * rstd * w[i] + b[i];
    }
  }
  __syncthreads();
  for (int i = tid; i < 320 * 32; i += 256) {
    int cc = i >> 5, t = i & 31;
    out[(size_t)cc * LSEQ + t0 + t] = sT[cc][t];
  }
}

// ---------------- layernorm rows (D=320), one wave per row, 4 rows/block -----
__global__ __launch_bounds__(256) void ln_rows256(float* __restrict__ io,
                                                  const float* __restrict__ w,
                                                  const float* __restrict__ b,
                                                  int nrows) {
  int row = blockIdx.x * 4 + (threadIdx.x >> 6);
  if (row >= nrows) return;
  float* xp = io + (size_t)row * CDIM;
  int lane = threadIdx.x & 63;
  float x[5];
  float s = 0.f;
#pragma unroll
  for (int k = 0; k < 5; ++k) { x[k] = xp[lane + 64 * k]; s += x[k]; }
  s = wave_sum(s); s = __shfl(s, 0, 64);
  float mean = s * (1.f / 320.f);
  float v = 0.f;
#pragma unroll
  for (int k = 0; k < 5; ++k) { float t = x[k] - mean; v += t * t; }
  v = wave_sum(v); v = __shfl(v, 0, 64);
  float rstd = rsqrtf(v * (1.f / 320.f) + 1e-5f);
#pragma unroll
  for (int k = 0; k < 5; ++k) {
    int i = lane + 64 * k;
    xp[i] = (x[k] - mean) * rstd * w[i] + b[i];
  }
}

// ------------- bf16 MFMA GEMM, 128x64 tile, XCD-chunked swizzle --------------
// C = (A (+pe)) @ [W;W2]^T (+bias/bias2) (+=C).  Column split at nsplit.
// abf: A bf16 (pe must be null).  wbf: W/W2 bf16.  cbf: C/C2 bf16 (addC=0).
__global__ __launch_bounds__(256) void gemm_bf(
    const void* __restrict__ A, const void* __restrict__ W,
    const float* __restrict__ bias, const float* __restrict__ pe,
    void* __restrict__ C, void* __restrict__ C2,
    const void* __restrict__ W2, const float* __restrict__ bias2, int wsplit,
    int M, int N, int K, int lda, int ldc, int nsplit, int ldc2,
    int addC, int abf, int wbf, int cbf, long long sA, long long sC) {
  int z = blockIdx.z;
  // bijective XCD-chunked swizzle
  int gx = gridDim.x;
  int nwg = gx * gridDim.y;
  int lin = blockIdx.y * gx + blockIdx.x;
  int xcd = lin & 7, idx = lin >> 3;
  int q = nwg >> 3, r = nwg & 7;
  int base = (xcd < r) ? xcd * (q + 1) : r * (q + 1) + (xcd - r) * q;
  int lin2 = base + idx;
  int mblk = lin2 / gx, nblk = lin2 % gx;
  int m0 = mblk << 7, n0 = nblk << 6;

  __shared__ __align__(16) bf16_t As[2][4096];
  __shared__ __align__(16) bf16_t Ws[2][2048];
  int tid = threadIdx.x;
  int wave = tid >> 6, lane = tid & 63;
  int fm = lane & 15, quad = lane >> 4;
  int rA = tid >> 1, hA = tid & 1;  // A row (0..127), col-half (16 elems)
  int rW = tid >> 2, qW = tid & 3;  // W row (0..63), col-quad (8 elems)
  const float* ag = nullptr;
  const bf16_t* agb = nullptr;
  const float* peg = nullptr;
  if (abf) {
    agb = (const bf16_t*)A + (size_t)z * sA + (size_t)(m0 + rA) * lda + hA * 16;
  } else {
    ag = (const float*)A + (size_t)z * sA + (size_t)(m0 + rA) * lda + hA * 16;
    if (pe) peg = pe + (size_t)(m0 + rA) * lda + hA * 16;
  }
  int wRow = n0 + rW;
  bool wok = wRow < N;
  const float* wg = nullptr;
  const bf16_t* wgb = nullptr;
  {
    const void* Wsel = (wRow < wsplit) ? W : W2;
    int wr = (wRow < wsplit) ? wRow : wRow - wsplit;
    if (wbf) wgb = (const bf16_t*)Wsel + (size_t)wr * K + qW * 8;
    else     wg  = (const float*)Wsel + (size_t)wr * K + qW * 8;
  }
  int aoff = (rA >> 4) * 512 + (hA * 32 + (rA & 15)) * 8;
  int woff = (rW >> 4) * 512 + (qW * 16 + (rW & 15)) * 8;

  f32x4 acc[2][4];
#pragma unroll
  for (int i = 0; i < 2; ++i)
#pragma unroll
    for (int j = 0; j < 4; ++j) acc[i][j] = (f32x4){0.f, 0.f, 0.f, 0.f};

  bf16x8 ra0, ra1, rw;
  float4 pa0, pa1, pa2, pa3, pw0, pw1;
  auto loadG = [&](int k0) {
    if (abf) {
      ra0 = *(const bf16x8*)(agb + k0);
      ra1 = *(const bf16x8*)(agb + k0 + 8);
    } else {
      pa0 = *(const float4*)(ag + k0);
      pa1 = *(const float4*)(ag + k0 + 4);
      pa2 = *(const float4*)(ag + k0 + 8);
      pa3 = *(const float4*)(ag + k0 + 12);
      if (peg) {
        float4 q0 = *(const float4*)(peg + k0);
        float4 q1 = *(const float4*)(peg + k0 + 4);
        float4 q2 = *(const float4*)(peg + k0 + 8);
        float4 q3 = *(const float4*)(peg + k0 + 12);
        pa0.x += q0.x; pa0.y += q0.y; pa0.z += q0.z; pa0.w += q0.w;
        pa1.x += q1.x; pa1.y += q1.y; pa1.z += q1.z; pa1.w += q1.w;
        pa2.x += q2.x; pa2.y += q2.y; pa2.z += q2.z; pa2.w += q2.w;
        pa3.x += q3.x; pa3.y += q3.y; pa3.z += q3.z; pa3.w += q3.w;
      }
    }
    if (wbf) {
      if (wok) rw = *(const bf16x8*)(wgb + k0);
      else {
#pragma unroll
        for (int j = 0; j < 8; ++j) rw[j] = (bf16_t)0.f;
      }
    } else {
      pw0 = make_float4(0.f, 0.f, 0.f, 0.f);
      pw1 = pw0;
      if (wok) {
        pw0 = *(const float4*)(wg + k0);
        pw1 = *(const float4*)(wg + k0 + 4);
      }
    }
  };
  auto packLDS = [&](int buf) {
    if (!abf) {
      ra0[0] = (bf16_t)pa0.x; ra0[1] = (bf16_t)pa0.y; ra0[2] = (bf16_t)pa0.z; ra0[3] = (bf16_t)pa0.w;
      ra0[4] = (bf16_t)pa1.x; ra0[5] = (bf16_t)pa1.y; ra0[6] = (bf16_t)pa1.z; ra0[7] = (bf16_t)pa1.w;
      ra1[0] = (bf16_t)pa2.x; ra1[1] = (bf16_t)pa2.y; ra1[2] = (bf16_t)pa2.z; ra1[3] = (bf16_t)pa2.w;
      ra1[4] = (bf16_t)pa3.x; ra1[5] = (bf16_t)pa3.y; ra1[6] = (bf16_t)pa3.z; ra1[7] = (bf16_t)pa3.w;
    }
    *(bf16x8*)&As[buf][aoff] = ra0;
    *(bf16x8*)&As[buf][aoff + 128] = ra1;
    if (!wbf) {
      rw[0] = (bf16_t)pw0.x; rw[1] = (bf16_t)pw0.y; rw[2] = (bf16_t)pw0.z; rw[3] = (bf16_t)pw0.w;
      rw[4] = (bf16_t)pw1.x; rw[5] = (bf16_t)pw1.y; rw[6] = (bf16_t)pw1.z; rw[7] = (bf16_t)pw1.w;
    }
    *(bf16x8*)&Ws[buf][woff] = rw;
  };

  int nk = K >> 5;
  loadG(0);
  packLDS(0);
  __syncthreads();
  for (int i = 0; i < nk; ++i) {
    int buf = i & 1;
    bool more = (i + 1 < nk);
    if (more) loadG((i + 1) << 5);
    int ab = wave * 1024 + lane * 8;
    bf16x8 af0 = *(bf16x8*)&As[buf][ab];
    bf16x8 af1 = *(bf16x8*)&As[buf][ab + 512];
    bf16x8 b0 = *(bf16x8*)&Ws[buf][lane * 8];
    bf16x8 b1 = *(bf16x8*)&Ws[buf][512 + lane * 8];
    bf16x8 b2 = *(bf16x8*)&Ws[buf][1024 + lane * 8];
    bf16x8 b3 = *(bf16x8*)&Ws[buf][1536 + lane * 8];
    acc[0][0] = __builtin_amdgcn_mfma_f32_16x16x32_bf16(af0, b0, acc[0][0], 0, 0, 0);
    acc[0][1] = __builtin_amdgcn_mfma_f32_16x16x32_bf16(af0, b1, acc[0][1], 0, 0, 0);
    acc[0][2] = __builtin_amdgcn_mfma_f32_16x16x32_bf16(af0, b2, acc[0][2], 0, 0, 0);
    acc[0][3] = __builtin_amdgcn_mfma_f32_16x16x32_bf16(af0, b3, acc[0][3], 0, 0, 0);
    acc[1][0] = __builtin_amdgcn_mfma_f32_16x16x32_bf16(af1, b0, acc[1][0], 0, 0, 0);
    acc[1][1] = __builtin_amdgcn_mfma_f32_16x16x32_bf16(af1, b1, acc[1][1], 0, 0, 0);
    acc[1][2] = __builtin_amdgcn_mfma_f32_16x16x32_bf16(af1, b2, acc[1][2], 0, 0, 0);
    acc[1][3] = __builtin_amdgcn_mfma_f32_16x16x32_bf16(af1, b3, acc[1][3], 0, 0, 0);
    if (more) {
      packLDS(buf ^ 1);
      __syncthreads();
    }
  }
#pragma unroll
  for (int ms = 0; ms < 2; ++ms)
#pragma unroll
    for (int ns = 0; ns < 4; ++ns) {
      int n = n0 + ns * 16 + fm;
      if (n >= N) continue;
      float bv = 0.f;
      if (n < wsplit) { if (bias) bv = bias[n]; }
      else            { if (bias2) bv = bias2[n - wsplit]; }
      void* Cb;
      int ldcb, nc;
      if (n < nsplit) { Cb = C; ldcb = ldc; nc = n; }
      else            { Cb = C2; ldcb = ldc2; nc = n - nsplit; }
#pragma unroll
      for (int rr = 0; rr < 4; ++rr) {
        int m = m0 + wave * 32 + ms * 16 + quad * 4 + rr;
        float v = acc[ms][ns][rr] + bv;
        size_t off = (size_t)z * sC + (size_t)m * ldcb + nc;
        if (cbf) {
          ((bf16_t*)Cb)[off] = (bf16_t)v;
        } else {
          float* Cf = (float*)Cb;
          if (addC) v += Cf[off];
          Cf[off] = v;
        }
      }
    }
}

// -------- small matmul (token side), M=12 fixed, wave-per-output-column ------
__global__ __launch_bounds__(256) void smallmm(
    const float* __restrict__ A, const float* __restrict__ A2,
    const float* __restrict__ W, const float* __restrict__ bias,
    float* __restrict__ C, int N, int K, int addC, int relu, int a2lim) {
  int wave = threadIdx.x >> 6, lane = threadIdx.x & 63;
  int n = blockIdx.x * 4 + wave;
  if (n >= N) return;
  const float* w = W + (size_t)n * K;
  bool useA2 = (A2 != nullptr) && (n < a2lim);
  float part[12];
#pragma unroll
  for (int m = 0; m < 12; ++m) part[m] = 0.f;
  for (int k0 = 0; k0 < K; k0 += 64) {
    int k = k0 + lane;
    if (k < K) {
      float wv = w[k];
      const float* ap = A + k;
      if (useA2) {
        const float* ap2 = A2 + k;
#pragma unroll
        for (int m = 0; m < 12; ++m)
          part[m] = fmaf(ap[(size_t)m * K] + ap2[(size_t)m * K], wv, part[m]);
      } else {
#pragma unroll
        for (int m = 0; m < 12; ++m)
          part[m] = fmaf(ap[(size_t)m * K], wv, part[m]);
      }
    }
  }
  float bv = bias ? bias[n] : 0.f;
#pragma unroll
  for (int m = 0; m < 12; ++m) {
    float dot = wave_sum(part[m]);
    if (lane == 0) {
      float v = dot + bv;
      if (relu) v = fmaxf(v, 0.f);
      size_t off = (size_t)m * N + n;
      if (addC) v += C[off];
      C[off] = v;
    }
  }
}

// ---------------- dt = softplus(dt_raw + dt_bias), layout (h,t) --------------
__global__ void dt_kernel(const bf16_t* __restrict__ XBC, const float* __restrict__ dt_bias,
                          float* __restrict__ dtbuf) {
  int idx = blockIdx.x * 256 + threadIdx.x;
  if (idx >= LSEQ * NHH) return;
  int h = idx & 7;
  int t = idx >> 3;
  float v = (float)XBC[(size_t)t * XBCW + 704 + h] + dt_bias[h];
  float sp = (v > 20.f) ? v : log1pf(expf(v));
  dtbuf[(size_t)h * LSEQ + t] = sp;
}

// ------- causal depthwise conv + silu, sliding-window registers, bf16 IO -----
__global__ __launch_bounds__(256) void conv2(const bf16_t* __restrict__ XBC,
                                             const float* __restrict__ conv_w,
                                             const float* __restrict__ conv_b,
                                             bf16_t* __restrict__ Cv) {
  int lane = threadIdx.x & 63, wv = threadIdx.x >> 6;
  int d = blockIdx.x * 64 + lane;
  int t0 = (blockIdx.y * 4 + wv) * 32;
  float w0 = conv_w[d * 4 + 0], w1 = conv_w[d * 4 + 1];
  float w2 = conv_w[d * 4 + 2], w3 = conv_w[d * 4 + 3];
  float bv = conv_b[d];
  const bf16_t* src = XBC + d;
  float xm3, xm2, xm1;
  if (t0 == 0) {
    xm3 = 0.f; xm2 = 0.f; xm1 = 0.f;
  } else {
    xm3 = (float)src[(size_t)(t0 - 3) * XBCW];
    xm2 = (float)src[(size_t)(t0 - 2) * XBCW];
    xm1 = (float)src[(size_t)(t0 - 1) * XBCW];
  }
#pragma unroll 8
  for (int t = t0; t < t0 + 32; ++t) {
    float xt = (float)src[(size_t)t * XBCW];
    float a = bv + xm3 * w0 + xm2 * w1 + xm1 * w2 + xt * w3;
    Cv[(size_t)t * CONVD + d] = (bf16_t)(a / (1.f + expf(-a)));
    xm3 = xm2; xm2 = xm1; xm1 = xt;
  }
}

// ---------------- scan phase A: per-chunk states + cumulative log-decay ------
__global__ __launch_bounds__(256) void scan_a(const bf16_t* __restrict__ Cv,
                                              const float* __restrict__ dtbuf,
                                              const float* __restrict__ A_log,
                                              float* __restrict__ Schunk,
                                              float* __restrict__ cabuf) {
  int c = blockIdx.x, h = blockIdx.y;
  int t0 = c * QCH;
  __shared__ float sdt[64], sca[64], sw[64];
  __shared__ __align__(16) float sB[64][36];
  __shared__ __align__(16) float sXt[80][68];
  int tid = threadIdx.x;
  float Aval = -expf(A_log[h]);
  if (tid < 64) sdt[tid] = dtbuf[(size_t)h * LSEQ + t0 + tid];
  __syncthreads();
  if (tid == 0) {
    float run = 0.f;
    for (int j = 0; j < 64; ++j) { run += sdt[j] * Aval; sca[j] = run; }
  }
  __syncthreads();
  float caend = sca[63];
  if (tid < 64) {
    sw[tid] = expf(caend - sca[tid]) * sdt[tid];
    cabuf[(size_t)h * LSEQ + t0 + tid] = sca[tid];
  }
  for (int i = tid; i < 2048; i += 256) {
    int j = i >> 5, n = i & 31;
    sB[j][n] = (float)Cv[(size_t)(t0 + j) * CONVD + 640 + n];
  }
  for (int i = tid; i < 5120; i += 256) {
    int j = i / 80, p = i % 80;
    sXt[p][j] = (float)Cv[(size_t)(t0 + j) * CONVD + h * 80 + p];
  }
  __syncthreads();
  int n = tid >> 3, pb = tid & 7;
  float acc[10];
#pragma unroll
  for (int u = 0; u < 10; ++u) acc[u] = 0.f;
  for (int jb = 0; jb < 16; ++jb) {
    float wB[4];
#pragma unroll
    for (int jj = 0; jj < 4; ++jj) {
      int j = jb * 4 + jj;
      wB[jj] = sw[j] * sB[j][n];
    }
#pragma unroll
    for (int u = 0; u < 10; ++u) {
      int p = pb * 10 + u;
      float4 x4 = *(const float4*)&sXt[p][jb * 4];
      acc[u] += wB[0] * x4.x + wB[1] * x4.y + wB[2] * x4.z + wB[3] * x4.w;
    }
  }
  float* outp = Schunk + (size_t)(h * NCHUNK + c) * 2560;
#pragma unroll
  for (int u = 0; u < 10; ++u) outp[n * 80 + pb * 10 + u] = acc[u];
}

// ---------------- scan phase B: sequential over chunks, 80 blocks ------------
__global__ __launch_bounds__(256) void scan_b(const float* __restrict__ Schunk,
                                              const float* __restrict__ cabuf,
                                              float* __restrict__ Sprev) {
  int pc = blockIdx.x, h = blockIdx.y;
  __shared__ float sdec[256];
  int tid = threadIdx.x;
  sdec[tid] = expf(cabuf[(size_t)h * LSEQ + tid * 64 + 63]);
  __syncthreads();
  int e = pc * 256 + tid;
  const float* base = Schunk + (size_t)h * NCHUNK * 2560 + e;
  float* pbase = Sprev + (size_t)h * NCHUNK * 2560 + e;
  float s = 0.f;
  float v = base[0];
  for (int c = 0; c < NCHUNK; ++c) {
    float vn = (c < NCHUNK - 1) ? base[(size_t)(c + 1) * 2560] : 0.f;
    pbase[(size_t)c * 2560] = s;
    s = s * sdec[c] + v;
    v = vn;
  }
}

// ---------------- scan phase C: MFMA; Y -> separate bf16 buffer --------------
__global__ __launch_bounds__(256) void scan_c(const bf16_t* __restrict__ Cv,
                                              const float* __restrict__ dtbuf,
                                              const float* __restrict__ cabuf,
                                              const float* __restrict__ Sprev,
                                              const float* __restrict__ Dp,
                                              bf16_t* __restrict__ Y) {
  int c = blockIdx.x, h = blockIdx.y;
  int t0 = c * QCH;
  __shared__ float sdt[64], sca[64], sexp[64];
  __shared__ __align__(16) bf16_t sC[64 * 40];
  __shared__ __align__(16) bf16_t sB[64 * 40];
  __shared__ __align__(16) bf16_t sXt[80 * 72];
  __shared__ __align__(16) bf16_t sSt[80 * 40];
  __shared__ __align__(16) bf16_t sP[64 * 72];
  int tid = threadIdx.x;
  int wave = tid >> 6, lane = tid & 63;
  int fm = lane & 15, quad = lane >> 4;
  if (tid < 64) {
    sdt[tid] = dtbuf[(size_t)h * LSEQ + t0 + tid];
    float cav = cabuf[(size_t)h * LSEQ + t0 + tid];
    sca[tid] = cav;
    sexp[tid] = expf(cav);
  }
  for (int i = tid; i < 2048; i += 256) {
    int j = i >> 5, n = i & 31;
    size_t base = (size_t)(t0 + j) * CONVD;
    sB[j * 40 + n] = Cv[base + 640 + n];
    sC[j * 40 + n] = Cv[base + 672 + n];
  }
  for (int i = tid; i < 5120; i += 256) {
    int j = i / 80, p = i % 80;
    sXt[p * 72 + j] = Cv[(size_t)(t0 + j) * CONVD + h * 80 + p];
  }
  {
    const float* sp = Sprev + (size_t)(h * NCHUNK + c) * 2560;
    for (int i = tid; i < 2560; i += 256) {
      int n = i / 80, p = i % 80;
      sSt[p * 40 + n] = (bf16_t)sp[i];
    }
  }
  __syncthreads();
  int m0 = wave * 16;
  int jbase = m0 + quad * 4;
  bf16x8 afC = *(bf16x8*)&sC[(m0 + fm) * 40 + quad * 8];
  f32x4 accS[4];
#pragma unroll
  for (int nt = 0; nt < 4; ++nt) {
    bf16x8 bf = *(bf16x8*)&sB[(nt * 16 + fm) * 40 + quad * 8];
    f32x4 zero = (f32x4){0.f, 0.f, 0.f, 0.f};
    accS[nt] = __builtin_amdgcn_mfma_f32_16x16x32_bf16(afC, bf, zero, 0, 0, 0);
  }
  float scaj[4];
#pragma unroll
  for (int r = 0; r < 4; ++r) scaj[r] = sca[jbase + r];
#pragma unroll
  for (int nt = 0; nt < 4; ++nt) {
    int s = nt * 16 + fm;
    float dts = sdt[s], scas = sca[s];
#pragma unroll
    for (int r = 0; r < 4; ++r) {
      int j = jbase + r;
      float v = 0.f;
      if (s <= j) v = accS[nt][r] * dts * expf(scaj[r] - scas);
      sP[j * 72 + s] = (bf16_t)v;
    }
  }
  f32x4 acc[5];
#pragma unroll
  for (int pt = 0; pt < 5; ++pt) {
    bf16x8 bf = *(bf16x8*)&sSt[(pt * 16 + fm) * 40 + quad * 8];
    f32x4 zero = (f32x4){0.f, 0.f, 0.f, 0.f};
    acc[pt] = __builtin_amdgcn_mfma_f32_16x16x32_bf16(afC, bf, zero, 0, 0, 0);
  }
  float gj[4];
#pragma unroll
  for (int r = 0; r < 4; ++r) gj[r] = sexp[jbase + r];
#pragma unroll
  for (int pt = 0; pt < 5; ++pt)
#pragma unroll
    for (int r = 0; r < 4; ++r) acc[pt][r] *= gj[r];
  bf16x8 afP0 = *(bf16x8*)&sP[(m0 + fm) * 72 + 0 + quad * 8];
  bf16x8 afP1 = *(bf16x8*)&sP[(m0 + fm) * 72 + 32 + quad * 8];
#pragma unroll
  for (int pt = 0; pt < 5; ++pt) {
    bf16x8 bx0 = *(bf16x8*)&sXt[(pt * 16 + fm) * 72 + 0 + quad * 8];
    bf16x8 bx1 = *(bf16x8*)&sXt[(pt * 16 + fm) * 72 + 32 + quad * 8];
    acc[pt] = __builtin_amdgcn_mfma_f32_16x16x32_bf16(afP0, bx0, acc[pt], 0, 0, 0);
    acc[pt] = __builtin_amdgcn_mfma_f32_16x16x32_bf16(afP1, bx1, acc[pt], 0, 0, 0);
  }
  float dval = Dp[h];
#pragma unroll
  for (int pt = 0; pt < 5; ++pt) {
    int p = pt * 16 + fm;
#pragma unroll
    for (int r = 0; r < 4; ++r) {
      int j = jbase + r;
      float xv = (float)sXt[p * 72 + j];
      Y[(size_t)(t0 + j) * DIN + h * 80 + p] = (bf16_t)(acc[pt][r] + dval * xv);
    }
  }
}

// ------- y *= silu(z); rmsnorm * rms_w; bf16 in-place ------------------------
__global__ __launch_bounds__(256) void gate_rms(bf16_t* __restrict__ YS,
                                                const bf16_t* __restrict__ Z,
                                                const float* __restrict__ rms_w) {
  __shared__ float red[4];
  size_t row = blockIdx.x;
  bf16_t* y = YS + row * DIN;
  const bf16_t* z = Z + row * DIN;
  int tid = threadIdx.x;
  float g0, g1, g2 = 0.f;
  {
    float zi = (float)z[tid];
    g0 = (float)y[tid] * (zi / (1.f + expf(-zi)));
    zi = (float)z[tid + 256];
    g1 = (float)y[tid + 256] * (zi / (1.f + expf(-zi)));
    if (tid + 512 < DIN) {
      zi = (float)z[tid + 512];
      g2 = (float)y[tid + 512] * (zi / (1.f + expf(-zi)));
    }
  }
  float ss = g0 * g0 + g1 * g1 + g2 * g2;
  float tot = block_sum256(ss, red);
  float r = rsqrtf(tot / (float)DIN + 1e-5f);
  y[tid] = (bf16_t)(g0 * r * rms_w[tid]);
  y[tid + 256] = (bf16_t)(g1 * r * rms_w[tid + 256]);
  if (tid + 512 < DIN) y[tid + 512] = (bf16_t)(g2 * r * rms_w[tid + 512]);
}

// ---------------- dense image PE ----------------
__global__ void kpe_kernel(const float* __restrict__ gauss, float* __restrict__ KPE) {
  int idx = blockIdx.x * 256 + threadIdx.x;
  if (idx >= LSEQ * 160) return;
  int f = idx % 160, t = idx / 160;
  int d = t >> 10, hh = (t >> 5) & 31, w = t & 31;
  float vx = 2.f * ((d + 0.5f) / 16.f) - 1.f;
  float vy = 2.f * ((hh + 0.5f) / 32.f) - 1.f;
  float vz = 2.f * ((w + 0.5f) / 32.f) - 1.f;
  float cc = 6.28318530717958647692f * (vx * gauss[f] + vy * gauss[160 + f] + vz * gauss[320 + f]);
  KPE[(size_t)t * CDIM + f] = sinf(cc);
  KPE[(size_t)t * CDIM + 160 + f] = cosf(cc);
}

// ---------------- point embeddings (both batches: 12 points) -----------------
__global__ void point_kernel(const float* __restrict__ coords, const int* __restrict__ labels,
                             const float* __restrict__ gauss, const float* __restrict__ ptab,
                             float* __restrict__ qpe, float* __restrict__ queries) {
  int idx = blockIdx.x * 64 + threadIdx.x;
  if (idx >= 12 * 160) return;
  int f = idx % 160, pt = idx / 160;
  const float* co = coords + pt * 3;
  float vx = 2.f * (co[0] / 128.f) - 1.f;
  float vy = 2.f * (co[1] / 256.f) - 1.f;
  float vz = 2.f * (co[2] / 256.f) - 1.f;
  float cc = 6.28318530717958647692f * (vx * gauss[f] + vy * gauss[160 + f] + vz * gauss[320 + f]);
  int lab = labels[pt];
  float sv = sinf(cc) + ptab[lab * CDIM + f];
  float cv = cosf(cc) + ptab[lab * CDIM + 160 + f];
  qpe[pt * CDIM + f] = sv;       qpe[pt * CDIM + 160 + f] = cv;
  queries[pt * CDIM + f] = sv;   queries[pt * CDIM + 160 + f] = cv;
}

// --------- self-attn over 6 tokens from fused P3[12][960], grid (4,2) --------
__global__ void attn_self(const float* __restrict__ P3, float* __restrict__ O) {
  int h = blockIdx.x, b = blockIdx.y;
  __shared__ float sq[6][80], sk[6][80], sv[6][80], sw[6][6];
  int tid = threadIdx.x;  // 128
  for (int i = tid; i < 480; i += 128) {
    int tok = i / 80, p = i % 80;
    const float* base = P3 + (size_t)(b * 6 + tok) * 960 + h * 80 + p;
    sq[tok][p] = base[0]; sk[tok][p] = base[320]; sv[tok][p] = base[640];
  }
  __syncthreads();
  if (tid < 36) {
    int qi = tid / 6, ki = tid % 6;
    float d = 0.f;
    for (int p = 0; p < 80; ++p) d += sq[qi][p] * sk[ki][p];
    sw[qi][ki] = d * 0.11180339887498948f;  // 1/sqrt(80)
  }
  __syncthreads();
  if (tid < 6) {
    float mx = sw[tid][0];
    for (int k = 1; k < 6; ++k) mx = fmaxf(mx, sw[tid][k]);
    float s = 0.f;
    for (int k = 0; k < 6; ++k) { float e = expf(sw[tid][k] - mx); sw[tid][k] = e; s += e; }
    float inv = 1.f / s;
    for (int k = 0; k < 6; ++k) sw[tid][k] *= inv;
  }
  __syncthreads();
  for (int i = tid; i < 480; i += 128) {
    int qi = i / 80, p = i % 80;
    float o = 0.f;
    for (int k = 0; k < 6; ++k) o += sw[qi][k] * sv[k][p];
    O[(size_t)(b * 6 + qi) * CDIM + h * 80 + p] = o;
  }
}

// ------------- t2i attention pass 1: bf16 K/V, LDS + MFMA PV, grid (64,4,2) --
__global__ __launch_bounds__(256) void attn_t2i_part2(const float* __restrict__ Qp,
                                                      const bf16_t* __restrict__ Kp,
                                                      const bf16_t* __restrict__ Vp,
                                                      float* __restrict__ Part) {
  int b = blockIdx.z, h = blockIdx.y, c = blockIdx.x;
  Qp += (size_t)b * 960;
  Kp += (size_t)b * LSEQ * 160;
  Vp += (size_t)b * LSEQ * 160;
  Part += (size_t)b * 24 * 64 * 42;
  __shared__ float sq[240];
  __shared__ float redm[4][6], reds[4][6];
  __shared__ __align__(16) bf16_t sPb[16 * 264];
  __shared__ __align__(16) bf16_t sVtb[48 * 264];
  int tid = threadIdx.x;
  int wave = tid >> 6, lane = tid & 63;
  if (tid < 240) sq[tid] = Qp[(size_t)(tid / 40) * 160 + h * 40 + (tid % 40)];
  __syncthreads();
  int t = c * 256 + tid;
  const bf16_t* kp = Kp + (size_t)t * 160 + h * 40;
  float kr[40];
#pragma unroll
  for (int v = 0; v < 5; ++v) {
    bf16x8 k8 = *(const bf16x8*)(kp + v * 8);
#pragma unroll
    for (int j = 0; j < 8; ++j) kr[v * 8 + j] = (float)k8[j];
  }
  const bf16_t* vp = Vp + (size_t)t * 160 + h * 40;
#pragma unroll
  for (int v = 0; v < 5; ++v) {
    bf16x8 v8 = *(const bf16x8*)(vp + v * 8);
#pragma unroll
    for (int j = 0; j < 8; ++j) sVtb[(v * 8 + j) * 264 + tid] = v8[j];
  }
  float s[6];
#pragma unroll
  for (int qi = 0; qi < 6; ++qi) {
    float d = 0.f;
#pragma unroll
    for (int p = 0; p < 40; ++p) d += sq[qi * 40 + p] * kr[p];
    s[qi] = d * 0.15811388300841897f;  // 1/sqrt(40)
  }
#pragma unroll
  for (int qi = 0; qi < 6; ++qi) {
    float wm = wave_max(s[qi]);
    if (lane == 0) redm[wave][qi] = wm;
  }
  __syncthreads();
  float gmax[6], ls[6];
#pragma unroll
  for (int qi = 0; qi < 6; ++qi)
    gmax[qi] = fmaxf(fmaxf(redm[0][qi], redm[1][qi]), fmaxf(redm[2][qi], redm[3][qi]));
#pragma unroll
  for (int qi = 0; qi < 6; ++qi) {
    float e = expf(s[qi] - gmax[qi]);
    sPb[qi * 264 + tid] = (bf16_t)e;
    float wsum = wave_sum(e);
    if (lane == 0) reds[wave][qi] = wsum;
  }
  __syncthreads();
#pragma unroll
  for (int qi = 0; qi < 6; ++qi)
    ls[qi] = reds[0][qi] + reds[1][qi] + reds[2][qi] + reds[3][qi];
  if (tid == 0) {
#pragma unroll
    for (int qi = 0; qi < 6; ++qi) {
      float* pml = Part + (size_t)((h * 6 + qi) * 64 + c) * 42;
      pml[40] = gmax[qi];
      pml[41] = ls[qi];
    }
  }
  if (wave == 0) {
    int fm = lane & 15, quad = lane >> 4;
    f32x4 acc[3];
#pragma unroll
    for (int nt = 0; nt < 3; ++nt) acc[nt] = (f32x4){0.f, 0.f, 0.f, 0.f};
#pragma unroll
    for (int ks = 0; ks < 8; ++ks) {
      bf16x8 a = *(bf16x8*)&sPb[fm * 264 + ks * 32 + quad * 8];
#pragma unroll
      for (int nt = 0; nt < 3; ++nt) {
        bf16x8 bb = *(bf16x8*)&sVtb[(nt * 16 + fm) * 264 + ks * 32 + quad * 8];
        acc[nt] = __builtin_amdgcn_mfma_f32_16x16x32_bf16(a, bb, acc[nt], 0, 0, 0);
      }
    }
#pragma unroll
    for (int nt = 0; nt < 3; ++nt)
#pragma unroll
      for (int r = 0; r < 4; ++r) {
        int qi = quad * 4 + r;
        int p = nt * 16 + fm;
        if (qi < 6 && p < 40)
          Part[(size_t)((h * 6 + qi) * 64 + c) * 42 + p] = acc[nt][r];
      }
  }
}

// ------------- t2i attention pass 2: combine 64 partials, grid (24,2) --------
__global__ void attn_t2i_comb(const float* __restrict__ Part, float* __restrict__ O) {
  int b = blockIdx.y;
  int blk = blockIdx.x;  // h*6 + qi
  int qi = blk % 6;
  int h = blk / 6;
  int j = threadIdx.x;  // 64
  const float* base = Part + (size_t)b * 24 * 64 * 42 + (size_t)blk * 64 * 42;
  float m = base[j * 42 + 40], l = base[j * 42 + 41];
  float gmax = wave_max(m);
  gmax = __shfl(gmax, 0, 64);
  float sc = expf(m - gmax);
  float tot = wave_sum(l * sc);
  tot = __shfl(tot, 0, 64);
  float inv = 1.f / tot;
  __shared__ float ssc[64];
  ssc[j] = sc;
  __syncthreads();
  if (j < 40) {
    float a0 = 0.f, a1 = 0.f, a2 = 0.f, a3 = 0.f;
    for (int jj = 0; jj < 64; jj += 4) {
      a0 = fmaf(base[(jj + 0) * 42 + j], ssc[jj + 0], a0);
      a1 = fmaf(base[(jj + 1) * 42 + j], ssc[jj + 1], a1);
      a2 = fmaf(base[(jj + 2) * 42 + j], ssc[jj + 2], a2);
      a3 = fmaf(base[(jj + 3) * 42 + j], ssc[jj + 3], a3);
    }
    O[(size_t)b * 960 + (size_t)qi * 160 + h * 40 + j] = (a0 + a1 + a2 + a3) * inv;
  }
}

// ------- i2t attention: bf16 Q in, bf16 out, grid (64,4,2) -------------------
__global__ __launch_bounds__(256) void attn_i2t(const bf16_t* __restrict__ Qp,
                                                const float* __restrict__ KV,
                                                bf16_t* __restrict__ O) {
  int h = blockIdx.y, b = blockIdx.z;
  int t = blockIdx.x * 256 + threadIdx.x;
  Qp += (size_t)b * LSEQ * 160;
  O += (size_t)b * LSEQ * 160;
  __shared__ float sk[6][40], sv[6][40];
  if (threadIdx.x < 240) {
    int tok = threadIdx.x / 40, p = threadIdx.x % 40;
    const float* base = KV + (size_t)(b * 6 + tok) * 320 + h * 40 + p;
    sk[tok][p] = base[0];
    sv[tok][p] = base[160];
  }
  __syncthreads();
  const bf16_t* q = Qp + (size_t)t * 160 + h * 40;
  float qr[40];
#pragma unroll
  for (int v = 0; v < 5; ++v) {
    bf16x8 q8 = *(const bf16x8*)(q + v * 8);
#pragma unroll
    for (int j = 0; j < 8; ++j) qr[v * 8 + j] = (float)q8[j];
  }
  float s[6];
#pragma unroll
  for (int k = 0; k < 6; ++k) {
    float d = 0.f;
    for (int p = 0; p < 40; ++p) d += qr[p] * sk[k][p];
    s[k] = d * 0.15811388300841897f;
  }
  float mx = s[0];
#pragma unroll
  for (int k = 1; k < 6; ++k) mx = fmaxf(mx, s[k]);
  float sum = 0.f;
#pragma unroll
  for (int k = 0; k < 6; ++k) { s[k] = expf(s[k] - mx); sum += s[k]; }
  float inv = 1.f / sum;
  bf16_t* o = O + (size_t)t * 160 + h * 40;
#pragma unroll
  for (int v = 0; v < 10; ++v) {
    float o0 = 0.f, o1 = 0.f, o2 = 0.f, o3 = 0.f;
#pragma unroll
    for (int k = 0; k < 6; ++k) {
      float w = s[k];
      o0 += w * sv[k][v * 4 + 0];
      o1 += w * sv[k][v * 4 + 1];
      o2 += w * sv[k][v * 4 + 2];
      o3 += w * sv[k][v * 4 + 3];
    }
    bf16x4 ov;
    ov[0] = (bf16_t)(o0 * inv); ov[1] = (bf16_t)(o1 * inv);
    ov[2] = (bf16_t)(o2 * inv); ov[3] = (bf16_t)(o3 * inv);
    *(bf16x4*)(o + v * 4) = ov;
  }
}

// =======================================================================
extern "C" void kernel_launch(void* const* d_in, const int* in_sizes, int n_in,
                              void* d_out, int out_size, void* d_ws, size_t ws_size,
                              hipStream_t stream) {
  (void)in_sizes; (void)n_in; (void)out_size;
  const float* x       = (const float*)d_in[0];
  const float* coords  = (const float*)d_in[1];
  const int*   labels  = (const int*)  d_in[2];
  const float* ln_w    = (const float*)d_in[3];
  const float* ln_b    = (const float*)d_in[4];
  const float* in_w    = (const float*)d_in[5];
  const float* conv_w  = (const float*)d_in[6];
  const float* conv_b  = (const float*)d_in[7];
  const float* dt_bias = (const float*)d_in[8];
  const float* A_log   = (const float*)d_in[9];
  const float* Dp      = (const float*)d_in[10];
  const float* rms_w   = (const float*)d_in[11];
  const float* out_w   = (const float*)d_in[12];
  const float* gauss   = (const float*)d_in[13];
  const float* ptab    = (const float*)d_in[14];
  const float* sa_w    = (const float*)d_in[15];
  const float* sa_b    = (const float*)d_in[16];
  const float* t2i_w   = (const float*)d_in[17];
  const float* t2i_b   = (const float*)d_in[18];
  const float* t2i_ow  = (const float*)d_in[19];
  const float* t2i_ob  = (const float*)d_in[20];
  const float* i2t_w   = (const float*)d_in[21];
  const float* i2t_b   = (const float*)d_in[22];
  const float* i2t_ow  = (const float*)d_in[23];
  const float* i2t_ob  = (const float*)d_in[24];
  const float* norms_w = (const float*)d_in[25];
  const float* norms_b = (const float*)d_in[26];
  const float* mlp_w1  = (const float*)d_in[27];
  const float* mlp_b1  = (const float*)d_in[28];
  const float* mlp_w2  = (const float*)d_in[29];
  const float* mlp_b2  = (const float*)d_in[30];
  float* out = (float*)d_out;
  float* ws = (float*)d_ws;

  const size_t NEED = (size_t)(10485760 + 5242880 + 11665408 + 11534336 + 10485760 +
                               131072 + 131072 + 65536) * 4;
  if (ws_size < NEED) {
    ws_probe<<<1, 1, 0, stream>>>(out, (float)ws_size);
    return;
  }
  float* R_K = ws;                           // [2][16384][320] fp32
  float* P   = ws + 10485760;                // scratch pool
  // ---- mamba-phase layout (per batch, reused) ----
  bf16_t* XNB_   = (bf16_t*)P;               // LN'd input bf16 [16384][320]
  float* SCHUNK_ = P;                        // reuses XNB after in_proj
  bf16_t* ZBB_   = (bf16_t*)(P + 5242880);   // z bf16 [16384][640]
  bf16_t* XBCB_  = (bf16_t*)(P + 10485760);  // xBC|dt bf16 [16384][712]
  float* SPREV_  = P + 10485760;             // reuses XBCB after conv/dt
  bf16_t* CVB_   = (bf16_t*)(P + 16318464);  // conv out bf16 [16384][704]
  bf16_t* YSB_   = (bf16_t*)(P + 22085632);  // scan-out / gated bf16 [16384][640]
  float* DT_     = P + 27328512;             // 131,072
  float* CA_     = P + 27459584;             // 131,072
  bf16_t* WBI_   = (bf16_t*)(P + 27590656);  // in_w bf16 (432,640)
  bf16_t* WBO_   = (bf16_t*)(P + 27806976);  // out_w bf16 (204,800)
  // ---- transformer-phase layout ----
  float* KPE_   = P;                         // 5,242,880 fp32
  bf16_t* T0B_  = (bf16_t*)(P + 5242880);    // [2][16384][160] bf16 t2i-K
  bf16_t* T3B_  = (bf16_t*)(P + 7864320);    // [2][16384][160] bf16 i2t-Q
  bf16_t* T1B_  = (bf16_t*)(P + 10485760);   // [2][16384][160] bf16 t2i-V
  bf16_t* T2B_  = (bf16_t*)(P + 13107200);   // [2][16384][160] bf16 i2t out
  float* PART_  = P + 15728640;              // [2][24][64][42]
  float* SM_    = P + 15857664;
  float* QPE_  = SM_;
  float* QRY_  = SM_ + 3840;
  float* P3_   = SM_ + 7680;
  float* PO_   = SM_ + 19200;
  float* H_    = SM_ + 23040;
  float* Q160_ = SM_ + 35328;
  float* O160_ = SM_ + 37248;
  float* KV_   = SM_ + 39168;

  const long long sIMG160 = (long long)LSEQ * 160;
  const long long sIMG320 = (long long)LSEQ * CDIM;
  const int NOSPLIT = 1 << 30;

  // weights -> bf16 once
  cvt_bf<<<(432640 / 4 + 255) / 256, 256, 0, stream>>>(in_w, WBI_, 432640);
  cvt_bf<<<(204800 / 4 + 255) / 256, 256, 0, stream>>>(out_w, WBO_, 204800);

  // ======== mamba phase, per batch ========
  for (int b = 0; b < 2; ++b) {
    const float* xb = x + (size_t)b * CDIM * LSEQ;
    float* Kb = R_K + (size_t)b * LSEQ * CDIM;

    tln<<<LSEQ / 32, 256, 0, stream>>>(xb, ln_w, ln_b, XNB_);

    // fused in_proj: cols [0,640) -> ZBB (bf16), cols [640,1352) -> XBCB (bf16)
    gemm_bf<<<dim3(22, 128, 1), 256, 0, stream>>>(
        XNB_, WBI_, nullptr, nullptr, ZBB_, XBCB_, nullptr, nullptr, NOSPLIT,
        LSEQ, 1352, CDIM, CDIM, DIN, DIN, XBCW, 0, 1, 1, 1, 0, 0);

    dt_kernel<<<LSEQ * NHH / 256, 256, 0, stream>>>(XBCB_, dt_bias, DT_);
    conv2<<<dim3(11, 128), 256, 0, stream>>>(XBCB_, conv_w, conv_b, CVB_);

    scan_a<<<dim3(NCHUNK, NHH), 256, 0, stream>>>(CVB_, DT_, A_log, SCHUNK_, CA_);
    scan_b<<<dim3(10, NHH), 256, 0, stream>>>(SCHUNK_, CA_, SPREV_);
    scan_c<<<dim3(NCHUNK, NHH), 256, 0, stream>>>(CVB_, DT_, CA_, SPREV_, Dp, YSB_);

    gate_rms<<<LSEQ, 256, 0, stream>>>(YSB_, ZBB_, rms_w);

    gemm_bf<<<dim3(5, 128, 1), 256, 0, stream>>>(
        YSB_, WBO_, nullptr, nullptr, Kb, nullptr, nullptr, nullptr, NOSPLIT,
        LSEQ, CDIM, DIN, DIN, CDIM, NOSPLIT, 0, 0, 1, 1, 0, 0, 0);
  }

  kpe_kernel<<<LSEQ * 160 / 256, 256, 0, stream>>>(gauss, KPE_);
  point_kernel<<<30, 64, 0, stream>>>(coords, labels, gauss, ptab, QPE_, QRY_);

  // ======== transformer phase, both batches per dispatch ========
  for (int i = 0; i < 2; ++i) {
    const float* saw = sa_w + (size_t)i * 4 * CDIM * CDIM;
    const float* sab = sa_b + (size_t)i * 4 * CDIM;
    smallmm<<<240, 256, 0, stream>>>(QRY_, (i == 0) ? nullptr : QPE_,
                                     saw, sab, P3_, 960, CDIM, 0, 0, 640);
    attn_self<<<dim3(4, 2), 128, 0, stream>>>(P3_, PO_);
    smallmm<<<80, 256, 0, stream>>>(PO_, nullptr, saw + 3 * 102400, sab + 3 * CDIM,
                                    QRY_, CDIM, CDIM, (i == 0) ? 0 : 1, 0, 0);
    ln_rows256<<<3, 256, 0, stream>>>(QRY_, norms_w + (size_t)(i * 4 + 0) * CDIM,
                                      norms_b + (size_t)(i * 4 + 0) * CDIM, 12);

    smallmm<<<40, 256, 0, stream>>>(QRY_, QPE_, t2i_w + (size_t)(i * 3 + 0) * 51200,
                                    t2i_b + (size_t)(i * 3 + 0) * 160, Q160_,
                                    160, CDIM, 0, 0, 160);
    // fused: cols 0-159 = t2i-K -> T0B (bf16); cols 160-319 = i2t-Q -> T3B.
    gemm_bf<<<dim3(5, 128, 2), 256, 0, stream>>>(
        R_K, t2i_w + (size_t)(i * 3 + 1) * 51200, t2i_b + (size_t)(i * 3 + 1) * 160,
        KPE_, T0B_, T3B_, i2t_w + (size_t)(i * 3 + 0) * 51200,
        i2t_b + (size_t)(i * 3 + 0) * 160, 160,
        LSEQ, 320, CDIM, CDIM, 160, 160, 160, 0, 0, 0, 1, sIMG320, sIMG160);
    gemm_bf<<<dim3(3, 128, 2), 256, 0, stream>>>(
        R_K, t2i_w + (size_t)(i * 3 + 2) * 51200, t2i_b + (size_t)(i * 3 + 2) * 160,
        nullptr, T1B_, nullptr, nullptr, nullptr, NOSPLIT,
        LSEQ, 160, CDIM, CDIM, 160, NOSPLIT, 0, 0, 0, 0, 1, sIMG320, sIMG160);
    attn_t2i_part2<<<dim3(64, 4, 2), 256, 0, stream>>>(Q160_, T0B_, T1B_, PART_);
    attn_t2i_comb<<<dim3(24, 2), 64, 0, stream>>>(PART_, O160_);
    smallmm<<<80, 256, 0, stream>>>(O160_, nullptr, t2i_ow + (size_t)i * 51200,
                                    t2i_ob + (size_t)i * CDIM, QRY_,
                                    CDIM, 160, 1, 0, 0);
    ln_rows256<<<3, 256, 0, stream>>>(QRY_, norms_w + (size_t)(i * 4 + 1) * CDIM,
                                      norms_b + (size_t)(i * 4 + 1) * CDIM, 12);

    smallmm<<<256, 256, 0, stream>>>(QRY_, nullptr, mlp_w1 + (size_t)i * 1024 * CDIM,
                                     mlp_b1 + (size_t)i * 1024, H_, 1024, CDIM, 0, 1, 0);
    smallmm<<<80, 256, 0, stream>>>(H_, nullptr, mlp_w2 + (size_t)i * CDIM * 1024,
                                    mlp_b2 + (size_t)i * CDIM, QRY_, CDIM, 1024, 1, 0, 0);
    ln_rows256<<<3, 256, 0, stream>>>(QRY_, norms_w + (size_t)(i * 4 + 2) * CDIM,
                                      norms_b + (size_t)(i * 4 + 2) * CDIM, 12);

    smallmm<<<80, 256, 0, stream>>>(QRY_, QPE_, i2t_w + (size_t)(i * 3 + 1) * 51200,
                                    i2t_b + (size_t)(i * 3 + 1) * 160, KV_,
                                    320, CDIM, 0, 0, 160);
    attn_i2t<<<dim3(LSEQ / 256, 4, 2), 256, 0, stream>>>(T3B_, KV_, T2B_);
    gemm_bf<<<dim3(5, 128, 2), 256, 0, stream>>>(
        T2B_, i2t_ow + (size_t)i * CDIM * 160, i2t_ob + (size_t)i * CDIM,
        nullptr, R_K, nullptr, nullptr, nullptr, NOSPLIT,
        LSEQ, CDIM, 160, 160, CDIM, NOSPLIT, 0, 1, 1, 0, 0, sIMG160, sIMG320);
    if (i == 0) {
      ln_rows256<<<2 * LSEQ / 4, 256, 0, stream>>>(
          R_K, norms_w + (size_t)3 * CDIM, norms_b + (size_t)3 * CDIM, 2 * LSEQ);
    }
  }

  // final layernorm fused with transpose to output layout (C,L)
  for (int b = 0; b < 2; ++b) {
    lnt<<<LSEQ / 32, 256, 0, stream>>>(
        R_K + (size_t)b * LSEQ * CDIM, norms_w + (size_t)7 * CDIM,
        norms_b + (size_t)7 * CDIM, out + (size_t)b * CDIM * LSEQ);
  }
}

// Round 8
// 957.980 us; speedup vs baseline: 1.8415x; 1.0451x over previous
//
#include <hip/hip_runtime.h>
#include <math.h>

#define LSEQ 16384
#define CDIM 320
#define DIN 640
#define NHH 8
#define CONVD 704
#define XBCW 712
#define QCH 64
#define NCHUNK 256

typedef __bf16 bf16_t;
typedef __bf16 bf16x8 __attribute__((ext_vector_type(8)));
typedef __bf16 bf16x4 __attribute__((ext_vector_type(4)));
typedef float f32x4 __attribute__((ext_vector_type(4)));

// ---------------- reduction helpers ----------------
__device__ __forceinline__ float wave_sum(float v) {
#pragma unroll
  for (int o = 32; o > 0; o >>= 1) v += __shfl_down(v, o, 64);
  return v;
}
__device__ __forceinline__ float wave_max(float v) {
#pragma unroll
  for (int o = 32; o > 0; o >>= 1) v = fmaxf(v, __shfl_down(v, o, 64));
  return v;
}
__device__ __forceinline__ float block_sum256(float v, float* red) {
  int tid = threadIdx.x;
  v = wave_sum(v);
  __syncthreads();
  if ((tid & 63) == 0) red[tid >> 6] = v;
  __syncthreads();
  return red[0] + red[1] + red[2] + red[3];
}

__global__ void ws_probe(float* out, float v) { out[0] = v; }

// ---------------- fp32 -> bf16 elementwise (n % 4 == 0) ----------------
__global__ void cvt_bf(const float* __restrict__ src, bf16_t* __restrict__ dst, int n) {
  int i = (blockIdx.x * 256 + threadIdx.x) * 4;
  if (i >= n) return;
  float4 v = *(const float4*)(src + i);
  bf16x4 o;
  o[0] = (bf16_t)v.x; o[1] = (bf16_t)v.y; o[2] = (bf16_t)v.z; o[3] = (bf16_t)v.w;
  *(bf16x4*)(dst + i) = o;
}

// -------- fused transpose + layernorm: x[b] (C,L) -> out (L,C) bf16 ----------
__global__ __launch_bounds__(256) void tln(const float* __restrict__ x,
                                           const float* __restrict__ w,
                                           const float* __restrict__ b,
                                           bf16_t* __restrict__ out) {
  __shared__ float sT[32][321];
  int t0 = blockIdx.x * 32;
  int tid = threadIdx.x;
  for (int i = tid; i < 2560; i += 256) {
    int c = i >> 3, j4 = i & 7;
    float4 v = *(const float4*)(x + (size_t)c * LSEQ + t0 + j4 * 4);
    sT[j4 * 4 + 0][c] = v.x;
    sT[j4 * 4 + 1][c] = v.y;
    sT[j4 * 4 + 2][c] = v.z;
    sT[j4 * 4 + 3][c] = v.w;
  }
  __syncthreads();
  int wave = tid >> 6, lane = tid & 63;
  for (int tt = wave; tt < 32; tt += 4) {
    float xv[5];
    float s = 0.f;
#pragma unroll
    for (int k = 0; k < 5; ++k) { xv[k] = sT[tt][lane + 64 * k]; s += xv[k]; }
    s = wave_sum(s); s = __shfl(s, 0, 64);
    float mean = s * (1.f / 320.f);
    float v = 0.f;
#pragma unroll
    for (int k = 0; k < 5; ++k) { float d = xv[k] - mean; v += d * d; }
    v = wave_sum(v); v = __shfl(v, 0, 64);
    float rstd = rsqrtf(v * (1.f / 320.f) + 1e-5f);
    bf16_t* op = out + (size_t)(t0 + tt) * CDIM;
#pragma unroll
    for (int k = 0; k < 5; ++k) {
      int i = lane + 64 * k;
      op[i] = (bf16_t)((xv[k] - mean) * rstd * w[i] + b[i]);
    }
  }
}

// -------- fused layernorm + transpose: in (L,C) -> out (C,L), LN over C ------
__global__ __launch_bounds__(256) void lnt(const float* __restrict__ in,
                                           const float* __restrict__ w,
                                           const float* __restrict__ b,
                                           float* __restrict__ out) {
  __shared__ float sT[CDIM][33];
  int t0 = blockIdx.x * 32;
  int tid = threadIdx.x;
  int wave = tid >> 6, lane = tid & 63;
  for (int tt = wave; tt < 32; tt += 4) {
    const float* xp = in + (size_t)(t0 + tt) * CDIM;
    float x[5];
    float s = 0.f;
#pragma unroll
    for (int k = 0; k < 5; ++k) { x[k] = xp[lane + 64 * k]; s += x[k]; }
    s = wave_sum(s); s = __shfl(s, 0, 64);
    float mean = s * (1.f / 320.f);
    float v = 0.f;
#pragma unroll
    for (int k = 0; k < 5; ++k) { float d = x[k] - mean; v += d * d; }
    v = wave_sum(v); v = __shfl(v, 0, 64);
    float rstd = rsqrtf(v * (1.f / 320.f) + 1e-5f);
#pragma unroll
    for (int k = 0; k < 5; ++k) {
      int i = lane + 64 * k;
      sT[i][tt] = (x[k] - mean) * rstd * w[i] + b[i];
    }
  }
  __syncthreads();
  for (int i = tid; i < 320 * 32; i += 256) {
    int cc = i >> 5, t = i & 31;
    out[(size_t)cc * LSEQ + t0 + t] = sT[cc][t];
  }
}

// ---------------- layernorm rows (D=320), one wave per row, 4 rows/block -----
__global__ __launch_bounds__(256) void ln_rows256(float* __restrict__ io,
                                                  const float* __restrict__ w,
                                                  const float* __restrict__ b,
                                                  int nrows) {
  int row = blockIdx.x * 4 + (threadIdx.x >> 6);
  if (row >= nrows) return;
  float* xp = io + (size_t)row * CDIM;
  int lane = threadIdx.x & 63;
  float x[5];
  float s = 0.f;
#pragma unroll
  for (int k = 0; k < 5; ++k) { x[k] = xp[lane + 64 * k]; s += x[k]; }
  s = wave_sum(s); s = __shfl(s, 0, 64);
  float mean = s * (1.f / 320.f);
  float v = 0.f;
#pragma unroll
  for (int k = 0; k < 5; ++k) { float t = x[k] - mean; v += t * t; }
  v = wave_sum(v); v = __shfl(v, 0, 64);
  float rstd = rsqrtf(v * (1.f / 320.f) + 1e-5f);
#pragma unroll
  for (int k = 0; k < 5; ++k) {
    int i = lane + 64 * k;
    xp[i] = (x[k] - mean) * rstd * w[i] + b[i];
  }
}

// ------------- bf16 MFMA GEMM, 128x64 tile, XCD-chunked swizzle --------------
// C = (A (+pe)) @ [W;W2]^T (+bias/bias2) (+=C).  Column split at nsplit.
// abf: A bf16 (pe must be null).  wbf: W/W2 bf16.  cbf: C/C2 bf16 (addC=0).
__global__ __launch_bounds__(256) void gemm_bf(
    const void* __restrict__ A, const void* __restrict__ W,
    const float* __restrict__ bias, const float* __restrict__ pe,
    void* __restrict__ C, void* __restrict__ C2,
    const void* __restrict__ W2, const float* __restrict__ bias2, int wsplit,
    int M, int N, int K, int lda, int ldc, int nsplit, int ldc2,
    int addC, int abf, int wbf, int cbf, long long sA, long long sC) {
  int z = blockIdx.z;
  // bijective XCD-chunked swizzle
  int gx = gridDim.x;
  int nwg = gx * gridDim.y;
  int lin = blockIdx.y * gx + blockIdx.x;
  int xcd = lin & 7, idx = lin >> 3;
  int q = nwg >> 3, r = nwg & 7;
  int base = (xcd < r) ? xcd * (q + 1) : r * (q + 1) + (xcd - r) * q;
  int lin2 = base + idx;
  int mblk = lin2 / gx, nblk = lin2 % gx;
  int m0 = mblk << 7, n0 = nblk << 6;

  __shared__ __align__(16) bf16_t As[2][4096];
  __shared__ __align__(16) bf16_t Ws[2][2048];
  int tid = threadIdx.x;
  int wave = tid >> 6, lane = tid & 63;
  int fm = lane & 15, quad = lane >> 4;
  int rA = tid >> 1, hA = tid & 1;  // A row (0..127), col-half (16 elems)
  int rW = tid >> 2, qW = tid & 3;  // W row (0..63), col-quad (8 elems)
  const float* ag = nullptr;
  const bf16_t* agb = nullptr;
  const float* peg = nullptr;
  if (abf) {
    agb = (const bf16_t*)A + (size_t)z * sA + (size_t)(m0 + rA) * lda + hA * 16;
  } else {
    ag = (const float*)A + (size_t)z * sA + (size_t)(m0 + rA) * lda + hA * 16;
    if (pe) peg = pe + (size_t)(m0 + rA) * lda + hA * 16;
  }
  int wRow = n0 + rW;
  bool wok = wRow < N;
  const float* wg = nullptr;
  const bf16_t* wgb = nullptr;
  {
    const void* Wsel = (wRow < wsplit) ? W : W2;
    int wr = (wRow < wsplit) ? wRow : wRow - wsplit;
    if (wbf) wgb = (const bf16_t*)Wsel + (size_t)wr * K + qW * 8;
    else     wg  = (const float*)Wsel + (size_t)wr * K + qW * 8;
  }
  int aoff = (rA >> 4) * 512 + (hA * 32 + (rA & 15)) * 8;
  int woff = (rW >> 4) * 512 + (qW * 16 + (rW & 15)) * 8;

  f32x4 acc[2][4];
#pragma unroll
  for (int i = 0; i < 2; ++i)
#pragma unroll
    for (int j = 0; j < 4; ++j) acc[i][j] = (f32x4){0.f, 0.f, 0.f, 0.f};

  bf16x8 ra0, ra1, rw;
  float4 pa0, pa1, pa2, pa3, pw0, pw1;
  auto loadG = [&](int k0) {
    if (abf) {
      ra0 = *(const bf16x8*)(agb + k0);
      ra1 = *(const bf16x8*)(agb + k0 + 8);
    } else {
      pa0 = *(const float4*)(ag + k0);
      pa1 = *(const float4*)(ag + k0 + 4);
      pa2 = *(const float4*)(ag + k0 + 8);
      pa3 = *(const float4*)(ag + k0 + 12);
      if (peg) {
        float4 q0 = *(const float4*)(peg + k0);
        float4 q1 = *(const float4*)(peg + k0 + 4);
        float4 q2 = *(const float4*)(peg + k0 + 8);
        float4 q3 = *(const float4*)(peg + k0 + 12);
        pa0.x += q0.x; pa0.y += q0.y; pa0.z += q0.z; pa0.w += q0.w;
        pa1.x += q1.x; pa1.y += q1.y; pa1.z += q1.z; pa1.w += q1.w;
        pa2.x += q2.x; pa2.y += q2.y; pa2.z += q2.z; pa2.w += q2.w;
        pa3.x += q3.x; pa3.y += q3.y; pa3.z += q3.z; pa3.w += q3.w;
      }
    }
    if (wbf) {
      if (wok) rw = *(const bf16x8*)(wgb + k0);
      else {
#pragma unroll
        for (int j = 0; j < 8; ++j) rw[j] = (bf16_t)0.f;
      }
    } else {
      pw0 = make_float4(0.f, 0.f, 0.f, 0.f);
      pw1 = pw0;
      if (wok) {
        pw0 = *(const float4*)(wg + k0);
        pw1 = *(const float4*)(wg + k0 + 4);
      }
    }
  };
  auto packLDS = [&](int buf) {
    if (!abf) {
      ra0[0] = (bf16_t)pa0.x; ra0[1] = (bf16_t)pa0.y; ra0[2] = (bf16_t)pa0.z; ra0[3] = (bf16_t)pa0.w;
      ra0[4] = (bf16_t)pa1.x; ra0[5] = (bf16_t)pa1.y; ra0[6] = (bf16_t)pa1.z; ra0[7] = (bf16_t)pa1.w;
      ra1[0] = (bf16_t)pa2.x; ra1[1] = (bf16_t)pa2.y; ra1[2] = (bf16_t)pa2.z; ra1[3] = (bf16_t)pa2.w;
      ra1[4] = (bf16_t)pa3.x; ra1[5] = (bf16_t)pa3.y; ra1[6] = (bf16_t)pa3.z; ra1[7] = (bf16_t)pa3.w;
    }
    *(bf16x8*)&As[buf][aoff] = ra0;
    *(bf16x8*)&As[buf][aoff + 128] = ra1;
    if (!wbf) {
      rw[0] = (bf16_t)pw0.x; rw[1] = (bf16_t)pw0.y; rw[2] = (bf16_t)pw0.z; rw[3] = (bf16_t)pw0.w;
      rw[4] = (bf16_t)pw1.x; rw[5] = (bf16_t)pw1.y; rw[6] = (bf16_t)pw1.z; rw[7] = (bf16_t)pw1.w;
    }
    *(bf16x8*)&Ws[buf][woff] = rw;
  };

  int nk = K >> 5;
  loadG(0);
  packLDS(0);
  __syncthreads();
  for (int i = 0; i < nk; ++i) {
    int buf = i & 1;
    bool more = (i + 1 < nk);
    if (more) loadG((i + 1) << 5);
    int ab = wave * 1024 + lane * 8;
    bf16x8 af0 = *(bf16x8*)&As[buf][ab];
    bf16x8 af1 = *(bf16x8*)&As[buf][ab + 512];
    bf16x8 b0 = *(bf16x8*)&Ws[buf][lane * 8];
    bf16x8 b1 = *(bf16x8*)&Ws[buf][512 + lane * 8];
    bf16x8 b2 = *(bf16x8*)&Ws[buf][1024 + lane * 8];
    bf16x8 b3 = *(bf16x8*)&Ws[buf][1536 + lane * 8];
    acc[0][0] = __builtin_amdgcn_mfma_f32_16x16x32_bf16(af0, b0, acc[0][0], 0, 0, 0);
    acc[0][1] = __builtin_amdgcn_mfma_f32_16x16x32_bf16(af0, b1, acc[0][1], 0, 0, 0);
    acc[0][2] = __builtin_amdgcn_mfma_f32_16x16x32_bf16(af0, b2, acc[0][2], 0, 0, 0);
    acc[0][3] = __builtin_amdgcn_mfma_f32_16x16x32_bf16(af0, b3, acc[0][3], 0, 0, 0);
    acc[1][0] = __builtin_amdgcn_mfma_f32_16x16x32_bf16(af1, b0, acc[1][0], 0, 0, 0);
    acc[1][1] = __builtin_amdgcn_mfma_f32_16x16x32_bf16(af1, b1, acc[1][1], 0, 0, 0);
    acc[1][2] = __builtin_amdgcn_mfma_f32_16x16x32_bf16(af1, b2, acc[1][2], 0, 0, 0);
    acc[1][3] = __builtin_amdgcn_mfma_f32_16x16x32_bf16(af1, b3, acc[1][3], 0, 0, 0);
    if (more) {
      packLDS(buf ^ 1);
      __syncthreads();
    }
  }
#pragma unroll
  for (int ms = 0; ms < 2; ++ms)
#pragma unroll
    for (int ns = 0; ns < 4; ++ns) {
      int n = n0 + ns * 16 + fm;
      if (n >= N) continue;
      float bv = 0.f;
      if (n < wsplit) { if (bias) bv = bias[n]; }
      else            { if (bias2) bv = bias2[n - wsplit]; }
      void* Cb;
      int ldcb, nc;
      if (n < nsplit) { Cb = C; ldcb = ldc; nc = n; }
      else            { Cb = C2; ldcb = ldc2; nc = n - nsplit; }
#pragma unroll
      for (int rr = 0; rr < 4; ++rr) {
        int m = m0 + wave * 32 + ms * 16 + quad * 4 + rr;
        float v = acc[ms][ns][rr] + bv;
        size_t off = (size_t)z * sC + (size_t)m * ldcb + nc;
        if (cbf) {
          ((bf16_t*)Cb)[off] = (bf16_t)v;
        } else {
          float* Cf = (float*)Cb;
          if (addC) v += Cf[off];
          Cf[off] = v;
        }
      }
    }
}

// ------------- bf16 MFMA GEMM, 64x64 tile (latency-optimized) ----------------
// Same semantics as gemm_bf but BM=64: 2x the blocks for thin-N streaming
// projections (latency-bound at 128-tile: occupancy 30%, all pipes idle).
__global__ __launch_bounds__(256) void gemm64(
    const void* __restrict__ A, const void* __restrict__ W,
    const float* __restrict__ bias, const float* __restrict__ pe,
    void* __restrict__ C, void* __restrict__ C2,
    const void* __restrict__ W2, const float* __restrict__ bias2, int wsplit,
    int M, int N, int K, int lda, int ldc, int nsplit, int ldc2,
    int addC, int abf, int wbf, int cbf, long long sA, long long sC) {
  int z = blockIdx.z;
  int gx = gridDim.x;
  int nwg = gx * gridDim.y;
  int lin = blockIdx.y * gx + blockIdx.x;
  int xcd = lin & 7, idx = lin >> 3;
  int q = nwg >> 3, r = nwg & 7;
  int base = (xcd < r) ? xcd * (q + 1) : r * (q + 1) + (xcd - r) * q;
  int lin2 = base + idx;
  int mblk = lin2 / gx, nblk = lin2 % gx;
  int m0 = mblk << 6, n0 = nblk << 6;

  __shared__ __align__(16) bf16_t As[2][2048];
  __shared__ __align__(16) bf16_t Ws[2][2048];
  int tid = threadIdx.x;
  int wave = tid >> 6, lane = tid & 63;
  int fm = lane & 15, quad = lane >> 4;
  int rA = tid >> 2, qA = tid & 3;  // row 0..63, col-quad (8 elems)
  const float* ag = nullptr;
  const bf16_t* agb = nullptr;
  const float* peg = nullptr;
  if (abf) {
    agb = (const bf16_t*)A + (size_t)z * sA + (size_t)(m0 + rA) * lda + qA * 8;
  } else {
    ag = (const float*)A + (size_t)z * sA + (size_t)(m0 + rA) * lda + qA * 8;
    if (pe) peg = pe + (size_t)(m0 + rA) * lda + qA * 8;
  }
  int wRow = n0 + rA;
  bool wok = wRow < N;
  const float* wg = nullptr;
  const bf16_t* wgb = nullptr;
  {
    const void* Wsel = (wRow < wsplit) ? W : W2;
    int wr = (wRow < wsplit) ? wRow : wRow - wsplit;
    if (wbf) wgb = (const bf16_t*)Wsel + (size_t)wr * K + qA * 8;
    else     wg  = (const float*)Wsel + (size_t)wr * K + qA * 8;
  }
  int off = (rA >> 4) * 512 + (qA * 16 + (rA & 15)) * 8;

  f32x4 acc[4];
#pragma unroll
  for (int j = 0; j < 4; ++j) acc[j] = (f32x4){0.f, 0.f, 0.f, 0.f};

  bf16x8 ra, rw;
  float4 pa0, pa1, pw0, pw1;
  auto loadG = [&](int k0) {
    if (abf) {
      ra = *(const bf16x8*)(agb + k0);
    } else {
      pa0 = *(const float4*)(ag + k0);
      pa1 = *(const float4*)(ag + k0 + 4);
      if (peg) {
        float4 q0 = *(const float4*)(peg + k0);
        float4 q1 = *(const float4*)(peg + k0 + 4);
        pa0.x += q0.x; pa0.y += q0.y; pa0.z += q0.z; pa0.w += q0.w;
        pa1.x += q1.x; pa1.y += q1.y; pa1.z += q1.z; pa1.w += q1.w;
      }
    }
    if (wbf) {
      if (wok) rw = *(const bf16x8*)(wgb + k0);
      else {
#pragma unroll
        for (int j = 0; j < 8; ++j) rw[j] = (bf16_t)0.f;
      }
    } else {
      pw0 = make_float4(0.f, 0.f, 0.f, 0.f);
      pw1 = pw0;
      if (wok) {
        pw0 = *(const float4*)(wg + k0);
        pw1 = *(const float4*)(wg + k0 + 4);
      }
    }
  };
  auto packLDS = [&](int buf) {
    if (!abf) {
      ra[0] = (bf16_t)pa0.x; ra[1] = (bf16_t)pa0.y; ra[2] = (bf16_t)pa0.z; ra[3] = (bf16_t)pa0.w;
      ra[4] = (bf16_t)pa1.x; ra[5] = (bf16_t)pa1.y; ra[6] = (bf16_t)pa1.z; ra[7] = (bf16_t)pa1.w;
    }
    *(bf16x8*)&As[buf][off] = ra;
    if (!wbf) {
      rw[0] = (bf16_t)pw0.x; rw[1] = (bf16_t)pw0.y; rw[2] = (bf16_t)pw0.z; rw[3] = (bf16_t)pw0.w;
      rw[4] = (bf16_t)pw1.x; rw[5] = (bf16_t)pw1.y; rw[6] = (bf16_t)pw1.z; rw[7] = (bf16_t)pw1.w;
    }
    *(bf16x8*)&Ws[buf][off] = rw;
  };

  int nk = K >> 5;
  loadG(0);
  packLDS(0);
  __syncthreads();
  for (int i = 0; i < nk; ++i) {
    int buf = i & 1;
    bool more = (i + 1 < nk);
    if (more) loadG((i + 1) << 5);
    bf16x8 af = *(bf16x8*)&As[buf][wave * 512 + lane * 8];
    bf16x8 b0 = *(bf16x8*)&Ws[buf][lane * 8];
    bf16x8 b1 = *(bf16x8*)&Ws[buf][512 + lane * 8];
    bf16x8 b2 = *(bf16x8*)&Ws[buf][1024 + lane * 8];
    bf16x8 b3 = *(bf16x8*)&Ws[buf][1536 + lane * 8];
    acc[0] = __builtin_amdgcn_mfma_f32_16x16x32_bf16(af, b0, acc[0], 0, 0, 0);
    acc[1] = __builtin_amdgcn_mfma_f32_16x16x32_bf16(af, b1, acc[1], 0, 0, 0);
    acc[2] = __builtin_amdgcn_mfma_f32_16x16x32_bf16(af, b2, acc[2], 0, 0, 0);
    acc[3] = __builtin_amdgcn_mfma_f32_16x16x32_bf16(af, b3, acc[3], 0, 0, 0);
    if (more) {
      packLDS(buf ^ 1);
      __syncthreads();
    }
  }
#pragma unroll
  for (int ns = 0; ns < 4; ++ns) {
    int n = n0 + ns * 16 + fm;
    if (n >= N) continue;
    float bv = 0.f;
    if (n < wsplit) { if (bias) bv = bias[n]; }
    else            { if (bias2) bv = bias2[n - wsplit]; }
    void* Cb;
    int ldcb, nc;
    if (n < nsplit) { Cb = C; ldcb = ldc; nc = n; }
    else            { Cb = C2; ldcb = ldc2; nc = n - nsplit; }
#pragma unroll
    for (int rr = 0; rr < 4; ++rr) {
      int m = m0 + wave * 16 + quad * 4 + rr;
      float v = acc[ns][rr] + bv;
      size_t off2 = (size_t)z * sC + (size_t)m * ldcb + nc;
      if (cbf) {
        ((bf16_t*)Cb)[off2] = (bf16_t)v;
      } else {
        float* Cf = (float*)Cb;
        if (addC) v += Cf[off2];
        Cf[off2] = v;
      }
    }
  }
}

// -------- small matmul (token side), M=12 fixed, wave-per-output-column ------
__global__ __launch_bounds__(256) void smallmm(
    const float* __restrict__ A, const float* __restrict__ A2,
    const float* __restrict__ W, const float* __restrict__ bias,
    float* __restrict__ C, int N, int K, int addC, int relu, int a2lim) {
  int wave = threadIdx.x >> 6, lane = threadIdx.x & 63;
  int n = blockIdx.x * 4 + wave;
  if (n >= N) return;
  const float* w = W + (size_t)n * K;
  bool useA2 = (A2 != nullptr) && (n < a2lim);
  float part[12];
#pragma unroll
  for (int m = 0; m < 12; ++m) part[m] = 0.f;
  for (int k0 = 0; k0 < K; k0 += 64) {
    int k = k0 + lane;
    if (k < K) {
      float wv = w[k];
      const float* ap = A + k;
      if (useA2) {
        const float* ap2 = A2 + k;
#pragma unroll
        for (int m = 0; m < 12; ++m)
          part[m] = fmaf(ap[(size_t)m * K] + ap2[(size_t)m * K], wv, part[m]);
      } else {
#pragma unroll
        for (int m = 0; m < 12; ++m)
          part[m] = fmaf(ap[(size_t)m * K], wv, part[m]);
      }
    }
  }
  float bv = bias ? bias[n] : 0.f;
#pragma unroll
  for (int m = 0; m < 12; ++m) {
    float dot = wave_sum(part[m]);
    if (lane == 0) {
      float v = dot + bv;
      if (relu) v = fmaxf(v, 0.f);
      size_t off = (size_t)m * N + n;
      if (addC) v += C[off];
      C[off] = v;
    }
  }
}

// ---------------- dt = softplus(dt_raw + dt_bias), layout (h,t) --------------
__global__ void dt_kernel(const bf16_t* __restrict__ XBC, const float* __restrict__ dt_bias,
                          float* __restrict__ dtbuf) {
  int idx = blockIdx.x * 256 + threadIdx.x;
  if (idx >= LSEQ * NHH) return;
  int h = idx & 7;
  int t = idx >> 3;
  float v = (float)XBC[(size_t)t * XBCW + 704 + h] + dt_bias[h];
  float sp = (v > 20.f) ? v : log1pf(expf(v));
  dtbuf[(size_t)h * LSEQ + t] = sp;
}

// ------- causal depthwise conv + silu, sliding-window registers, bf16 IO -----
__global__ __launch_bounds__(256) void conv2(const bf16_t* __restrict__ XBC,
                                             const float* __restrict__ conv_w,
                                             const float* __restrict__ conv_b,
                                             bf16_t* __restrict__ Cv) {
  int lane = threadIdx.x & 63, wv = threadIdx.x >> 6;
  int d = blockIdx.x * 64 + lane;
  int t0 = (blockIdx.y * 4 + wv) * 32;
  float w0 = conv_w[d * 4 + 0], w1 = conv_w[d * 4 + 1];
  float w2 = conv_w[d * 4 + 2], w3 = conv_w[d * 4 + 3];
  float bv = conv_b[d];
  const bf16_t* src = XBC + d;
  float xm3, xm2, xm1;
  if (t0 == 0) {
    xm3 = 0.f; xm2 = 0.f; xm1 = 0.f;
  } else {
    xm3 = (float)src[(size_t)(t0 - 3) * XBCW];
    xm2 = (float)src[(size_t)(t0 - 2) * XBCW];
    xm1 = (float)src[(size_t)(t0 - 1) * XBCW];
  }
#pragma unroll 8
  for (int t = t0; t < t0 + 32; ++t) {
    float xt = (float)src[(size_t)t * XBCW];
    float a = bv + xm3 * w0 + xm2 * w1 + xm1 * w2 + xt * w3;
    Cv[(size_t)t * CONVD + d] = (bf16_t)(a / (1.f + expf(-a)));
    xm3 = xm2; xm2 = xm1; xm1 = xt;
  }
}

// ---------------- scan phase A: per-chunk states + cumulative log-decay ------
__global__ __launch_bounds__(256) void scan_a(const bf16_t* __restrict__ Cv,
                                              const float* __restrict__ dtbuf,
                                              const float* __restrict__ A_log,
                                              float* __restrict__ Schunk,
                                              float* __restrict__ cabuf) {
  int c = blockIdx.x, h = blockIdx.y;
  int t0 = c * QCH;
  __shared__ float sdt[64], sca[64], sw[64];
  __shared__ __align__(16) float sB[64][36];
  __shared__ __align__(16) float sXt[80][68];
  int tid = threadIdx.x;
  float Aval = -expf(A_log[h]);
  if (tid < 64) sdt[tid] = dtbuf[(size_t)h * LSEQ + t0 + tid];
  __syncthreads();
  if (tid == 0) {
    float run = 0.f;
    for (int j = 0; j < 64; ++j) { run += sdt[j] * Aval; sca[j] = run; }
  }
  __syncthreads();
  float caend = sca[63];
  if (tid < 64) {
    sw[tid] = expf(caend - sca[tid]) * sdt[tid];
    cabuf[(size_t)h * LSEQ + t0 + tid] = sca[tid];
  }
  for (int i = tid; i < 2048; i += 256) {
    int j = i >> 5, n = i & 31;
    sB[j][n] = (float)Cv[(size_t)(t0 + j) * CONVD + 640 + n];
  }
  for (int i = tid; i < 5120; i += 256) {
    int j = i / 80, p = i % 80;
    sXt[p][j] = (float)Cv[(size_t)(t0 + j) * CONVD + h * 80 + p];
  }
  __syncthreads();
  int n = tid >> 3, pb = tid & 7;
  float acc[10];
#pragma unroll
  for (int u = 0; u < 10; ++u) acc[u] = 0.f;
  for (int jb = 0; jb < 16; ++jb) {
    float wB[4];
#pragma unroll
    for (int jj = 0; jj < 4; ++jj) {
      int j = jb * 4 + jj;
      wB[jj] = sw[j] * sB[j][n];
    }
#pragma unroll
    for (int u = 0; u < 10; ++u) {
      int p = pb * 10 + u;
      float4 x4 = *(const float4*)&sXt[p][jb * 4];
      acc[u] += wB[0] * x4.x + wB[1] * x4.y + wB[2] * x4.z + wB[3] * x4.w;
    }
  }
  float* outp = Schunk + (size_t)(h * NCHUNK + c) * 2560;
#pragma unroll
  for (int u = 0; u < 10; ++u) outp[n * 80 + pb * 10 + u] = acc[u];
}

// ---------------- scan phase B: sequential over chunks, 80 blocks ------------
__global__ __launch_bounds__(256) void scan_b(const float* __restrict__ Schunk,
                                              const float* __restrict__ cabuf,
                                              float* __restrict__ Sprev) {
  int pc = blockIdx.x, h = blockIdx.y;
  __shared__ float sdec[256];
  int tid = threadIdx.x;
  sdec[tid] = expf(cabuf[(size_t)h * LSEQ + tid * 64 + 63]);
  __syncthreads();
  int e = pc * 256 + tid;
  const float* base = Schunk + (size_t)h * NCHUNK * 2560 + e;
  float* pbase = Sprev + (size_t)h * NCHUNK * 2560 + e;
  float s = 0.f;
  float v = base[0];
  for (int c = 0; c < NCHUNK; ++c) {
    float vn = (c < NCHUNK - 1) ? base[(size_t)(c + 1) * 2560] : 0.f;
    pbase[(size_t)c * 2560] = s;
    s = s * sdec[c] + v;
    v = vn;
  }
}

// ---------------- scan phase C: MFMA; Y -> separate bf16 buffer --------------
__global__ __launch_bounds__(256) void scan_c(const bf16_t* __restrict__ Cv,
                                              const float* __restrict__ dtbuf,
                                              const float* __restrict__ cabuf,
                                              const float* __restrict__ Sprev,
                                              const float* __restrict__ Dp,
                                              bf16_t* __restrict__ Y) {
  int c = blockIdx.x, h = blockIdx.y;
  int t0 = c * QCH;
  __shared__ float sdt[64], sca[64], sexp[64];
  __shared__ __align__(16) bf16_t sC[64 * 40];
  __shared__ __align__(16) bf16_t sB[64 * 40];
  __shared__ __align__(16) bf16_t sXt[80 * 72];
  __shared__ __align__(16) bf16_t sSt[80 * 40];
  __shared__ __align__(16) bf16_t sP[64 * 72];
  int tid = threadIdx.x;
  int wave = tid >> 6, lane = tid & 63;
  int fm = lane & 15, quad = lane >> 4;
  if (tid < 64) {
    sdt[tid] = dtbuf[(size_t)h * LSEQ + t0 + tid];
    float cav = cabuf[(size_t)h * LSEQ + t0 + tid];
    sca[tid] = cav;
    sexp[tid] = expf(cav);
  }
  for (int i = tid; i < 2048; i += 256) {
    int j = i >> 5, n = i & 31;
    size_t base = (size_t)(t0 + j) * CONVD;
    sB[j * 40 + n] = Cv[base + 640 + n];
    sC[j * 40 + n] = Cv[base + 672 + n];
  }
  for (int i = tid; i < 5120; i += 256) {
    int j = i / 80, p = i % 80;
    sXt[p * 72 + j] = Cv[(size_t)(t0 + j) * CONVD + h * 80 + p];
  }
  {
    const float* sp = Sprev + (size_t)(h * NCHUNK + c) * 2560;
    for (int i = tid; i < 2560; i += 256) {
      int n = i / 80, p = i % 80;
      sSt[p * 40 + n] = (bf16_t)sp[i];
    }
  }
  __syncthreads();
  int m0 = wave * 16;
  int jbase = m0 + quad * 4;
  bf16x8 afC = *(bf16x8*)&sC[(m0 + fm) * 40 + quad * 8];
  f32x4 accS[4];
#pragma unroll
  for (int nt = 0; nt < 4; ++nt) {
    bf16x8 bf = *(bf16x8*)&sB[(nt * 16 + fm) * 40 + quad * 8];
    f32x4 zero = (f32x4){0.f, 0.f, 0.f, 0.f};
    accS[nt] = __builtin_amdgcn_mfma_f32_16x16x32_bf16(afC, bf, zero, 0, 0, 0);
  }
  float scaj[4];
#pragma unroll
  for (int r = 0; r < 4; ++r) scaj[r] = sca[jbase + r];
#pragma unroll
  for (int nt = 0; nt < 4; ++nt) {
    int s = nt * 16 + fm;
    float dts = sdt[s], scas = sca[s];
#pragma unroll
    for (int r = 0; r < 4; ++r) {
      int j = jbase + r;
      float v = 0.f;
      if (s <= j) v = accS[nt][r] * dts * expf(scaj[r] - scas);
      sP[j * 72 + s] = (bf16_t)v;
    }
  }
  f32x4 acc[5];
#pragma unroll
  for (int pt = 0; pt < 5; ++pt) {
    bf16x8 bf = *(bf16x8*)&sSt[(pt * 16 + fm) * 40 + quad * 8];
    f32x4 zero = (f32x4){0.f, 0.f, 0.f, 0.f};
    acc[pt] = __builtin_amdgcn_mfma_f32_16x16x32_bf16(afC, bf, zero, 0, 0, 0);
  }
  float gj[4];
#pragma unroll
  for (int r = 0; r < 4; ++r) gj[r] = sexp[jbase + r];
#pragma unroll
  for (int pt = 0; pt < 5; ++pt)
#pragma unroll
    for (int r = 0; r < 4; ++r) acc[pt][r] *= gj[r];
  bf16x8 afP0 = *(bf16x8*)&sP[(m0 + fm) * 72 + 0 + quad * 8];
  bf16x8 afP1 = *(bf16x8*)&sP[(m0 + fm) * 72 + 32 + quad * 8];
#pragma unroll
  for (int pt = 0; pt < 5; ++pt) {
    bf16x8 bx0 = *(bf16x8*)&sXt[(pt * 16 + fm) * 72 + 0 + quad * 8];
    bf16x8 bx1 = *(bf16x8*)&sXt[(pt * 16 + fm) * 72 + 32 + quad * 8];
    acc[pt] = __builtin_amdgcn_mfma_f32_16x16x32_bf16(afP0, bx0, acc[pt], 0, 0, 0);
    acc[pt] = __builtin_amdgcn_mfma_f32_16x16x32_bf16(afP1, bx1, acc[pt], 0, 0, 0);
  }
  float dval = Dp[h];
#pragma unroll
  for (int pt = 0; pt < 5; ++pt) {
    int p = pt * 16 + fm;
#pragma unroll
    for (int r = 0; r < 4; ++r) {
      int j = jbase + r;
      float xv = (float)sXt[p * 72 + j];
      Y[(size_t)(t0 + j) * DIN + h * 80 + p] = (bf16_t)(acc[pt][r] + dval * xv);
    }
  }
}

// ------- y *= silu(z); rmsnorm * rms_w; bf16 in-place ------------------------
__global__ __launch_bounds__(256) void gate_rms(bf16_t* __restrict__ YS,
                                                const bf16_t* __restrict__ Z,
                                                const float* __restrict__ rms_w) {
  __shared__ float red[4];
  size_t row = blockIdx.x;
  bf16_t* y = YS + row * DIN;
  const bf16_t* z = Z + row * DIN;
  int tid = threadIdx.x;
  float g0, g1, g2 = 0.f;
  {
    float zi = (float)z[tid];
    g0 = (float)y[tid] * (zi / (1.f + expf(-zi)));
    zi = (float)z[tid + 256];
    g1 = (float)y[tid + 256] * (zi / (1.f + expf(-zi)));
    if (tid + 512 < DIN) {
      zi = (float)z[tid + 512];
      g2 = (float)y[tid + 512] * (zi / (1.f + expf(-zi)));
    }
  }
  float ss = g0 * g0 + g1 * g1 + g2 * g2;
  float tot = block_sum256(ss, red);
  float r = rsqrtf(tot / (float)DIN + 1e-5f);
  y[tid] = (bf16_t)(g0 * r * rms_w[tid]);
  y[tid + 256] = (bf16_t)(g1 * r * rms_w[tid + 256]);
  if (tid + 512 < DIN) y[tid + 512] = (bf16_t)(g2 * r * rms_w[tid + 512]);
}

// ---------------- dense image PE ----------------
__global__ void kpe_kernel(const float* __restrict__ gauss, float* __restrict__ KPE) {
  int idx = blockIdx.x * 256 + threadIdx.x;
  if (idx >= LSEQ * 160) return;
  int f = idx % 160, t = idx / 160;
  int d = t >> 10, hh = (t >> 5) & 31, w = t & 31;
  float vx = 2.f * ((d + 0.5f) / 16.f) - 1.f;
  float vy = 2.f * ((hh + 0.5f) / 32.f) - 1.f;
  float vz = 2.f * ((w + 0.5f) / 32.f) - 1.f;
  float cc = 6.28318530717958647692f * (vx * gauss[f] + vy * gauss[160 + f] + vz * gauss[320 + f]);
  KPE[(size_t)t * CDIM + f] = sinf(cc);
  KPE[(size_t)t * CDIM + 160 + f] = cosf(cc);
}

// ---------------- point embeddings (both batches: 12 points) -----------------
__global__ void point_kernel(const float* __restrict__ coords, const int* __restrict__ labels,
                             const float* __restrict__ gauss, const float* __restrict__ ptab,
                             float* __restrict__ qpe, float* __restrict__ queries) {
  int idx = blockIdx.x * 64 + threadIdx.x;
  if (idx >= 12 * 160) return;
  int f = idx % 160, pt = idx / 160;
  const float* co = coords + pt * 3;
  float vx = 2.f * (co[0] / 128.f) - 1.f;
  float vy = 2.f * (co[1] / 256.f) - 1.f;
  float vz = 2.f * (co[2] / 256.f) - 1.f;
  float cc = 6.28318530717958647692f * (vx * gauss[f] + vy * gauss[160 + f] + vz * gauss[320 + f]);
  int lab = labels[pt];
  float sv = sinf(cc) + ptab[lab * CDIM + f];
  float cv = cosf(cc) + ptab[lab * CDIM + 160 + f];
  qpe[pt * CDIM + f] = sv;       qpe[pt * CDIM + 160 + f] = cv;
  queries[pt * CDIM + f] = sv;   queries[pt * CDIM + 160 + f] = cv;
}

// --------- self-attn over 6 tokens from fused P3[12][960], grid (4,2) --------
__global__ void attn_self(const float* __restrict__ P3, float* __restrict__ O) {
  int h = blockIdx.x, b = blockIdx.y;
  __shared__ float sq[6][80], sk[6][80], sv[6][80], sw[6][6];
  int tid = threadIdx.x;  // 128
  for (int i = tid; i < 480; i += 128) {
    int tok = i / 80, p = i % 80;
    const float* base = P3 + (size_t)(b * 6 + tok) * 960 + h * 80 + p;
    sq[tok][p] = base[0]; sk[tok][p] = base[320]; sv[tok][p] = base[640];
  }
  __syncthreads();
  if (tid < 36) {
    int qi = tid / 6, ki = tid % 6;
    float d = 0.f;
    for (int p = 0; p < 80; ++p) d += sq[qi][p] * sk[ki][p];
    sw[qi][ki] = d * 0.11180339887498948f;  // 1/sqrt(80)
  }
  __syncthreads();
  if (tid < 6) {
    float mx = sw[tid][0];
    for (int k = 1; k < 6; ++k) mx = fmaxf(mx, sw[tid][k]);
    float s = 0.f;
    for (int k = 0; k < 6; ++k) { float e = expf(sw[tid][k] - mx); sw[tid][k] = e; s += e; }
    float inv = 1.f / s;
    for (int k = 0; k < 6; ++k) sw[tid][k] *= inv;
  }
  __syncthreads();
  for (int i = tid; i < 480; i += 128) {
    int qi = i / 80, p = i % 80;
    float o = 0.f;
    for (int k = 0; k < 6; ++k) o += sw[qi][k] * sv[k][p];
    O[(size_t)(b * 6 + qi) * CDIM + h * 80 + p] = o;
  }
}

// ------------- t2i attention pass 1: bf16 K/V, LDS + MFMA PV, grid (64,4,2) --
__global__ __launch_bounds__(256) void attn_t2i_part2(const float* __restrict__ Qp,
                                                      const bf16_t* __restrict__ Kp,
                                                      const bf16_t* __restrict__ Vp,
                                                      float* __restrict__ Part) {
  int b = blockIdx.z, h = blockIdx.y, c = blockIdx.x;
  Qp += (size_t)b * 960;
  Kp += (size_t)b * LSEQ * 160;
  Vp += (size_t)b * LSEQ * 160;
  Part += (size_t)b * 24 * 64 * 42;
  __shared__ float sq[240];
  __shared__ float redm[4][6], reds[4][6];
  __shared__ __align__(16) bf16_t sPb[16 * 264];
  __shared__ __align__(16) bf16_t sVtb[48 * 264];
  int tid = threadIdx.x;
  int wave = tid >> 6, lane = tid & 63;
  if (tid < 240) sq[tid] = Qp[(size_t)(tid / 40) * 160 + h * 40 + (tid % 40)];
  __syncthreads();
  int t = c * 256 + tid;
  const bf16_t* kp = Kp + (size_t)t * 160 + h * 40;
  float kr[40];
#pragma unroll
  for (int v = 0; v < 5; ++v) {
    bf16x8 k8 = *(const bf16x8*)(kp + v * 8);
#pragma unroll
    for (int j = 0; j < 8; ++j) kr[v * 8 + j] = (float)k8[j];
  }
  const bf16_t* vp = Vp + (size_t)t * 160 + h * 40;
#pragma unroll
  for (int v = 0; v < 5; ++v) {
    bf16x8 v8 = *(const bf16x8*)(vp + v * 8);
#pragma unroll
    for (int j = 0; j < 8; ++j) sVtb[(v * 8 + j) * 264 + tid] = v8[j];
  }
  float s[6];
#pragma unroll
  for (int qi = 0; qi < 6; ++qi) {
    float d = 0.f;
#pragma unroll
    for (int p = 0; p < 40; ++p) d += sq[qi * 40 + p] * kr[p];
    s[qi] = d * 0.15811388300841897f;  // 1/sqrt(40)
  }
#pragma unroll
  for (int qi = 0; qi < 6; ++qi) {
    float wm = wave_max(s[qi]);
    if (lane == 0) redm[wave][qi] = wm;
  }
  __syncthreads();
  float gmax[6], ls[6];
#pragma unroll
  for (int qi = 0; qi < 6; ++qi)
    gmax[qi] = fmaxf(fmaxf(redm[0][qi], redm[1][qi]), fmaxf(redm[2][qi], redm[3][qi]));
#pragma unroll
  for (int qi = 0; qi < 6; ++qi) {
    float e = expf(s[qi] - gmax[qi]);
    sPb[qi * 264 + tid] = (bf16_t)e;
    float wsum = wave_sum(e);
    if (lane == 0) reds[wave][qi] = wsum;
  }
  __syncthreads();
#pragma unroll
  for (int qi = 0; qi < 6; ++qi)
    ls[qi] = reds[0][qi] + reds[1][qi] + reds[2][qi] + reds[3][qi];
  if (tid == 0) {
#pragma unroll
    for (int qi = 0; qi < 6; ++qi) {
      float* pml = Part + (size_t)((h * 6 + qi) * 64 + c) * 42;
      pml[40] = gmax[qi];
      pml[41] = ls[qi];
    }
  }
  if (wave == 0) {
    int fm = lane & 15, quad = lane >> 4;
    f32x4 acc[3];
#pragma unroll
    for (int nt = 0; nt < 3; ++nt) acc[nt] = (f32x4){0.f, 0.f, 0.f, 0.f};
#pragma unroll
    for (int ks = 0; ks < 8; ++ks) {
      bf16x8 a = *(bf16x8*)&sPb[fm * 264 + ks * 32 + quad * 8];
#pragma unroll
      for (int nt = 0; nt < 3; ++nt) {
        bf16x8 bb = *(bf16x8*)&sVtb[(nt * 16 + fm) * 264 + ks * 32 + quad * 8];
        acc[nt] = __builtin_amdgcn_mfma_f32_16x16x32_bf16(a, bb, acc[nt], 0, 0, 0);
      }
    }
#pragma unroll
    for (int nt = 0; nt < 3; ++nt)
#pragma unroll
      for (int r = 0; r < 4; ++r) {
        int qi = quad * 4 + r;
        int p = nt * 16 + fm;
        if (qi < 6 && p < 40)
          Part[(size_t)((h * 6 + qi) * 64 + c) * 42 + p] = acc[nt][r];
      }
  }
}

// ------------- t2i attention pass 2: combine 64 partials, grid (24,2) --------
__global__ void attn_t2i_comb(const float* __restrict__ Part, float* __restrict__ O) {
  int b = blockIdx.y;
  int blk = blockIdx.x;  // h*6 + qi
  int qi = blk % 6;
  int h = blk / 6;
  int j = threadIdx.x;  // 64
  const float* base = Part + (size_t)b * 24 * 64 * 42 + (size_t)blk * 64 * 42;
  float m = base[j * 42 + 40], l = base[j * 42 + 41];
  float gmax = wave_max(m);
  gmax = __shfl(gmax, 0, 64);
  float sc = expf(m - gmax);
  float tot = wave_sum(l * sc);
  tot = __shfl(tot, 0, 64);
  float inv = 1.f / tot;
  __shared__ float ssc[64];
  ssc[j] = sc;
  __syncthreads();
  if (j < 40) {
    float a0 = 0.f, a1 = 0.f, a2 = 0.f, a3 = 0.f;
    for (int jj = 0; jj < 64; jj += 4) {
      a0 = fmaf(base[(jj + 0) * 42 + j], ssc[jj + 0], a0);
      a1 = fmaf(base[(jj + 1) * 42 + j], ssc[jj + 1], a1);
      a2 = fmaf(base[(jj + 2) * 42 + j], ssc[jj + 2], a2);
      a3 = fmaf(base[(jj + 3) * 42 + j], ssc[jj + 3], a3);
    }
    O[(size_t)b * 960 + (size_t)qi * 160 + h * 40 + j] = (a0 + a1 + a2 + a3) * inv;
  }
}

// ------- i2t attention: bf16 Q in, bf16 out, grid (64,4,2) -------------------
__global__ __launch_bounds__(256) void attn_i2t(const bf16_t* __restrict__ Qp,
                                                const float* __restrict__ KV,
                                                bf16_t* __restrict__ O) {
  int h = blockIdx.y, b = blockIdx.z;
  int t = blockIdx.x * 256 + threadIdx.x;
  Qp += (size_t)b * LSEQ * 160;
  O += (size_t)b * LSEQ * 160;
  __shared__ float sk[6][40], sv[6][40];
  if (threadIdx.x < 240) {
    int tok = threadIdx.x / 40, p = threadIdx.x % 40;
    const float* base = KV + (size_t)(b * 6 + tok) * 320 + h * 40 + p;
    sk[tok][p] = base[0];
    sv[tok][p] = base[160];
  }
  __syncthreads();
  const bf16_t* q = Qp + (size_t)t * 160 + h * 40;
  float qr[40];
#pragma unroll
  for (int v = 0; v < 5; ++v) {
    bf16x8 q8 = *(const bf16x8*)(q + v * 8);
#pragma unroll
    for (int j = 0; j < 8; ++j) qr[v * 8 + j] = (float)q8[j];
  }
  float s[6];
#pragma unroll
  for (int k = 0; k < 6; ++k) {
    float d = 0.f;
    for (int p = 0; p < 40; ++p) d += qr[p] * sk[k][p];
    s[k] = d * 0.15811388300841897f;
  }
  float mx = s[0];
#pragma unroll
  for (int k = 1; k < 6; ++k) mx = fmaxf(mx, s[k]);
  float sum = 0.f;
#pragma unroll
  for (int k = 0; k < 6; ++k) { s[k] = expf(s[k] - mx); sum += s[k]; }
  float inv = 1.f / sum;
  bf16_t* o = O + (size_t)t * 160 + h * 40;
#pragma unroll
  for (int v = 0; v < 10; ++v) {
    float o0 = 0.f, o1 = 0.f, o2 = 0.f, o3 = 0.f;
#pragma unroll
    for (int k = 0; k < 6; ++k) {
      float w = s[k];
      o0 += w * sv[k][v * 4 + 0];
      o1 += w * sv[k][v * 4 + 1];
      o2 += w * sv[k][v * 4 + 2];
      o3 += w * sv[k][v * 4 + 3];
    }
    bf16x4 ov;
    ov[0] = (bf16_t)(o0 * inv); ov[1] = (bf16_t)(o1 * inv);
    ov[2] = (bf16_t)(o2 * inv); ov[3] = (bf16_t)(o3 * inv);
    *(bf16x4*)(o + v * 4) = ov;
  }
}

// =======================================================================
extern "C" void kernel_launch(void* const* d_in, const int* in_sizes, int n_in,
                              void* d_out, int out_size, void* d_ws, size_t ws_size,
                              hipStream_t stream) {
  (void)in_sizes; (void)n_in; (void)out_size;
  const float* x       = (const float*)d_in[0];
  const float* coords  = (const float*)d_in[1];
  const int*   labels  = (const int*)  d_in[2];
  const float* ln_w    = (const float*)d_in[3];
  const float* ln_b    = (const float*)d_in[4];
  const float* in_w    = (const float*)d_in[5];
  const float* conv_w  = (const float*)d_in[6];
  const float* conv_b  = (const float*)d_in[7];
  const float* dt_bias = (const float*)d_in[8];
  const float* A_log   = (const float*)d_in[9];
  const float* Dp      = (const float*)d_in[10];
  const float* rms_w   = (const float*)d_in[11];
  const float* out_w   = (const float*)d_in[12];
  const float* gauss   = (const float*)d_in[13];
  const float* ptab    = (const float*)d_in[14];
  const float* sa_w    = (const float*)d_in[15];
  const float* sa_b    = (const float*)d_in[16];
  const float* t2i_w   = (const float*)d_in[17];
  const float* t2i_b   = (const float*)d_in[18];
  const float* t2i_ow  = (const float*)d_in[19];
  const float* t2i_ob  = (const float*)d_in[20];
  const float* i2t_w   = (const float*)d_in[21];
  const float* i2t_b   = (const float*)d_in[22];
  const float* i2t_ow  = (const float*)d_in[23];
  const float* i2t_ob  = (const float*)d_in[24];
  const float* norms_w = (const float*)d_in[25];
  const float* norms_b = (const float*)d_in[26];
  const float* mlp_w1  = (const float*)d_in[27];
  const float* mlp_b1  = (const float*)d_in[28];
  const float* mlp_w2  = (const float*)d_in[29];
  const float* mlp_b2  = (const float*)d_in[30];
  float* out = (float*)d_out;
  float* ws = (float*)d_ws;

  const size_t NEED = (size_t)(10485760 + 5242880 + 11665408 + 11534336 + 10485760 +
                               131072 + 131072 + 65536) * 4;
  if (ws_size < NEED) {
    ws_probe<<<1, 1, 0, stream>>>(out, (float)ws_size);
    return;
  }
  float* R_K = ws;                           // [2][16384][320] fp32
  float* P   = ws + 10485760;                // scratch pool
  // ---- mamba-phase layout (per batch, reused) ----
  bf16_t* XNB_   = (bf16_t*)P;               // LN'd input bf16 [16384][320]
  float* SCHUNK_ = P;                        // reuses XNB after in_proj
  bf16_t* ZBB_   = (bf16_t*)(P + 5242880);   // z bf16 [16384][640]
  bf16_t* XBCB_  = (bf16_t*)(P + 10485760);  // xBC|dt bf16 [16384][712]
  float* SPREV_  = P + 10485760;             // reuses XBCB after conv/dt
  bf16_t* CVB_   = (bf16_t*)(P + 16318464);  // conv out bf16 [16384][704]
  bf16_t* YSB_   = (bf16_t*)(P + 22085632);  // scan-out / gated bf16 [16384][640]
  float* DT_     = P + 27328512;             // 131,072
  float* CA_     = P + 27459584;             // 131,072
  bf16_t* WBI_   = (bf16_t*)(P + 27590656);  // in_w bf16 (432,640)
  bf16_t* WBO_   = (bf16_t*)(P + 27806976);  // out_w bf16 (204,800)
  // ---- transformer-phase layout ----
  float* KPE_   = P;                         // 5,242,880 fp32
  bf16_t* T0B_  = (bf16_t*)(P + 5242880);    // [2][16384][160] bf16 t2i-K
  bf16_t* T3B_  = (bf16_t*)(P + 7864320);    // [2][16384][160] bf16 i2t-Q
  bf16_t* T1B_  = (bf16_t*)(P + 10485760);   // [2][16384][160] bf16 t2i-V
  bf16_t* T2B_  = (bf16_t*)(P + 13107200);   // [2][16384][160] bf16 i2t out
  float* PART_  = P + 15728640;              // [2][24][64][42]
  float* SM_    = P + 15857664;
  float* QPE_  = SM_;
  float* QRY_  = SM_ + 3840;
  float* P3_   = SM_ + 7680;
  float* PO_   = SM_ + 19200;
  float* H_    = SM_ + 23040;
  float* Q160_ = SM_ + 35328;
  float* O160_ = SM_ + 37248;
  float* KV_   = SM_ + 39168;

  const long long sIMG160 = (long long)LSEQ * 160;
  const long long sIMG320 = (long long)LSEQ * CDIM;
  const int NOSPLIT = 1 << 30;

  // weights -> bf16 once
  cvt_bf<<<(432640 / 4 + 255) / 256, 256, 0, stream>>>(in_w, WBI_, 432640);
  cvt_bf<<<(204800 / 4 + 255) / 256, 256, 0, stream>>>(out_w, WBO_, 204800);

  // ======== mamba phase, per batch ========
  for (int b = 0; b < 2; ++b) {
    const float* xb = x + (size_t)b * CDIM * LSEQ;
    float* Kb = R_K + (size_t)b * LSEQ * CDIM;

    tln<<<LSEQ / 32, 256, 0, stream>>>(xb, ln_w, ln_b, XNB_);

    // fused in_proj: cols [0,640) -> ZBB (bf16), cols [640,1352) -> XBCB (bf16)
    gemm_bf<<<dim3(22, 128, 1), 256, 0, stream>>>(
        XNB_, WBI_, nullptr, nullptr, ZBB_, XBCB_, nullptr, nullptr, NOSPLIT,
        LSEQ, 1352, CDIM, CDIM, DIN, DIN, XBCW, 0, 1, 1, 1, 0, 0);

    dt_kernel<<<LSEQ * NHH / 256, 256, 0, stream>>>(XBCB_, dt_bias, DT_);
    conv2<<<dim3(11, 128), 256, 0, stream>>>(XBCB_, conv_w, conv_b, CVB_);

    scan_a<<<dim3(NCHUNK, NHH), 256, 0, stream>>>(CVB_, DT_, A_log, SCHUNK_, CA_);
    scan_b<<<dim3(10, NHH), 256, 0, stream>>>(SCHUNK_, CA_, SPREV_);
    scan_c<<<dim3(NCHUNK, NHH), 256, 0, stream>>>(CVB_, DT_, CA_, SPREV_, Dp, YSB_);

    gate_rms<<<LSEQ, 256, 0, stream>>>(YSB_, ZBB_, rms_w);

    gemm64<<<dim3(5, 256, 1), 256, 0, stream>>>(
        YSB_, WBO_, nullptr, nullptr, Kb, nullptr, nullptr, nullptr, NOSPLIT,
        LSEQ, CDIM, DIN, DIN, CDIM, NOSPLIT, 0, 0, 1, 1, 0, 0, 0);
  }

  kpe_kernel<<<LSEQ * 160 / 256, 256, 0, stream>>>(gauss, KPE_);
  point_kernel<<<30, 64, 0, stream>>>(coords, labels, gauss, ptab, QPE_, QRY_);

  // ======== transformer phase, both batches per dispatch ========
  for (int i = 0; i < 2; ++i) {
    const float* saw = sa_w + (size_t)i * 4 * CDIM * CDIM;
    const float* sab = sa_b + (size_t)i * 4 * CDIM;
    smallmm<<<240, 256, 0, stream>>>(QRY_, (i == 0) ? nullptr : QPE_,
                                     saw, sab, P3_, 960, CDIM, 0, 0, 640);
    attn_self<<<dim3(4, 2), 128, 0, stream>>>(P3_, PO_);
    smallmm<<<80, 256, 0, stream>>>(PO_, nullptr, saw + 3 * 102400, sab + 3 * CDIM,
                                    QRY_, CDIM, CDIM, (i == 0) ? 0 : 1, 0, 0);
    ln_rows256<<<3, 256, 0, stream>>>(QRY_, norms_w + (size_t)(i * 4 + 0) * CDIM,
                                      norms_b + (size_t)(i * 4 + 0) * CDIM, 12);

    smallmm<<<40, 256, 0, stream>>>(QRY_, QPE_, t2i_w + (size_t)(i * 3 + 0) * 51200,
                                    t2i_b + (size_t)(i * 3 + 0) * 160, Q160_,
                                    160, CDIM, 0, 0, 160);
    // fused: cols 0-159 = t2i-K -> T0B (bf16); cols 160-319 = i2t-Q -> T3B.
    gemm64<<<dim3(5, 256, 2), 256, 0, stream>>>(
        R_K, t2i_w + (size_t)(i * 3 + 1) * 51200, t2i_b + (size_t)(i * 3 + 1) * 160,
        KPE_, T0B_, T3B_, i2t_w + (size_t)(i * 3 + 0) * 51200,
        i2t_b + (size_t)(i * 3 + 0) * 160, 160,
        LSEQ, 320, CDIM, CDIM, 160, 160, 160, 0, 0, 0, 1, sIMG320, sIMG160);
    gemm64<<<dim3(3, 256, 2), 256, 0, stream>>>(
        R_K, t2i_w + (size_t)(i * 3 + 2) * 51200, t2i_b + (size_t)(i * 3 + 2) * 160,
        nullptr, T1B_, nullptr, nullptr, nullptr, NOSPLIT,
        LSEQ, 160, CDIM, CDIM, 160, NOSPLIT, 0, 0, 0, 0, 1, sIMG320, sIMG160);
    attn_t2i_part2<<<dim3(64, 4, 2), 256, 0, stream>>>(Q160_, T0B_, T1B_, PART_);
    attn_t2i_comb<<<dim3(24, 2), 64, 0, stream>>>(PART_, O160_);
    smallmm<<<80, 256, 0, stream>>>(O160_, nullptr, t2i_ow + (size_t)i * 51200,
                                    t2i_ob + (size_t)i * CDIM, QRY_,
                                    CDIM, 160, 1, 0, 0);
    ln_rows256<<<3, 256, 0, stream>>>(QRY_, norms_w + (size_t)(i * 4 + 1) * CDIM,
                                      norms_b + (size_t)(i * 4 + 1) * CDIM, 12);

    smallmm<<<256, 256, 0, stream>>>(QRY_, nullptr, mlp_w1 + (size_t)i * 1024 * CDIM,
                                     mlp_b1 + (size_t)i * 1024, H_, 1024, CDIM, 0, 1, 0);
    smallmm<<<80, 256, 0, stream>>>(H_, nullptr, mlp_w2 + (size_t)i * CDIM * 1024,
                                    mlp_b2 + (size_t)i * CDIM, QRY_, CDIM, 1024, 1, 0, 0);
    ln_rows256<<<3, 256, 0, stream>>>(QRY_, norms_w + (size_t)(i * 4 + 2) * CDIM,
                                      norms_b + (size_t)(i * 4 + 2) * CDIM, 12);

    smallmm<<<80, 256, 0, stream>>>(QRY_, QPE_, i2t_w + (size_t)(i * 3 + 1) * 51200,
                                    i2t_b + (size_t)(i * 3 + 1) * 160, KV_,
                                    320, CDIM, 0, 0, 160);
    attn_i2t<<<dim3(LSEQ / 256, 4, 2), 256, 0, stream>>>(T3B_, KV_, T2B_);
    gemm64<<<dim3(5, 256, 2), 256, 0, stream>>>(
        T2B_, i2t_ow + (size_t)i * CDIM * 160, i2t_ob + (size_t)i * CDIM,
        nullptr, R_K, nullptr, nullptr, nullptr, NOSPLIT,
        LSEQ, CDIM, 160, 160, CDIM, NOSPLIT, 0, 1, 1, 0, 0, sIMG160, sIMG320);
    if (i == 0) {
      ln_rows256<<<2 * LSEQ / 4, 256, 0, stream>>>(
          R_K, norms_w + (size_t)3 * CDIM, norms_b + (size_t)3 * CDIM, 2 * LSEQ);
    }
  }

  // final layernorm fused with transpose to output layout (C,L)
  for (int b = 0; b < 2; ++b) {
    lnt<<<LSEQ / 32, 256, 0, stream>>>(
        R_K + (size_t)b * LSEQ * CDIM, norms_w + (size_t)7 * CDIM,
        norms_b + (size_t)7 * CDIM, out + (size_t)b * CDIM * LSEQ);
  }
}